// Round 1
// 2246.937 us; speedup vs baseline: 1.0651x; 1.0651x over previous
//
#include <hip/hip_runtime.h>
#include <hip/hip_bf16.h>
#include <math.h>
#include <stddef.h>

// B=32, P=196, E=256, A=512, M=512, D=512, V=20000, L=52, T=51
// fp32 in/out. Step loop fused into ONE persistent kernel (88 blocks).
// R1: contention-free flag barrier (per-block flag stores + parallel poll by
//     block 0) replaces the serialized fetch_add counter barrier; gatesH kept
//     in registers (phase C remapped to blocks 24-87, same cols as phase A).

typedef unsigned short ushort_t;
typedef __bf16 bf16x8 __attribute__((ext_vector_type(8)));
typedef float f32x4 __attribute__((ext_vector_type(4)));
typedef unsigned short ushort8 __attribute__((ext_vector_type(8)));
typedef unsigned short ushort4v __attribute__((ext_vector_type(4)));

union FragU { ushort8 u; bf16x8 b; };

__device__ __forceinline__ unsigned short f2bu(float f){
  union { float f; unsigned int i; } c; c.f = f;
  unsigned int x = c.i;
  unsigned int r = x + 0x7fffu + ((x >> 16) & 1u);
  return (unsigned short)(r >> 16);
}
__device__ __forceinline__ float bu2f(unsigned short u){
  union { unsigned int i; float f; } c; c.i = ((unsigned int)u) << 16; return c.f;
}
__device__ __forceinline__ float sigm(float x){ return 1.f/(1.f+__expf(-x)); }
__device__ __forceinline__ float ftanh(float x){ float e = __expf(2.f*x); return 1.f - 2.f/(e+1.f); }

#define NB 88

// ---- contention-free grid barrier: per-block flags + master (block 0) poll ----------------
// flags[b] and *gen are MONOTONIC epochs within one launch (zeroed by k_misc each launch).
__device__ __forceinline__ void gridbar2(int* flags, int* gen, int ep){
  __syncthreads();
  if (blockIdx.x == 0){
    int tid = threadIdx.x;
    if (tid > 0 && tid < NB){
      // parallel poll: lane i waits for block i's arrival flag (reads, no RMW contention)
      while (__hip_atomic_load(flags + tid, __ATOMIC_RELAXED, __HIP_MEMORY_SCOPE_AGENT) < ep) {}
    }
    __syncthreads();
    if (tid == 0){
      __threadfence();  // full fence: release block 0's phase writes + acquire others'
      __hip_atomic_store(gen, ep, __ATOMIC_RELAXED, __HIP_MEMORY_SCOPE_AGENT);
    }
    __syncthreads();
  } else {
    if (threadIdx.x == 0){
      __threadfence();  // release: make this block's phase writes visible
      __hip_atomic_store(flags + blockIdx.x, ep, __ATOMIC_RELAXED, __HIP_MEMORY_SCOPE_AGENT);
      while (__hip_atomic_load(gen, __ATOMIC_RELAXED, __HIP_MEMORY_SCOPE_AGENT) < ep)
        __builtin_amdgcn_s_sleep(1);
      __threadfence();  // acquire: invalidate stale lines
    }
    __syncthreads();
  }
}

// ---- transpose + fp32->bf16; optional dest-row permute r=d*4+g (for 2048-col gate mats) ---
__global__ __launch_bounds__(256) void k_cvtT(const float* __restrict__ src, int C,
                                              ushort_t* __restrict__ dst, int ldd, int perm){
  __shared__ float tile[32][33];
  int c0 = blockIdx.x*32, r0 = blockIdx.y*32;
  int tx = threadIdx.x & 31, ty = threadIdx.x >> 5;
  #pragma unroll
  for (int i=0;i<4;i++){ int r = ty + i*8; tile[r][tx] = src[(size_t)(r0+r)*C + c0+tx]; }
  __syncthreads();
  #pragma unroll
  for (int i=0;i<4;i++){
    int c = ty + i*8;
    int row = c0 + c;
    if (perm) row = ((row & 511) << 2) | (row >> 9);   // g*512+d -> d*4+g
    dst[(size_t)row*ldd + r0+tx] = f2bu(tile[tx][c]);
  }
}

// ---- elementwise fp32 -> bf16 -------------------------------------------------------------
__global__ __launch_bounds__(256) void k_cvt4(const float* __restrict__ src,
                                              ushort_t* __restrict__ dst, int n4){
  int i = blockIdx.x*256 + threadIdx.x;
  if (i < n4){
    float4 v = ((const float4*)src)[i];
    ushort4v o; o.x=f2bu(v.x); o.y=f2bu(v.y); o.z=f2bu(v.z); o.w=f2bu(v.w);
    ((ushort4v*)dst)[i] = o;
  }
}

// ---- misc: int outputs, declen, biases, zero barrier flags --------------------------------
__global__ __launch_bounds__(256) void k_misc(const int* __restrict__ cap, const int* __restrict__ lens,
                      const float* __restrict__ bdec, const float* __restrict__ bfb,
                      const float* __restrict__ bih, const float* __restrict__ bhh,
                      float* out_cap, float* out_dl, int* declen,
                      float* xbias, float* bihR, int* flags, int* gen){
  int tid = blockIdx.x*256 + threadIdx.x;
  if (tid < 128) flags[tid] = 0;
  if (tid == 0) *gen = 0;
  if (tid < 32*52) out_cap[tid] = (float)cap[tid];
  if (tid < 32){ int dl = lens[tid]-1; out_dl[tid] = (float)dl; declen[tid] = dl; }
  if (tid < 768) xbias[tid] = (tid<512) ? bdec[tid] : bfb[tid-512];
  if (tid < 2048){
    int c = (tid&3)*512 + (tid>>2);   // reordered col r=d*4+g <- original c=g*512+d
    bihR[tid] = bih[c] + bhh[c];      // bhh folded in (gatesH bias no longer separate)
  }
}

// ---- init: mean_enc -> h0 (bf16), c0 (fp32) -----------------------------------------------
__global__ __launch_bounds__(256) void k_init(const float* __restrict__ enc,
                     const float* __restrict__ Wih_, const float* __restrict__ bih_,
                     const float* __restrict__ Wic_, const float* __restrict__ bic_,
                     ushort_t* __restrict__ hnewb, float* __restrict__ cbuf){
  int b = blockIdx.x, tid = threadIdx.x;
  __shared__ float mean_s[256];
  const float* eb = enc + (size_t)b*196*256;
  float s = 0.f;
  for (int p=0;p<196;p++) s += eb[p*256 + tid];
  mean_s[tid] = s * (1.f/196.f);
  __syncthreads();
  float h0=0.f,h1=0.f,c0=0.f,c1=0.f;
  for (int k=0;k<256;k++){
    float m = mean_s[k];
    h0 += m*Wih_[k*512+tid];      h1 += m*Wih_[k*512+tid+256];
    c0 += m*Wic_[k*512+tid];      c1 += m*Wic_[k*512+tid+256];
  }
  hnewb[b*512+tid]     = f2bu(h0 + bih_[tid]);
  hnewb[b*512+tid+256] = f2bu(h1 + bih_[tid+256]);
  cbuf[b*512+tid]      = c0 + bic_[tid];
  cbuf[b*512+tid+256]  = c1 + bic_[tid+256];
}

// ---- gather embedding rows -> bf16 --------------------------------------------------------
__global__ __launch_bounds__(256) void k_gather(const int* __restrict__ cap,
                                                const float* __restrict__ emb,
                                                ushort_t* __restrict__ erowsb){
  int row = blockIdx.x; int b = row/51, t = row%51;
  int tok = cap[b*52 + t];
  const float* src = emb + (size_t)tok*512;
  ushort_t* dst = erowsb + (size_t)row*512;
  dst[threadIdx.x]       = f2bu(src[threadIdx.x]);
  dst[threadIdx.x + 256] = f2bu(src[threadIdx.x + 256]);
}

// ---- generic bf16 MFMA GEMM (128x128 tile); optional XCD-aware flat mapping ---------------
#define LDT 40
__global__ __launch_bounds__(256)
void k_gemm(const ushort_t* __restrict__ Ag, int lda,
            const ushort_t* __restrict__ Bg, int ldb,
            int Mrows, int Ncols, int K,
            const float* __restrict__ bias,
            float* __restrict__ outF, ushort_t* __restrict__ outH, int ldo,
            const int* __restrict__ declen,
            int Mtiles, int Ntiles, int xcdswz)
{
  __shared__ ushort_t As[128*LDT];
  __shared__ ushort_t Bs[128*LDT];
  int m0, n0;
  if (xcdswz){
    int l = blockIdx.x; int xcd = l & 7; int i = l >> 3;
    int mt = i % Mtiles; int ns = i / Mtiles;
    int nt = ns*8 + xcd;
    if (nt >= Ntiles) return;
    m0 = mt*128; n0 = nt*128;
  } else {
    m0 = blockIdx.y*128; n0 = blockIdx.x*128;
  }
  int tid = threadIdx.x;
  int wave = tid>>6, lane = tid&63;
  int wm = wave>>1, wn = wave&1;
  int q = lane>>4, r = lane&15;
  f32x4 acc[4][4];
  f32x4 zero4 = {0.f,0.f,0.f,0.f};
  #pragma unroll
  for(int i=0;i<4;i++){ acc[i][0]=zero4; acc[i][1]=zero4; acc[i][2]=zero4; acc[i][3]=zero4; }

  for (int k0=0; k0<K; k0+=32){
    __syncthreads();
    #pragma unroll
    for (int c=tid; c<512; c+=256){
      int row = c>>2, ko = (c&3)*8;
      ushort8 v = {0,0,0,0,0,0,0,0};
      if (m0+row < Mrows) v = *(const ushort8*)(Ag + (size_t)(m0+row)*lda + k0 + ko);
      *(ushort8*)(As + row*LDT + ko) = v;
      ushort8 wv = {0,0,0,0,0,0,0,0};
      if (n0+row < Ncols) wv = *(const ushort8*)(Bg + (size_t)(n0+row)*ldb + k0 + ko);
      *(ushort8*)(Bs + row*LDT + ko) = wv;
    }
    __syncthreads();
    FragU a[4], bb[4];
    #pragma unroll
    for(int i=0;i<4;i++){
      a[i].u  = *(const ushort8*)(As + (64*wm + 16*i + r)*LDT + 8*q);
      bb[i].u = *(const ushort8*)(Bs + (64*wn + 16*i + r)*LDT + 8*q);
    }
    #pragma unroll
    for(int i=0;i<4;i++)
      #pragma unroll
      for(int j=0;j<4;j++)
        acc[i][j] = __builtin_amdgcn_mfma_f32_16x16x32_bf16(a[i].b, bb[j].b, acc[i][j], 0,0,0);
  }
  #pragma unroll
  for(int i=0;i<4;i++){
    int rowbase = m0 + 64*wm + 16*i + q*4;
    #pragma unroll
    for(int j=0;j<4;j++){
      int col = n0 + 64*wn + 16*j + r;
      if (col >= Ncols) continue;
      float bv = bias ? bias[col] : 0.f;
      #pragma unroll
      for(int rr=0;rr<4;rr++){
        int row = rowbase + rr;
        if (row >= Mrows) continue;
        float v = acc[i][j][rr] + bv;
        if (declen){ int tt = row % 51; int b = row / 51; if (tt >= declen[b]) v = 0.f; }
        if (outF) outF[(size_t)row*ldo + col] = v;
        else      outH[(size_t)row*ldo + col] = f2bu(v);
      }
    }
  }
}

// ---- 32x32 MFMA tile: C(32 x 32cols) = A(32xK) @ Brows(32xK)^T, K templated ---------------
template<int K>
__device__ __forceinline__ f32x4 tile32(const ushort_t* __restrict__ Ag, int lda,
                                        const ushort_t* __restrict__ Bg, int ldb,
                                        ushort_t* As, ushort_t* Bs){
  const int KW = K/8, LDS = K+8;
  int tid = threadIdx.x, wave = tid>>6, lane = tid&63;
  int q = lane>>4, r = lane&15;
  int wm = (wave>>1)*16, wn = (wave&1)*16;
  for (int i=tid; i<32*KW; i+=256){
    int row = i/KW, ko = (i%KW)*8;
    *(ushort8*)(As + row*LDS + ko) = *(const ushort8*)(Ag + (size_t)row*lda + ko);
    *(ushort8*)(Bs + row*LDS + ko) = *(const ushort8*)(Bg + (size_t)row*ldb + ko);
  }
  __syncthreads();
  f32x4 acc = {0.f,0.f,0.f,0.f};
  #pragma unroll
  for (int kc=0; kc<K; kc+=32){
    FragU a, b;
    a.u = *(const ushort8*)(As + (wm + r)*LDS + kc + 8*q);
    b.u = *(const ushort8*)(Bs + (wn + r)*LDS + kc + 8*q);
    acc = __builtin_amdgcn_mfma_f32_16x16x32_bf16(a.b, b.b, acc, 0,0,0);
  }
  return acc;
}

// ---- persistent fused step loop: 88 blocks ------------------------------------------------
__global__ __launch_bounds__(256)
void k_steps(const ushort_t* __restrict__ XWT768, const ushort_t* __restrict__ WHCp,
             const float* __restrict__ xbias,
             const ushort_t* __restrict__ att1b, const float* __restrict__ wfull,
             const ushort_t* __restrict__ encb, const ushort_t* __restrict__ eihR,
             const int* __restrict__ declen,
             ushort_t* __restrict__ hnewb, float* __restrict__ cbuf,
             float* __restrict__ XO,
             ushort_t* __restrict__ xaweb, ushort_t* __restrict__ hallb,
             float* __restrict__ out_alph, int* flags, int* gen)
{
  int blk = blockIdx.x, tid = threadIdx.x;
  int wave = tid>>6, lane = tid&63;
  int q = lane>>4, r = lane&15;
  int wm = (wave>>1)*16, wn = (wave&1)*16;
  __shared__ ushort_t As[32*520];
  __shared__ ushort_t Bs[32*520];
  __shared__ float gl[32][32];

  int ep = 0;
  for (int t=0; t<51; t++){
    // ---------- phase A: XO = h@[Wdec|Wfb]+b (24 blks); accGH = h@Whh^T slice (64, in regs)
    f32x4 accGH = {0.f,0.f,0.f,0.f};
    if (blk < 24){
      int n0 = blk*32;
      f32x4 acc = tile32<512>(hnewb, 512, XWT768 + (size_t)n0*512, 512, As, Bs);
      int col = n0 + wn + r;
      float bv = xbias[col];
      #pragma unroll
      for (int rr=0;rr<4;rr++) XO[(size_t)(wm + 4*q + rr)*768 + col] = acc[rr] + bv;
    } else {
      int n0 = (blk-24)*32;
      accGH = tile32<512>(hnewb, 512, WHCp + (size_t)n0*768, 768, As, Bs);
      // stays in registers; consumed in phase C by THIS block (same cols)
    }
    gridbar2(flags, gen, ++ep);

    // ---------- phase B: attention + softmax + awe + gate (32 blocks, one per batch) -------
    if (blk < 32){
      int b = blk;
      float* att2_s  = (float*)As;           // 512
      float* wf_s    = att2_s + 512;         // 512
      float* alpha_s = wf_s + 512;           // 196
      float* red_s   = alpha_s + 200;        // 40
      const float* xo = XO + (size_t)b*768;
      for (int i=tid;i<512;i+=256){ att2_s[i]=xo[i]; wf_s[i]=wfull[i]; }
      __syncthreads();
      float av = -1e30f;
      if (tid < 196){
        const ushort_t* arow = att1b + ((size_t)b*196 + tid)*512;
        float s = 0.f;
        for (int k=0;k<512;k+=8){
          ushort8 v = *(const ushort8*)(arow + k);
          #pragma unroll
          for (int u=0;u<8;u++) s += fmaxf(bu2f(v[u]) + att2_s[k+u], 0.f)*wf_s[k+u];
        }
        av = s;
      }
      float m = av;
      #pragma unroll
      for (int off=32;off>0;off>>=1) m = fmaxf(m, __shfl_down(m, off, 64));
      if ((tid&63)==0) red_s[tid>>6] = m;
      __syncthreads();
      if (tid==0) red_s[16] = fmaxf(fmaxf(red_s[0],red_s[1]), fmaxf(red_s[2],red_s[3]));
      __syncthreads();
      float gmax = red_s[16];
      float ev = (tid<196) ? __expf(av - gmax) : 0.f;
      float ssum = ev;
      #pragma unroll
      for (int off=32;off>0;off>>=1) ssum += __shfl_down(ssum, off, 64);
      if ((tid&63)==0) red_s[20+(tid>>6)] = ssum;
      __syncthreads();
      if (tid==0) red_s[17] = red_s[20]+red_s[21]+red_s[22]+red_s[23];
      __syncthreads();
      float inv = 1.f/red_s[17];
      int mask = (t < declen[b]) ? 1 : 0;
      if (tid<196){
        float al = ev*inv;
        alpha_s[tid] = al;
        out_alph[((size_t)b*51 + t)*196 + tid] = mask ? al : 0.f;
      }
      __syncthreads();
      const ushort_t* eb = encb + (size_t)b*196*256;
      float aw = 0.f;
      for (int p=0;p<196;p++) aw += alpha_s[p]*bu2f(eb[p*256 + tid]);
      float gate = sigm(xo[512+tid]);
      xaweb[b*256 + tid] = f2bu(gate*aw);
    }
    gridbar2(flags, gen, ++ep);

    // ---------- phase C: gates = accGH + xawe@WihBot^T(reord) + eihR; LSTM (blocks 24-87) --
    if (blk >= 24){
      int n0 = (blk-24)*32;
      f32x4 acc2 = tile32<256>(xaweb, 256, WHCp + (size_t)n0*768 + 512, 768, As, Bs);
      int col = n0 + wn + r;
      #pragma unroll
      for (int rr=0;rr<4;rr++){
        int row = wm + 4*q + rr;
        gl[row][wn + r] = accGH[rr] + acc2[rr]
                        + bu2f(eihR[((size_t)row*51 + t)*2048 + col]);
      }
      __syncthreads();
      int b = tid>>3, dd = tid&7;
      int d = (n0>>2) + dd;
      float gi = gl[b][dd*4+0], gf = gl[b][dd*4+1], gg = gl[b][dd*4+2], go = gl[b][dd*4+3];
      float cold = cbuf[b*512 + d];
      float cnew = sigm(gf)*cold + sigm(gi)*ftanh(gg);
      float hnew = sigm(go)*ftanh(cnew);
      hallb[((size_t)b*51 + t)*512 + d] = f2bu(hnew);
      if (t < declen[b]){ cbuf[b*512 + d] = cnew; hnewb[b*512 + d] = f2bu(hnew); }
    }
    gridbar2(flags, gen, ++ep);
  }
}

// -------------------------------------------------------------------------------------------
extern "C" void kernel_launch(void* const* d_in, const int* in_sizes, int n_in,
                              void* d_out, int out_size, void* d_ws, size_t ws_size,
                              hipStream_t stream)
{
  const float* enc   = (const float*)d_in[0];
  const int*   cap   = (const int*)d_in[1];
  const int*   lens  = (const int*)d_in[2];
  const float* Wenc  = (const float*)d_in[3];
  const float* benc  = (const float*)d_in[4];
  const float* Wdec  = (const float*)d_in[5];
  const float* bdec  = (const float*)d_in[6];
  const float* Wfull = (const float*)d_in[7];
  // d_in[8] = b_full_att: softmax-invariant, skipped
  const float* emb   = (const float*)d_in[9];
  const float* Wih   = (const float*)d_in[10];
  const float* bih   = (const float*)d_in[11];
  const float* Whh   = (const float*)d_in[12];
  const float* bhh   = (const float*)d_in[13];
  const float* Winh  = (const float*)d_in[14];
  const float* binh  = (const float*)d_in[15];
  const float* Winc  = (const float*)d_in[16];
  const float* binc  = (const float*)d_in[17];
  const float* Wfb   = (const float*)d_in[18];
  const float* bfb   = (const float*)d_in[19];
  const float* Wfc   = (const float*)d_in[20];
  const float* bfc   = (const float*)d_in[21];
  float* out = (float*)d_out;

  char* w = (char*)d_ws;
  size_t off = 0;
  auto alloc = [&](size_t bytes)->char*{ char* p = w + off; off += (bytes + 255) & ~(size_t)255; return p; };
  ushort_t* WfcT    = (ushort_t*)alloc(20000ull*512*2);  // [20000][512]
  ushort_t* WHCp    = (ushort_t*)alloc(2048ull*768*2);   // rows r=d*4+g; k: [Whh^T | WihBot^T]
  ushort_t* WihTopTp= (ushort_t*)alloc(2048ull*512*2);   // rows r=d*4+g
  ushort_t* XWT768  = (ushort_t*)alloc(768ull*512*2);    // [Wdec^T ; Wfb^T]
  ushort_t* WencT   = (ushort_t*)alloc(512ull*256*2);
  ushort_t* encb    = (ushort_t*)alloc(32ull*196*256*2);
  ushort_t* erowsb  = (ushort_t*)alloc(1632ull*512*2);
  ushort_t* att1b   = (ushort_t*)alloc(6272ull*512*2);
  ushort_t* eihR    = (ushort_t*)alloc(1632ull*2048*2);  // cols r=d*4+g, incl. b_ih + b_hh
  ushort_t* hallb   = (ushort_t*)alloc(1632ull*512*2);
  ushort_t* hnewb   = (ushort_t*)alloc(32ull*512*2);
  ushort_t* xaweb   = (ushort_t*)alloc(32ull*256*2);
  float*    XO      = (float*)alloc(32ull*768*4);
  float*    cbuf    = (float*)alloc(32ull*512*4);
  float*    xbias   = (float*)alloc(768*4);
  float*    bihR    = (float*)alloc(2048*4);
  int*      declen  = (int*)alloc(32*4);
  int*      flags   = (int*)alloc(512);                  // 128 ints, per-block arrival epochs
  int*      gen     = (int*)alloc(256);                  // release epoch (own cacheline)

  float* out_preds = out;                        // 32*51*20000
  float* out_cap   = out + 32640000ull;          // 32*52
  float* out_dl    = out_cap + 1664;             // 32
  float* out_alph  = out_dl + 32;                // 32*51*196

  // ---- preamble ----
  k_cvtT<<<dim3(625,16),256,0,stream>>>(Wfc, 20000, WfcT, 512, 0);
  k_cvtT<<<dim3(64,16), 256,0,stream>>>(Whh, 2048, WHCp, 768, 1);                     // k 0..511
  k_cvtT<<<dim3(64,8),  256,0,stream>>>(Wih + 512ull*2048, 2048, WHCp + 512, 768, 1); // k 512..767
  k_cvtT<<<dim3(64,16), 256,0,stream>>>(Wih, 2048, WihTopTp, 512, 1);
  k_cvtT<<<dim3(16,16), 256,0,stream>>>(Wdec, 512, XWT768, 512, 0);
  k_cvtT<<<dim3(8,16),  256,0,stream>>>(Wfb, 256, XWT768 + 512ull*512, 512, 0);
  k_cvtT<<<dim3(16,8),  256,0,stream>>>(Wenc, 512, WencT, 256, 0);
  k_cvt4<<<1568,256,0,stream>>>(enc, encb, 401408);
  k_misc<<<8,256,0,stream>>>(cap, lens, bdec, bfb, bih, bhh, out_cap, out_dl, declen,
                             xbias, bihR, flags, gen);
  k_init<<<32,256,0,stream>>>(enc, Winh, binh, Winc, binc, hnewb, cbuf);
  k_gather<<<1632,256,0,stream>>>(cap, emb, erowsb);
  // att1b = encb @ WencT^T + benc  (6272 x 512, K=256) -> bf16
  k_gemm<<<dim3(4,49),256,0,stream>>>(encb, 256, WencT, 256, 6272, 512, 256,
                                      benc, nullptr, att1b, 512, nullptr, 0,0,0);
  // eihR = erowsb @ WihTopTp^T + (bihR+bhhR)  (1632 x 2048(reord), K=512) -> bf16
  k_gemm<<<dim3(16,13),256,0,stream>>>(erowsb, 512, WihTopTp, 512, 1632, 2048, 512,
                                       bihR, nullptr, eihR, 2048, nullptr, 0,0,0);

  // ---- fused 51-step recurrence: ONE launch ----
  k_steps<<<NB,256,0,stream>>>(XWT768, WHCp, xbias, att1b, Wfull, encb, eihR, declen,
                               hnewb, cbuf, XO, xaweb, hallb, out_alph, flags, gen);

  // ---- preds = hallb @ WfcT^T + bfc (masked). M=1632, N=20000, K=512; XCD-aware mapping ---
  k_gemm<<<2080,256,0,stream>>>(hallb, 512, WfcT, 512, 1632, 20000, 512,
                                bfc, out_preds, nullptr, 20000, declen, 13, 157, 1);
}

// Round 2
// 1933.336 us; speedup vs baseline: 1.2379x; 1.1622x over previous
//
#include <hip/hip_runtime.h>
#include <hip/hip_bf16.h>
#include <math.h>
#include <stddef.h>

// B=32, P=196, E=256, A=512, M=512, D=512, V=20000, L=52, T=51
// fp32 in/out. Step loop fused into ONE persistent kernel (88 blocks).
// R2: FENCE-FREE grid barrier. All inter-phase communication buffers (hnewb,
//     XO, xaweb, flags) go through agent-scope RELAXED atomics (LLC-coherent,
//     bypass per-XCD L2), so no __threadfence / buffer_wbl2 / buffer_inv is
//     ever executed in the steady state and the L2 stays warm with weights
//     (att1b/encb/WHCp/eihR) across all 51 steps. Barrier = syncthreads
//     (drains vmcnt for all waves) + per-block flag store + all-to-all poll.

typedef unsigned short ushort_t;
typedef __bf16 bf16x8 __attribute__((ext_vector_type(8)));
typedef float f32x4 __attribute__((ext_vector_type(4)));
typedef unsigned short ushort8 __attribute__((ext_vector_type(8)));
typedef unsigned short ushort4v __attribute__((ext_vector_type(4)));
typedef unsigned long long u64_t;

union FragU { ushort8 u; bf16x8 b; };

__device__ __forceinline__ unsigned short f2bu(float f){
  union { float f; unsigned int i; } c; c.f = f;
  unsigned int x = c.i;
  unsigned int r = x + 0x7fffu + ((x >> 16) & 1u);
  return (unsigned short)(r >> 16);
}
__device__ __forceinline__ float bu2f(unsigned short u){
  union { unsigned int i; float f; } c; c.i = ((unsigned int)u) << 16; return c.f;
}
__device__ __forceinline__ float sigm(float x){ return 1.f/(1.f+__expf(-x)); }
__device__ __forceinline__ float ftanh(float x){ float e = __expf(2.f*x); return 1.f - 2.f/(e+1.f); }

#define NB 88

// coherent (LLC) access helpers: agent-scope relaxed atomics -> sc-flagged
// global ops that bypass the non-coherent per-XCD L2. No fences needed.
__device__ __forceinline__ u64_t coh_ld64(const u64_t* p){
  return __hip_atomic_load(p, __ATOMIC_RELAXED, __HIP_MEMORY_SCOPE_AGENT);
}
__device__ __forceinline__ void coh_st64(u64_t* p, u64_t v){
  __hip_atomic_store(p, v, __ATOMIC_RELAXED, __HIP_MEMORY_SCOPE_AGENT);
}
__device__ __forceinline__ float coh_ldf(const float* p){
  return __hip_atomic_load(p, __ATOMIC_RELAXED, __HIP_MEMORY_SCOPE_AGENT);
}
__device__ __forceinline__ void coh_stf(float* p, float v){
  __hip_atomic_store(p, v, __ATOMIC_RELAXED, __HIP_MEMORY_SCOPE_AGENT);
}

// ---- fence-free all-to-all grid barrier ---------------------------------------------------
// flags[b] are MONOTONIC epochs (zeroed by k_misc each launch). __syncthreads() drains each
// wave's outstanding (coherent) stores to the LLC before the arrival flag is published.
__device__ __forceinline__ void gridbarA(int* flags, int ep){
  __syncthreads();   // emits s_waitcnt vmcnt(0) per wave before s_barrier -> release
  if (threadIdx.x == 0)
    __hip_atomic_store(flags + blockIdx.x, ep, __ATOMIC_RELAXED, __HIP_MEMORY_SCOPE_AGENT);
  if (threadIdx.x < NB){
    while (__hip_atomic_load(flags + threadIdx.x, __ATOMIC_RELAXED, __HIP_MEMORY_SCOPE_AGENT) < ep) {}
  }
  __syncthreads();
}

// ---- transpose + fp32->bf16; optional dest-row permute r=d*4+g (for 2048-col gate mats) ---
__global__ __launch_bounds__(256) void k_cvtT(const float* __restrict__ src, int C,
                                              ushort_t* __restrict__ dst, int ldd, int perm){
  __shared__ float tile[32][33];
  int c0 = blockIdx.x*32, r0 = blockIdx.y*32;
  int tx = threadIdx.x & 31, ty = threadIdx.x >> 5;
  #pragma unroll
  for (int i=0;i<4;i++){ int r = ty + i*8; tile[r][tx] = src[(size_t)(r0+r)*C + c0+tx]; }
  __syncthreads();
  #pragma unroll
  for (int i=0;i<4;i++){
    int c = ty + i*8;
    int row = c0 + c;
    if (perm) row = ((row & 511) << 2) | (row >> 9);   // g*512+d -> d*4+g
    dst[(size_t)row*ldd + r0+tx] = f2bu(tile[tx][c]);
  }
}

// ---- elementwise fp32 -> bf16 -------------------------------------------------------------
__global__ __launch_bounds__(256) void k_cvt4(const float* __restrict__ src,
                                              ushort_t* __restrict__ dst, int n4){
  int i = blockIdx.x*256 + threadIdx.x;
  if (i < n4){
    float4 v = ((const float4*)src)[i];
    ushort4v o; o.x=f2bu(v.x); o.y=f2bu(v.y); o.z=f2bu(v.z); o.w=f2bu(v.w);
    ((ushort4v*)dst)[i] = o;
  }
}

// ---- misc: int outputs, declen, biases, zero barrier flags --------------------------------
__global__ __launch_bounds__(256) void k_misc(const int* __restrict__ cap, const int* __restrict__ lens,
                      const float* __restrict__ bdec, const float* __restrict__ bfb,
                      const float* __restrict__ bih, const float* __restrict__ bhh,
                      float* out_cap, float* out_dl, int* declen,
                      float* xbias, float* bihR, int* flags){
  int tid = blockIdx.x*256 + threadIdx.x;
  if (tid < 128) flags[tid] = 0;
  if (tid < 32*52) out_cap[tid] = (float)cap[tid];
  if (tid < 32){ int dl = lens[tid]-1; out_dl[tid] = (float)dl; declen[tid] = dl; }
  if (tid < 768) xbias[tid] = (tid<512) ? bdec[tid] : bfb[tid-512];
  if (tid < 2048){
    int c = (tid&3)*512 + (tid>>2);   // reordered col r=d*4+g <- original c=g*512+d
    bihR[tid] = bih[c] + bhh[c];      // bhh folded in
  }
}

// ---- init: mean_enc -> h0 (bf16), c0 (fp32) -----------------------------------------------
__global__ __launch_bounds__(256) void k_init(const float* __restrict__ enc,
                     const float* __restrict__ Wih_, const float* __restrict__ bih_,
                     const float* __restrict__ Wic_, const float* __restrict__ bic_,
                     ushort_t* __restrict__ hnewb, float* __restrict__ cbuf){
  int b = blockIdx.x, tid = threadIdx.x;
  __shared__ float mean_s[256];
  const float* eb = enc + (size_t)b*196*256;
  float s = 0.f;
  for (int p=0;p<196;p++) s += eb[p*256 + tid];
  mean_s[tid] = s * (1.f/196.f);
  __syncthreads();
  float h0=0.f,h1=0.f,c0=0.f,c1=0.f;
  for (int k=0;k<256;k++){
    float m = mean_s[k];
    h0 += m*Wih_[k*512+tid];      h1 += m*Wih_[k*512+tid+256];
    c0 += m*Wic_[k*512+tid];      c1 += m*Wic_[k*512+tid+256];
  }
  hnewb[b*512+tid]     = f2bu(h0 + bih_[tid]);
  hnewb[b*512+tid+256] = f2bu(h1 + bih_[tid+256]);
  cbuf[b*512+tid]      = c0 + bic_[tid];
  cbuf[b*512+tid+256]  = c1 + bic_[tid+256];
}

// ---- gather embedding rows -> bf16 --------------------------------------------------------
__global__ __launch_bounds__(256) void k_gather(const int* __restrict__ cap,
                                                const float* __restrict__ emb,
                                                ushort_t* __restrict__ erowsb){
  int row = blockIdx.x; int b = row/51, t = row%51;
  int tok = cap[b*52 + t];
  const float* src = emb + (size_t)tok*512;
  ushort_t* dst = erowsb + (size_t)row*512;
  dst[threadIdx.x]       = f2bu(src[threadIdx.x]);
  dst[threadIdx.x + 256] = f2bu(src[threadIdx.x + 256]);
}

// ---- generic bf16 MFMA GEMM (128x128 tile); optional XCD-aware flat mapping ---------------
#define LDT 40
__global__ __launch_bounds__(256)
void k_gemm(const ushort_t* __restrict__ Ag, int lda,
            const ushort_t* __restrict__ Bg, int ldb,
            int Mrows, int Ncols, int K,
            const float* __restrict__ bias,
            float* __restrict__ outF, ushort_t* __restrict__ outH, int ldo,
            const int* __restrict__ declen,
            int Mtiles, int Ntiles, int xcdswz)
{
  __shared__ ushort_t As[128*LDT];
  __shared__ ushort_t Bs[128*LDT];
  int m0, n0;
  if (xcdswz){
    int l = blockIdx.x; int xcd = l & 7; int i = l >> 3;
    int mt = i % Mtiles; int ns = i / Mtiles;
    int nt = ns*8 + xcd;
    if (nt >= Ntiles) return;
    m0 = mt*128; n0 = nt*128;
  } else {
    m0 = blockIdx.y*128; n0 = blockIdx.x*128;
  }
  int tid = threadIdx.x;
  int wave = tid>>6, lane = tid&63;
  int wm = wave>>1, wn = wave&1;
  int q = lane>>4, r = lane&15;
  f32x4 acc[4][4];
  f32x4 zero4 = {0.f,0.f,0.f,0.f};
  #pragma unroll
  for(int i=0;i<4;i++){ acc[i][0]=zero4; acc[i][1]=zero4; acc[i][2]=zero4; acc[i][3]=zero4; }

  for (int k0=0; k0<K; k0+=32){
    __syncthreads();
    #pragma unroll
    for (int c=tid; c<512; c+=256){
      int row = c>>2, ko = (c&3)*8;
      ushort8 v = {0,0,0,0,0,0,0,0};
      if (m0+row < Mrows) v = *(const ushort8*)(Ag + (size_t)(m0+row)*lda + k0 + ko);
      *(ushort8*)(As + row*LDT + ko) = v;
      ushort8 wv = {0,0,0,0,0,0,0,0};
      if (n0+row < Ncols) wv = *(const ushort8*)(Bg + (size_t)(n0+row)*ldb + k0 + ko);
      *(ushort8*)(Bs + row*LDT + ko) = wv;
    }
    __syncthreads();
    FragU a[4], bb[4];
    #pragma unroll
    for(int i=0;i<4;i++){
      a[i].u  = *(const ushort8*)(As + (64*wm + 16*i + r)*LDT + 8*q);
      bb[i].u = *(const ushort8*)(Bs + (64*wn + 16*i + r)*LDT + 8*q);
    }
    #pragma unroll
    for(int i=0;i<4;i++)
      #pragma unroll
      for(int j=0;j<4;j++)
        acc[i][j] = __builtin_amdgcn_mfma_f32_16x16x32_bf16(a[i].b, bb[j].b, acc[i][j], 0,0,0);
  }
  #pragma unroll
  for(int i=0;i<4;i++){
    int rowbase = m0 + 64*wm + 16*i + q*4;
    #pragma unroll
    for(int j=0;j<4;j++){
      int col = n0 + 64*wn + 16*j + r;
      if (col >= Ncols) continue;
      float bv = bias ? bias[col] : 0.f;
      #pragma unroll
      for(int rr=0;rr<4;rr++){
        int row = rowbase + rr;
        if (row >= Mrows) continue;
        float v = acc[i][j][rr] + bv;
        if (declen){ int tt = row % 51; int b = row / 51; if (tt >= declen[b]) v = 0.f; }
        if (outF) outF[(size_t)row*ldo + col] = v;
        else      outH[(size_t)row*ldo + col] = f2bu(v);
      }
    }
  }
}

// ---- 32x32 MFMA tile, A loaded COHERENTLY (LLC): C = A(32xK,packed) @ B(32xK)^T -----------
template<int K>
__device__ __forceinline__ f32x4 tile32c(const ushort_t* __restrict__ Ag,
                                         const ushort_t* __restrict__ Bg, int ldb,
                                         ushort_t* As, ushort_t* Bs){
  const int KW = K/8, LDS = K+8;
  int tid = threadIdx.x, wave = tid>>6, lane = tid&63;
  int q = lane>>4, r = lane&15;
  int wm = (wave>>1)*16, wn = (wave&1)*16;
  // A: coherent 8B loads (hnewb/xaweb change every step; must come from LLC)
  const u64_t* A8 = (const u64_t*)Ag;
  for (int i=tid; i<32*(K/4); i+=256){
    u64_t v = coh_ld64(A8 + i);
    int row = i/(K/4), ko = (i%(K/4))*4;
    *(u64_t*)(As + row*LDS + ko) = v;
  }
  // B: plain vector loads (weights, L2-resident across all steps)
  for (int i=tid; i<32*KW; i+=256){
    int row = i/KW, ko = (i%KW)*8;
    *(ushort8*)(Bs + row*LDS + ko) = *(const ushort8*)(Bg + (size_t)row*ldb + ko);
  }
  __syncthreads();
  f32x4 acc = {0.f,0.f,0.f,0.f};
  #pragma unroll
  for (int kc=0; kc<K; kc+=32){
    FragU a, b;
    a.u = *(const ushort8*)(As + (wm + r)*LDS + kc + 8*q);
    b.u = *(const ushort8*)(Bs + (wn + r)*LDS + kc + 8*q);
    acc = __builtin_amdgcn_mfma_f32_16x16x32_bf16(a.b, b.b, acc, 0,0,0);
  }
  return acc;
}

// ---- persistent fused step loop: 88 blocks ------------------------------------------------
__global__ __launch_bounds__(256)
void k_steps(const ushort_t* __restrict__ XWT768, const ushort_t* __restrict__ WHCp,
             const float* __restrict__ xbias,
             const ushort_t* __restrict__ att1b, const float* __restrict__ wfull,
             const ushort_t* __restrict__ encb, const ushort_t* __restrict__ eihR,
             const int* __restrict__ declen,
             ushort_t* __restrict__ hnewb, float* __restrict__ cbuf,
             float* __restrict__ XO,
             ushort_t* __restrict__ xaweb, ushort_t* __restrict__ hallb,
             float* __restrict__ out_alph, int* flags)
{
  int blk = blockIdx.x, tid = threadIdx.x;
  int wave = tid>>6, lane = tid&63;
  int q = lane>>4, r = lane&15;
  int wm = (wave>>1)*16, wn = (wave&1)*16;
  __shared__ ushort_t As[32*520];
  __shared__ ushort_t Bs[32*520];
  __shared__ float gl[32][32];

  int ep = 0;
  for (int t=0; t<51; t++){
    // ---------- phase A: XO = h@[Wdec|Wfb]+b (24 blks); accGH = h@Whh^T slice (64, regs) ---
    f32x4 accGH = {0.f,0.f,0.f,0.f};
    if (blk < 24){
      int n0 = blk*32;
      f32x4 acc = tile32c<512>(hnewb, XWT768 + (size_t)n0*512, 512, As, Bs);
      int col = n0 + wn + r;
      float bv = xbias[col];
      #pragma unroll
      for (int rr=0;rr<4;rr++)
        coh_stf(XO + (size_t)(wm + 4*q + rr)*768 + col, acc[rr] + bv);
    } else {
      int n0 = (blk-24)*32;
      accGH = tile32c<512>(hnewb, WHCp + (size_t)n0*768, 768, As, Bs);
      // stays in registers; consumed in phase C by THIS block (same cols)
    }
    gridbarA(flags, ++ep);

    // ---------- phase B: attention + softmax + awe + gate (32 blocks, one per batch) -------
    if (blk < 32){
      int b = blk;
      float* att2_s  = (float*)As;           // 512
      float* wf_s    = att2_s + 512;         // 512
      float* alpha_s = wf_s + 512;           // 196
      float* red_s   = alpha_s + 200;        // 40
      const float* xo = XO + (size_t)b*768;
      for (int i=tid;i<512;i+=256){ att2_s[i] = coh_ldf(xo + i); wf_s[i] = wfull[i]; }
      __syncthreads();
      float av = -1e30f;
      if (tid < 196){
        const ushort_t* arow = att1b + ((size_t)b*196 + tid)*512;
        float s0=0.f,s1=0.f,s2=0.f,s3=0.f;   // 4 accumulators: break serial FMA chain
        for (int k=0;k<512;k+=8){
          ushort8 v = *(const ushort8*)(arow + k);
          s0 += fmaxf(bu2f(v[0]) + att2_s[k+0], 0.f)*wf_s[k+0];
          s1 += fmaxf(bu2f(v[1]) + att2_s[k+1], 0.f)*wf_s[k+1];
          s2 += fmaxf(bu2f(v[2]) + att2_s[k+2], 0.f)*wf_s[k+2];
          s3 += fmaxf(bu2f(v[3]) + att2_s[k+3], 0.f)*wf_s[k+3];
          s0 += fmaxf(bu2f(v[4]) + att2_s[k+4], 0.f)*wf_s[k+4];
          s1 += fmaxf(bu2f(v[5]) + att2_s[k+5], 0.f)*wf_s[k+5];
          s2 += fmaxf(bu2f(v[6]) + att2_s[k+6], 0.f)*wf_s[k+6];
          s3 += fmaxf(bu2f(v[7]) + att2_s[k+7], 0.f)*wf_s[k+7];
        }
        av = (s0+s1)+(s2+s3);
      }
      float m = av;
      #pragma unroll
      for (int off=32;off>0;off>>=1) m = fmaxf(m, __shfl_down(m, off, 64));
      if ((tid&63)==0) red_s[tid>>6] = m;
      __syncthreads();
      if (tid==0) red_s[16] = fmaxf(fmaxf(red_s[0],red_s[1]), fmaxf(red_s[2],red_s[3]));
      __syncthreads();
      float gmax = red_s[16];
      float ev = (tid<196) ? __expf(av - gmax) : 0.f;
      float ssum = ev;
      #pragma unroll
      for (int off=32;off>0;off>>=1) ssum += __shfl_down(ssum, off, 64);
      if ((tid&63)==0) red_s[20+(tid>>6)] = ssum;
      __syncthreads();
      if (tid==0) red_s[17] = red_s[20]+red_s[21]+red_s[22]+red_s[23];
      __syncthreads();
      float inv = 1.f/red_s[17];
      int mask = (t < declen[b]) ? 1 : 0;
      if (tid<196){
        float al = ev*inv;
        alpha_s[tid] = al;
        out_alph[((size_t)b*51 + t)*196 + tid] = mask ? al : 0.f;
      }
      __syncthreads();
      const ushort_t* eb = encb + (size_t)b*196*256;
      float aw0 = 0.f, aw1 = 0.f;
      for (int p=0;p<196;p+=2){
        aw0 += alpha_s[p]  *bu2f(eb[(size_t)p*256 + tid]);
        aw1 += alpha_s[p+1]*bu2f(eb[(size_t)(p+1)*256 + tid]);
      }
      float gate = sigm(coh_ldf(xo + 512 + tid));
      // stage bf16 result in LDS (Bs is free in phase B), pack to 8B coherent stores
      ((ushort_t*)Bs)[tid] = f2bu(gate*(aw0+aw1));
      __syncthreads();
      if (tid < 64){
        u64_t v = *(const u64_t*)((const ushort_t*)Bs + tid*4);
        coh_st64((u64_t*)(xaweb + (size_t)b*256) + tid, v);
      }
    }
    gridbarA(flags, ++ep);

    // ---------- phase C: gates = accGH + xawe@WihBot^T(reord) + eihR; LSTM (blocks 24-87) --
    if (blk >= 24){
      int n0 = (blk-24)*32;
      f32x4 acc2 = tile32c<256>(xaweb, WHCp + (size_t)n0*768 + 512, 768, As, Bs);
      int col = n0 + wn + r;
      #pragma unroll
      for (int rr=0;rr<4;rr++){
        int row = wm + 4*q + rr;
        gl[row][wn + r] = accGH[rr] + acc2[rr]
                        + bu2f(eihR[((size_t)row*51 + t)*2048 + col]);
      }
      __syncthreads();
      int b = tid>>3, dd = tid&7;
      int d = (n0>>2) + dd;
      float gi = gl[b][dd*4+0], gf = gl[b][dd*4+1], gg = gl[b][dd*4+2], go = gl[b][dd*4+3];
      float cold = cbuf[b*512 + d];
      float cnew = sigm(gf)*cold + sigm(gi)*ftanh(gg);
      float hnew = sigm(go)*ftanh(cnew);
      hallb[((size_t)b*51 + t)*512 + d] = f2bu(hnew);        // plain: read by later kernel
      if (t < declen[b]) cbuf[b*512 + d] = cnew;             // plain: block-private
      // stage hnew bf16 in LDS (As free now), pack to 8B coherent stores of hnewb
      ((ushort_t*)As)[tid] = f2bu(hnew);                     // [b][dd]
      __syncthreads();
      if (tid < 64){
        int bb = tid>>1, half = tid&1;
        if (t < declen[bb]){
          u64_t v = *(const u64_t*)((const ushort_t*)As + bb*8 + half*4);
          coh_st64((u64_t*)(hnewb + (size_t)bb*512 + (n0>>2)) + half, v);
        }
      }
    }
    gridbarA(flags, ++ep);
  }
}

// -------------------------------------------------------------------------------------------
extern "C" void kernel_launch(void* const* d_in, const int* in_sizes, int n_in,
                              void* d_out, int out_size, void* d_ws, size_t ws_size,
                              hipStream_t stream)
{
  const float* enc   = (const float*)d_in[0];
  const int*   cap   = (const int*)d_in[1];
  const int*   lens  = (const int*)d_in[2];
  const float* Wenc  = (const float*)d_in[3];
  const float* benc  = (const float*)d_in[4];
  const float* Wdec  = (const float*)d_in[5];
  const float* bdec  = (const float*)d_in[6];
  const float* Wfull = (const float*)d_in[7];
  // d_in[8] = b_full_att: softmax-invariant, skipped
  const float* emb   = (const float*)d_in[9];
  const float* Wih   = (const float*)d_in[10];
  const float* bih   = (const float*)d_in[11];
  const float* Whh   = (const float*)d_in[12];
  const float* bhh   = (const float*)d_in[13];
  const float* Winh  = (const float*)d_in[14];
  const float* binh  = (const float*)d_in[15];
  const float* Winc  = (const float*)d_in[16];
  const float* binc  = (const float*)d_in[17];
  const float* Wfb   = (const float*)d_in[18];
  const float* bfb   = (const float*)d_in[19];
  const float* Wfc   = (const float*)d_in[20];
  const float* bfc   = (const float*)d_in[21];
  float* out = (float*)d_out;

  char* w = (char*)d_ws;
  size_t off = 0;
  auto alloc = [&](size_t bytes)->char*{ char* p = w + off; off += (bytes + 255) & ~(size_t)255; return p; };
  ushort_t* WfcT    = (ushort_t*)alloc(20000ull*512*2);  // [20000][512]
  ushort_t* WHCp    = (ushort_t*)alloc(2048ull*768*2);   // rows r=d*4+g; k: [Whh^T | WihBot^T]
  ushort_t* WihTopTp= (ushort_t*)alloc(2048ull*512*2);   // rows r=d*4+g
  ushort_t* XWT768  = (ushort_t*)alloc(768ull*512*2);    // [Wdec^T ; Wfb^T]
  ushort_t* WencT   = (ushort_t*)alloc(512ull*256*2);
  ushort_t* encb    = (ushort_t*)alloc(32ull*196*256*2);
  ushort_t* erowsb  = (ushort_t*)alloc(1632ull*512*2);
  ushort_t* att1b   = (ushort_t*)alloc(6272ull*512*2);
  ushort_t* eihR    = (ushort_t*)alloc(1632ull*2048*2);  // cols r=d*4+g, incl. b_ih + b_hh
  ushort_t* hallb   = (ushort_t*)alloc(1632ull*512*2);
  ushort_t* hnewb   = (ushort_t*)alloc(32ull*512*2);
  ushort_t* xaweb   = (ushort_t*)alloc(32ull*256*2);
  float*    XO      = (float*)alloc(32ull*768*4);
  float*    cbuf    = (float*)alloc(32ull*512*4);
  float*    xbias   = (float*)alloc(768*4);
  float*    bihR    = (float*)alloc(2048*4);
  int*      declen  = (int*)alloc(32*4);
  int*      flags   = (int*)alloc(512);                  // 128 ints, per-block arrival epochs

  float* out_preds = out;                        // 32*51*20000
  float* out_cap   = out + 32640000ull;          // 32*52
  float* out_dl    = out_cap + 1664;             // 32
  float* out_alph  = out_dl + 32;                // 32*51*196

  // ---- preamble ----
  k_cvtT<<<dim3(625,16),256,0,stream>>>(Wfc, 20000, WfcT, 512, 0);
  k_cvtT<<<dim3(64,16), 256,0,stream>>>(Whh, 2048, WHCp, 768, 1);                     // k 0..511
  k_cvtT<<<dim3(64,8),  256,0,stream>>>(Wih + 512ull*2048, 2048, WHCp + 512, 768, 1); // k 512..767
  k_cvtT<<<dim3(64,16), 256,0,stream>>>(Wih, 2048, WihTopTp, 512, 1);
  k_cvtT<<<dim3(16,16), 256,0,stream>>>(Wdec, 512, XWT768, 512, 0);
  k_cvtT<<<dim3(8,16),  256,0,stream>>>(Wfb, 256, XWT768 + 512ull*512, 512, 0);
  k_cvtT<<<dim3(16,8),  256,0,stream>>>(Wenc, 512, WencT, 256, 0);
  k_cvt4<<<1568,256,0,stream>>>(enc, encb, 401408);
  k_misc<<<8,256,0,stream>>>(cap, lens, bdec, bfb, bih, bhh, out_cap, out_dl, declen,
                             xbias, bihR, flags);
  k_init<<<32,256,0,stream>>>(enc, Winh, binh, Winc, binc, hnewb, cbuf);
  k_gather<<<1632,256,0,stream>>>(cap, emb, erowsb);
  // att1b = encb @ WencT^T + benc  (6272 x 512, K=256) -> bf16
  k_gemm<<<dim3(4,49),256,0,stream>>>(encb, 256, WencT, 256, 6272, 512, 256,
                                      benc, nullptr, att1b, 512, nullptr, 0,0,0);
  // eihR = erowsb @ WihTopTp^T + (bih+bhh reordered)  (1632 x 2048(reord), K=512) -> bf16
  k_gemm<<<dim3(16,13),256,0,stream>>>(erowsb, 512, WihTopTp, 512, 1632, 2048, 512,
                                       bihR, nullptr, eihR, 2048, nullptr, 0,0,0);

  // ---- fused 51-step recurrence: ONE launch ----
  k_steps<<<NB,256,0,stream>>>(XWT768, WHCp, xbias, att1b, Wfull, encb, eihR, declen,
                               hnewb, cbuf, XO, xaweb, hallb, out_alph, flags);

  // ---- preds = hallb @ WfcT^T + bfc (masked). M=1632, N=20000, K=512; XCD-aware mapping ---
  k_gemm<<<2080,256,0,stream>>>(hallb, 512, WfcT, 512, 1632, 20000, 512,
                                bfc, out_preds, nullptr, 20000, declen, 13, 157, 1);
}

// Round 3
// 1798.383 us; speedup vs baseline: 1.3308x; 1.0750x over previous
//
#include <hip/hip_runtime.h>
#include <hip/hip_bf16.h>
#include <math.h>
#include <stddef.h>

// B=32, P=196, E=256, A=512, M=512, D=512, V=20000, L=52, T=51
// fp32 in/out. Step loop fused into ONE persistent kernel.
// R3: 64-block role-split pipeline with partial producer-only barriers.
//   front blocks 0-31 (b=blk): [0-23] XO = h@[Wdec|Wfb]+b -> flagA; all: attention -> flagB
//   back  blocks 32-63 (64 gate-cols): h@Whh (OVERLAPPED with XO+attention, off the
//   critical path) -> wait flagB -> xawe@WihBot + eihR + LSTM -> flagC
//   Weights live in LDS persistently (staged once). eihR prefetched into regs
//   before the top-of-step wait. All inter-phase buffers via agent-scope relaxed
//   atomics (LLC-coherent, no fences, per-XCD L2 stays warm with att1b/encb).

typedef unsigned short ushort_t;
typedef __bf16 bf16x8 __attribute__((ext_vector_type(8)));
typedef float f32x4 __attribute__((ext_vector_type(4)));
typedef unsigned short ushort8 __attribute__((ext_vector_type(8)));
typedef unsigned short ushort4v __attribute__((ext_vector_type(4)));
typedef unsigned long long u64_t;

union FragU { ushort8 u; bf16x8 b; };

__device__ __forceinline__ unsigned short f2bu(float f){
  union { float f; unsigned int i; } c; c.f = f;
  unsigned int x = c.i;
  unsigned int r = x + 0x7fffu + ((x >> 16) & 1u);
  return (unsigned short)(r >> 16);
}
__device__ __forceinline__ float bu2f(unsigned short u){
  union { unsigned int i; float f; } c; c.i = ((unsigned int)u) << 16; return c.f;
}
__device__ __forceinline__ float sigm(float x){ return 1.f/(1.f+__expf(-x)); }
__device__ __forceinline__ float ftanh(float x){ float e = __expf(2.f*x); return 1.f - 2.f/(e+1.f); }

// coherent (LLC) access helpers: agent-scope relaxed atomics bypass the
// non-coherent per-XCD L2. __syncthreads() drains each wave's vmcnt, so
// "stores ... syncthreads ... flag store" is a complete release.
__device__ __forceinline__ u64_t coh_ld64(const u64_t* p){
  return __hip_atomic_load(p, __ATOMIC_RELAXED, __HIP_MEMORY_SCOPE_AGENT);
}
__device__ __forceinline__ void coh_st64(u64_t* p, u64_t v){
  __hip_atomic_store(p, v, __ATOMIC_RELAXED, __HIP_MEMORY_SCOPE_AGENT);
}
__device__ __forceinline__ float coh_ldf(const float* p){
  return __hip_atomic_load(p, __ATOMIC_RELAXED, __HIP_MEMORY_SCOPE_AGENT);
}
__device__ __forceinline__ void coh_stf(float* p, float v){
  __hip_atomic_store(p, v, __ATOMIC_RELAXED, __HIP_MEMORY_SCOPE_AGENT);
}
__device__ __forceinline__ int coh_ldi(const int* p){
  return __hip_atomic_load(p, __ATOMIC_RELAXED, __HIP_MEMORY_SCOPE_AGENT);
}
__device__ __forceinline__ void coh_sti(int* p, int v){
  __hip_atomic_store(p, v, __ATOMIC_RELAXED, __HIP_MEMORY_SCOPE_AGENT);
}

// ---- transpose + fp32->bf16; optional dest-row permute r=d*4+g (for 2048-col gate mats) ---
__global__ __launch_bounds__(256) void k_cvtT(const float* __restrict__ src, int C,
                                              ushort_t* __restrict__ dst, int ldd, int perm){
  __shared__ float tile[32][33];
  int c0 = blockIdx.x*32, r0 = blockIdx.y*32;
  int tx = threadIdx.x & 31, ty = threadIdx.x >> 5;
  #pragma unroll
  for (int i=0;i<4;i++){ int r = ty + i*8; tile[r][tx] = src[(size_t)(r0+r)*C + c0+tx]; }
  __syncthreads();
  #pragma unroll
  for (int i=0;i<4;i++){
    int c = ty + i*8;
    int row = c0 + c;
    if (perm) row = ((row & 511) << 2) | (row >> 9);   // g*512+d -> d*4+g
    dst[(size_t)row*ldd + r0+tx] = f2bu(tile[tx][c]);
  }
}

// ---- elementwise fp32 -> bf16 -------------------------------------------------------------
__global__ __launch_bounds__(256) void k_cvt4(const float* __restrict__ src,
                                              ushort_t* __restrict__ dst, int n4){
  int i = blockIdx.x*256 + threadIdx.x;
  if (i < n4){
    float4 v = ((const float4*)src)[i];
    ushort4v o; o.x=f2bu(v.x); o.y=f2bu(v.y); o.z=f2bu(v.z); o.w=f2bu(v.w);
    ((ushort4v*)dst)[i] = o;
  }
}

// ---- misc: int outputs, declen, biases, zero barrier flags --------------------------------
__global__ __launch_bounds__(256) void k_misc(const int* __restrict__ cap, const int* __restrict__ lens,
                      const float* __restrict__ bdec, const float* __restrict__ bfb,
                      const float* __restrict__ bih, const float* __restrict__ bhh,
                      float* out_cap, float* out_dl, int* declen,
                      float* xbias, float* bihR, int* flags){
  int tid = blockIdx.x*256 + threadIdx.x;
  if (tid < 128) flags[tid] = 0;
  if (tid < 32*52) out_cap[tid] = (float)cap[tid];
  if (tid < 32){ int dl = lens[tid]-1; out_dl[tid] = (float)dl; declen[tid] = dl; }
  if (tid < 768) xbias[tid] = (tid<512) ? bdec[tid] : bfb[tid-512];
  if (tid < 2048){
    int c = (tid&3)*512 + (tid>>2);   // reordered col r=d*4+g <- original c=g*512+d
    bihR[tid] = bih[c] + bhh[c];      // bhh folded in
  }
}

// ---- init: mean_enc -> h0 (bf16), c0 (fp32) -----------------------------------------------
__global__ __launch_bounds__(256) void k_init(const float* __restrict__ enc,
                     const float* __restrict__ Wih_, const float* __restrict__ bih_,
                     const float* __restrict__ Wic_, const float* __restrict__ bic_,
                     ushort_t* __restrict__ hnewb, float* __restrict__ cbuf){
  int b = blockIdx.x, tid = threadIdx.x;
  __shared__ float mean_s[256];
  const float* eb = enc + (size_t)b*196*256;
  float s = 0.f;
  for (int p=0;p<196;p++) s += eb[p*256 + tid];
  mean_s[tid] = s * (1.f/196.f);
  __syncthreads();
  float h0=0.f,h1=0.f,c0=0.f,c1=0.f;
  for (int k=0;k<256;k++){
    float m = mean_s[k];
    h0 += m*Wih_[k*512+tid];      h1 += m*Wih_[k*512+tid+256];
    c0 += m*Wic_[k*512+tid];      c1 += m*Wic_[k*512+tid+256];
  }
  hnewb[b*512+tid]     = f2bu(h0 + bih_[tid]);
  hnewb[b*512+tid+256] = f2bu(h1 + bih_[tid+256]);
  cbuf[b*512+tid]      = c0 + bic_[tid];
  cbuf[b*512+tid+256]  = c1 + bic_[tid+256];
}

// ---- gather embedding rows -> bf16 --------------------------------------------------------
__global__ __launch_bounds__(256) void k_gather(const int* __restrict__ cap,
                                                const float* __restrict__ emb,
                                                ushort_t* __restrict__ erowsb){
  int row = blockIdx.x; int b = row/51, t = row%51;
  int tok = cap[b*52 + t];
  const float* src = emb + (size_t)tok*512;
  ushort_t* dst = erowsb + (size_t)row*512;
  dst[threadIdx.x]       = f2bu(src[threadIdx.x]);
  dst[threadIdx.x + 256] = f2bu(src[threadIdx.x + 256]);
}

// ---- generic bf16 MFMA GEMM (128x128 tile); optional XCD-aware flat mapping ---------------
#define LDT 40
__global__ __launch_bounds__(256)
void k_gemm(const ushort_t* __restrict__ Ag, int lda,
            const ushort_t* __restrict__ Bg, int ldb,
            int Mrows, int Ncols, int K,
            const float* __restrict__ bias,
            float* __restrict__ outF, ushort_t* __restrict__ outH, int ldo,
            const int* __restrict__ declen,
            int Mtiles, int Ntiles, int xcdswz)
{
  __shared__ ushort_t As[128*LDT];
  __shared__ ushort_t Bs[128*LDT];
  int m0, n0;
  if (xcdswz){
    int l = blockIdx.x; int xcd = l & 7; int i = l >> 3;
    int mt = i % Mtiles; int ns = i / Mtiles;
    int nt = ns*8 + xcd;
    if (nt >= Ntiles) return;
    m0 = mt*128; n0 = nt*128;
  } else {
    m0 = blockIdx.y*128; n0 = blockIdx.x*128;
  }
  int tid = threadIdx.x;
  int wave = tid>>6, lane = tid&63;
  int wm = wave>>1, wn = wave&1;
  int q = lane>>4, r = lane&15;
  f32x4 acc[4][4];
  f32x4 zero4 = {0.f,0.f,0.f,0.f};
  #pragma unroll
  for(int i=0;i<4;i++){ acc[i][0]=zero4; acc[i][1]=zero4; acc[i][2]=zero4; acc[i][3]=zero4; }

  for (int k0=0; k0<K; k0+=32){
    __syncthreads();
    #pragma unroll
    for (int c=tid; c<512; c+=256){
      int row = c>>2, ko = (c&3)*8;
      ushort8 v = {0,0,0,0,0,0,0,0};
      if (m0+row < Mrows) v = *(const ushort8*)(Ag + (size_t)(m0+row)*lda + k0 + ko);
      *(ushort8*)(As + row*LDT + ko) = v;
      ushort8 wv = {0,0,0,0,0,0,0,0};
      if (n0+row < Ncols) wv = *(const ushort8*)(Bg + (size_t)(n0+row)*ldb + k0 + ko);
      *(ushort8*)(Bs + row*LDT + ko) = wv;
    }
    __syncthreads();
    FragU a[4], bb[4];
    #pragma unroll
    for(int i=0;i<4;i++){
      a[i].u  = *(const ushort8*)(As + (64*wm + 16*i + r)*LDT + 8*q);
      bb[i].u = *(const ushort8*)(Bs + (64*wn + 16*i + r)*LDT + 8*q);
    }
    #pragma unroll
    for(int i=0;i<4;i++)
      #pragma unroll
      for(int j=0;j<4;j++)
        acc[i][j] = __builtin_amdgcn_mfma_f32_16x16x32_bf16(a[i].b, bb[j].b, acc[i][j], 0,0,0);
  }
  #pragma unroll
  for(int i=0;i<4;i++){
    int rowbase = m0 + 64*wm + 16*i + q*4;
    #pragma unroll
    for(int j=0;j<4;j++){
      int col = n0 + 64*wn + 16*j + r;
      if (col >= Ncols) continue;
      float bv = bias ? bias[col] : 0.f;
      #pragma unroll
      for(int rr=0;rr<4;rr++){
        int row = rowbase + rr;
        if (row >= Mrows) continue;
        float v = acc[i][j][rr] + bv;
        if (declen){ int tt = row % 51; int b = row / 51; if (tt >= declen[b]) v = 0.f; }
        if (outF) outF[(size_t)row*ldo + col] = v;
        else      outH[(size_t)row*ldo + col] = f2bu(v);
      }
    }
  }
}

// ---- persistent fused step loop: 64 blocks, role-split ------------------------------------
__global__ __launch_bounds__(256)
void k_steps(const ushort_t* __restrict__ XWT768, const ushort_t* __restrict__ WHCp,
             const float* __restrict__ xbias,
             const ushort_t* __restrict__ att1b, const float* __restrict__ wfull,
             const ushort_t* __restrict__ encb, const ushort_t* __restrict__ eihR,
             const int* __restrict__ declen,
             ushort_t* __restrict__ hnewb, float* __restrict__ cbuf,
             float* __restrict__ XO,
             ushort_t* __restrict__ xaweb, ushort_t* __restrict__ hallb,
             float* __restrict__ out_alph, int* flags)
{
  int blk = blockIdx.x, tid = threadIdx.x;
  int wave = tid>>6, lane = tid&63;
  int q = lane>>4, r = lane&15;
  int wm = (wave>>1)*16, wn = (wave&1)*16;

  __shared__ ushort_t Wa[64*520];   // persistent: front XWT slice (32 rows) / back Whh^T slice (64 rows)
  __shared__ ushort_t Wc[64*264];   // persistent: back WihBot^T slice; front: wf (f32, 512) in first 2KB
  __shared__ ushort_t As[32*520];   // per-phase activation staging
  __shared__ float    scr[2048];    // back: gl[32][64]; front: att scratch

  const bool front = (blk < 32);
  const int n0f = blk*32;           // front A_xo col base (blk<24)
  const int n0b = (blk-32)*64;      // back gate-col base

  // ---- stage persistent weights (once) ----
  if (front){
    if (blk < 24){
      const ushort_t* src = XWT768 + (size_t)n0f*512;
      for (int i=tid; i<32*64; i+=256){
        int row=i>>6, ko=(i&63)*8;
        *(ushort8*)(Wa + row*520 + ko) = *(const ushort8*)(src + (size_t)row*512 + ko);
      }
    }
    float* wfp = (float*)Wc;
    for (int i=tid;i<512;i+=256) wfp[i] = wfull[i];
  } else {
    for (int i=tid; i<64*64; i+=256){
      int row=i>>6, ko=(i&63)*8;
      *(ushort8*)(Wa + row*520 + ko) = *(const ushort8*)(WHCp + (size_t)(n0b+row)*768 + ko);
    }
    for (int i=tid; i<64*32; i+=256){
      int row=i>>5, ko=(i&31)*8;
      *(ushort8*)(Wc + row*264 + ko) = *(const ushort8*)(WHCp + (size_t)(n0b+row)*768 + 512 + ko);
    }
  }
  __syncthreads();

  for (int t=0; t<51; t++){
    int ep = 3*t;   // flagA=ep+1 (blocks 0-23), flagB=ep+2 (0-31), flagC=ep+3 (32-63)

    if (front){
      // ---------- phase A_xo (blocks 0-23): XO = h@[Wdec|Wfb]+b ----------
      if (blk < 24){
        if (tid < 32) while (coh_ldi(flags+32+tid) < ep) {}   // wait epC(t-1)
        __syncthreads();
        const u64_t* A8 = (const u64_t*)hnewb;
        for (int i=tid; i<32*128; i+=256){
          int row=i>>7, k4=i&127;
          *(u64_t*)(As + row*520 + k4*4) = coh_ld64(A8 + row*64 + k4);
        }
        __syncthreads();
        f32x4 acc = {0.f,0.f,0.f,0.f};
        #pragma unroll
        for (int kc=0; kc<512; kc+=32){
          FragU a,b;
          a.u = *(const ushort8*)(As + (wm + r)*520 + kc + 8*q);
          b.u = *(const ushort8*)(Wa + (wn + r)*520 + kc + 8*q);
          acc = __builtin_amdgcn_mfma_f32_16x16x32_bf16(a.b, b.b, acc, 0,0,0);
        }
        int col = n0f + wn + r;
        float bv = xbias[col];
        #pragma unroll
        for (int rr=0;rr<4;rr++)
          coh_stf(XO + (size_t)(wm + 4*q + rr)*768 + col, acc[rr] + bv);
        __syncthreads();                                      // drain XO stores
        if (tid==0) coh_sti(flags+blk, ep+1);
      }

      // ---------- phase B (blocks 0-31): attention + softmax + awe + gate ----------
      {
        int b = blk;
        float* att2_s  = scr;           // 512
        float* wf_s    = (float*)Wc;    // 512 (persistent)
        float* alpha_s = scr + 1024;    // 196
        float* red_s   = scr + 1224;    // 40
        if (tid < 24) while (coh_ldi(flags+tid) < ep+1) {}    // wait epA
        __syncthreads();
        for (int i=tid;i<512;i+=256) att2_s[i] = coh_ldf(XO + (size_t)b*768 + i);
        __syncthreads();
        float av = -1e30f;
        if (tid < 196){
          const ushort_t* arow = att1b + ((size_t)b*196 + tid)*512;
          float s0=0.f,s1=0.f,s2=0.f,s3=0.f;
          for (int k=0;k<512;k+=8){
            ushort8 v = *(const ushort8*)(arow + k);
            s0 += fmaxf(bu2f(v[0]) + att2_s[k+0], 0.f)*wf_s[k+0];
            s1 += fmaxf(bu2f(v[1]) + att2_s[k+1], 0.f)*wf_s[k+1];
            s2 += fmaxf(bu2f(v[2]) + att2_s[k+2], 0.f)*wf_s[k+2];
            s3 += fmaxf(bu2f(v[3]) + att2_s[k+3], 0.f)*wf_s[k+3];
            s0 += fmaxf(bu2f(v[4]) + att2_s[k+4], 0.f)*wf_s[k+4];
            s1 += fmaxf(bu2f(v[5]) + att2_s[k+5], 0.f)*wf_s[k+5];
            s2 += fmaxf(bu2f(v[6]) + att2_s[k+6], 0.f)*wf_s[k+6];
            s3 += fmaxf(bu2f(v[7]) + att2_s[k+7], 0.f)*wf_s[k+7];
          }
          av = (s0+s1)+(s2+s3);
        }
        float m = av;
        #pragma unroll
        for (int off=32;off>0;off>>=1) m = fmaxf(m, __shfl_down(m, off, 64));
        if ((tid&63)==0) red_s[tid>>6] = m;
        __syncthreads();
        if (tid==0) red_s[16] = fmaxf(fmaxf(red_s[0],red_s[1]), fmaxf(red_s[2],red_s[3]));
        __syncthreads();
        float gmax = red_s[16];
        float ev = (tid<196) ? __expf(av - gmax) : 0.f;
        float ssum = ev;
        #pragma unroll
        for (int off=32;off>0;off>>=1) ssum += __shfl_down(ssum, off, 64);
        if ((tid&63)==0) red_s[20+(tid>>6)] = ssum;
        __syncthreads();
        if (tid==0) red_s[17] = red_s[20]+red_s[21]+red_s[22]+red_s[23];
        __syncthreads();
        float inv = 1.f/red_s[17];
        int mask = (t < declen[b]) ? 1 : 0;
        if (tid<196){
          float al = ev*inv;
          alpha_s[tid] = al;
          out_alph[((size_t)b*51 + t)*196 + tid] = mask ? al : 0.f;
        }
        __syncthreads();
        const ushort_t* eb = encb + (size_t)b*196*256;
        float aw0 = 0.f, aw1 = 0.f;
        for (int p=0;p<196;p+=2){
          aw0 += alpha_s[p]  *bu2f(eb[(size_t)p*256 + tid]);
          aw1 += alpha_s[p+1]*bu2f(eb[(size_t)(p+1)*256 + tid]);
        }
        float gate = sigm(coh_ldf(XO + (size_t)b*768 + 512 + tid));
        ((ushort_t*)As)[tid] = f2bu(gate*(aw0+aw1));
        __syncthreads();
        if (tid < 64){
          u64_t v = *(const u64_t*)((const ushort_t*)As + tid*4);
          coh_st64((u64_t*)(xaweb + (size_t)b*256) + tid, v);
        }
        __syncthreads();                                      // drain xaweb stores
        if (tid==0) coh_sti(flags+blk, ep+2);
      }
    } else {
      // ---------- back blocks: A_whh (overlapped) then phase C ----------
      // prefetch eihR for this step (read-only, no dependency)
      float eih0[4], eih1[4];
      #pragma unroll
      for (int rr=0; rr<4; rr++){
        int row = wm + 4*q + rr;
        eih0[rr] = bu2f(eihR[((size_t)row*51 + t)*2048 + n0b +      wn + r]);
        eih1[rr] = bu2f(eihR[((size_t)row*51 + t)*2048 + n0b + 32 + wn + r]);
      }
      if (tid < 32) while (coh_ldi(flags+32+tid) < ep) {}     // wait epC(t-1)
      __syncthreads();
      // A_whh: accG = h @ Whh^T slice (64 cols), in registers
      const u64_t* A8 = (const u64_t*)hnewb;
      for (int i=tid; i<32*128; i+=256){
        int row=i>>7, k4=i&127;
        *(u64_t*)(As + row*520 + k4*4) = coh_ld64(A8 + row*64 + k4);
      }
      __syncthreads();
      f32x4 g0 = {0.f,0.f,0.f,0.f}, g1 = {0.f,0.f,0.f,0.f};
      #pragma unroll
      for (int kc=0; kc<512; kc+=32){
        FragU a,b0,b1;
        a.u  = *(const ushort8*)(As + (wm + r)*520 + kc + 8*q);
        b0.u = *(const ushort8*)(Wa + (     wn + r)*520 + kc + 8*q);
        b1.u = *(const ushort8*)(Wa + (32 + wn + r)*520 + kc + 8*q);
        g0 = __builtin_amdgcn_mfma_f32_16x16x32_bf16(a.b, b0.b, g0, 0,0,0);
        g1 = __builtin_amdgcn_mfma_f32_16x16x32_bf16(a.b, b1.b, g1, 0,0,0);
      }
      // wait epB (xawe ready)
      if (tid < 32) while (coh_ldi(flags+tid) < ep+2) {}
      __syncthreads();
      // C: acc2 = xawe @ WihBot^T slice (K=256)
      const u64_t* X8 = (const u64_t*)xaweb;
      for (int i=tid; i<32*64; i+=256){
        int row=i>>6, k4=i&63;
        *(u64_t*)(As + row*264 + k4*4) = coh_ld64(X8 + row*32 + k4);
      }
      __syncthreads();
      f32x4 c0 = {0.f,0.f,0.f,0.f}, c1 = {0.f,0.f,0.f,0.f};
      #pragma unroll
      for (int kc=0; kc<256; kc+=32){
        FragU a,b0,b1;
        a.u  = *(const ushort8*)(As + (wm + r)*264 + kc + 8*q);
        b0.u = *(const ushort8*)(Wc + (     wn + r)*264 + kc + 8*q);
        b1.u = *(const ushort8*)(Wc + (32 + wn + r)*264 + kc + 8*q);
        c0 = __builtin_amdgcn_mfma_f32_16x16x32_bf16(a.b, b0.b, c0, 0,0,0);
        c1 = __builtin_amdgcn_mfma_f32_16x16x32_bf16(a.b, b1.b, c1, 0,0,0);
      }
      float* gl = scr;   // [32][64]
      #pragma unroll
      for (int rr=0;rr<4;rr++){
        int row = wm + 4*q + rr;
        gl[row*64 +      wn + r] = g0[rr] + c0[rr] + eih0[rr];
        gl[row*64 + 32 + wn + r] = g1[rr] + c1[rr] + eih1[rr];
      }
      __syncthreads();
      // LSTM: 512 (b,d) items, 2 per thread
      ushort_t hloc0, hloc1;
      {
        int it = tid;
        int b = it>>4, dd = it&15, d = (n0b>>2) + dd;
        float gi = gl[b*64 + dd*4+0], gf = gl[b*64 + dd*4+1];
        float gg = gl[b*64 + dd*4+2], go = gl[b*64 + dd*4+3];
        float cold = cbuf[b*512 + d];
        float cnew = sigm(gf)*cold + sigm(gi)*ftanh(gg);
        float hnew = sigm(go)*ftanh(cnew);
        hallb[((size_t)b*51 + t)*512 + d] = f2bu(hnew);
        if (t < declen[b]) cbuf[b*512 + d] = cnew;
        hloc0 = f2bu(hnew);
      }
      {
        int it = tid + 256;
        int b = it>>4, dd = it&15, d = (n0b>>2) + dd;
        float gi = gl[b*64 + dd*4+0], gf = gl[b*64 + dd*4+1];
        float gg = gl[b*64 + dd*4+2], go = gl[b*64 + dd*4+3];
        float cold = cbuf[b*512 + d];
        float cnew = sigm(gf)*cold + sigm(gi)*ftanh(gg);
        float hnew = sigm(go)*ftanh(cnew);
        hallb[((size_t)b*51 + t)*512 + d] = f2bu(hnew);
        if (t < declen[b]) cbuf[b*512 + d] = cnew;
        hloc1 = f2bu(hnew);
      }
      __syncthreads();                 // gl reads done -> As reusable
      ((ushort_t*)As)[tid]     = hloc0;
      ((ushort_t*)As)[tid+256] = hloc1;
      __syncthreads();
      if (tid < 128){
        int b = tid>>2;
        if (t < declen[b]){
          u64_t v = *(const u64_t*)((const ushort_t*)As + tid*4);
          coh_st64((u64_t*)(hnewb + (size_t)b*512 + (n0b>>2)) + (tid&3), v);
        }
      }
      __syncthreads();                 // drain hnewb stores
      if (tid==0) coh_sti(flags+blk, ep+3);
    }
  }
}

// -------------------------------------------------------------------------------------------
extern "C" void kernel_launch(void* const* d_in, const int* in_sizes, int n_in,
                              void* d_out, int out_size, void* d_ws, size_t ws_size,
                              hipStream_t stream)
{
  const float* enc   = (const float*)d_in[0];
  const int*   cap   = (const int*)d_in[1];
  const int*   lens  = (const int*)d_in[2];
  const float* Wenc  = (const float*)d_in[3];
  const float* benc  = (const float*)d_in[4];
  const float* Wdec  = (const float*)d_in[5];
  const float* bdec  = (const float*)d_in[6];
  const float* Wfull = (const float*)d_in[7];
  // d_in[8] = b_full_att: softmax-invariant, skipped
  const float* emb   = (const float*)d_in[9];
  const float* Wih   = (const float*)d_in[10];
  const float* bih   = (const float*)d_in[11];
  const float* Whh   = (const float*)d_in[12];
  const float* bhh   = (const float*)d_in[13];
  const float* Winh  = (const float*)d_in[14];
  const float* binh  = (const float*)d_in[15];
  const float* Winc  = (const float*)d_in[16];
  const float* binc  = (const float*)d_in[17];
  const float* Wfb   = (const float*)d_in[18];
  const float* bfb   = (const float*)d_in[19];
  const float* Wfc   = (const float*)d_in[20];
  const float* bfc   = (const float*)d_in[21];
  float* out = (float*)d_out;

  char* w = (char*)d_ws;
  size_t off = 0;
  auto alloc = [&](size_t bytes)->char*{ char* p = w + off; off += (bytes + 255) & ~(size_t)255; return p; };
  ushort_t* WfcT    = (ushort_t*)alloc(20000ull*512*2);  // [20000][512]
  ushort_t* WHCp    = (ushort_t*)alloc(2048ull*768*2);   // rows r=d*4+g; k: [Whh^T | WihBot^T]
  ushort_t* WihTopTp= (ushort_t*)alloc(2048ull*512*2);   // rows r=d*4+g
  ushort_t* XWT768  = (ushort_t*)alloc(768ull*512*2);    // [Wdec^T ; Wfb^T]
  ushort_t* WencT   = (ushort_t*)alloc(512ull*256*2);
  ushort_t* encb    = (ushort_t*)alloc(32ull*196*256*2);
  ushort_t* erowsb  = (ushort_t*)alloc(1632ull*512*2);
  ushort_t* att1b   = (ushort_t*)alloc(6272ull*512*2);
  ushort_t* eihR    = (ushort_t*)alloc(1632ull*2048*2);  // cols r=d*4+g, incl. b_ih + b_hh
  ushort_t* hallb   = (ushort_t*)alloc(1632ull*512*2);
  ushort_t* hnewb   = (ushort_t*)alloc(32ull*512*2);
  ushort_t* xaweb   = (ushort_t*)alloc(32ull*256*2);
  float*    XO      = (float*)alloc(32ull*768*4);
  float*    cbuf    = (float*)alloc(32ull*512*4);
  float*    xbias   = (float*)alloc(768*4);
  float*    bihR    = (float*)alloc(2048*4);
  int*      declen  = (int*)alloc(32*4);
  int*      flags   = (int*)alloc(512);                  // 128 ints, per-block arrival epochs

  float* out_preds = out;                        // 32*51*20000
  float* out_cap   = out + 32640000ull;          // 32*52
  float* out_dl    = out_cap + 1664;             // 32
  float* out_alph  = out_dl + 32;                // 32*51*196

  // ---- preamble ----
  k_cvtT<<<dim3(625,16),256,0,stream>>>(Wfc, 20000, WfcT, 512, 0);
  k_cvtT<<<dim3(64,16), 256,0,stream>>>(Whh, 2048, WHCp, 768, 1);                     // k 0..511
  k_cvtT<<<dim3(64,8),  256,0,stream>>>(Wih + 512ull*2048, 2048, WHCp + 512, 768, 1); // k 512..767
  k_cvtT<<<dim3(64,16), 256,0,stream>>>(Wih, 2048, WihTopTp, 512, 1);
  k_cvtT<<<dim3(16,16), 256,0,stream>>>(Wdec, 512, XWT768, 512, 0);
  k_cvtT<<<dim3(8,16),  256,0,stream>>>(Wfb, 256, XWT768 + 512ull*512, 512, 0);
  k_cvtT<<<dim3(16,8),  256,0,stream>>>(Wenc, 512, WencT, 256, 0);
  k_cvt4<<<1568,256,0,stream>>>(enc, encb, 401408);
  k_misc<<<8,256,0,stream>>>(cap, lens, bdec, bfb, bih, bhh, out_cap, out_dl, declen,
                             xbias, bihR, flags);
  k_init<<<32,256,0,stream>>>(enc, Winh, binh, Winc, binc, hnewb, cbuf);
  k_gather<<<1632,256,0,stream>>>(cap, emb, erowsb);
  // att1b = encb @ WencT^T + benc  (6272 x 512, K=256) -> bf16
  k_gemm<<<dim3(4,49),256,0,stream>>>(encb, 256, WencT, 256, 6272, 512, 256,
                                      benc, nullptr, att1b, 512, nullptr, 0,0,0);
  // eihR = erowsb @ WihTopTp^T + (bih+bhh reordered)  (1632 x 2048(reord), K=512) -> bf16
  k_gemm<<<dim3(16,13),256,0,stream>>>(erowsb, 512, WihTopTp, 512, 1632, 2048, 512,
                                       bihR, nullptr, eihR, 2048, nullptr, 0,0,0);

  // ---- fused 51-step recurrence: ONE launch, 64 role-split blocks ----
  k_steps<<<64,256,0,stream>>>(XWT768, WHCp, xbias, att1b, Wfull, encb, eihR, declen,
                               hnewb, cbuf, XO, xaweb, hallb, out_alph, flags);

  // ---- preds = hallb @ WfcT^T + bfc (masked). M=1632, N=20000, K=512; XCD-aware mapping ---
  k_gemm<<<2080,256,0,stream>>>(hallb, 512, WfcT, 512, 1632, 20000, 512,
                                bfc, out_preds, nullptr, 20000, declen, 13, 157, 1);
}

// Round 5
// 1705.319 us; speedup vs baseline: 1.4034x; 1.0546x over previous
//
#include <hip/hip_runtime.h>
#include <hip/hip_bf16.h>
#include <math.h>
#include <stddef.h>

// B=32, P=196, E=256, A=512, M=512, D=512, V=20000, L=52, T=51
// R5: R4 staggered dual-pipeline (96 blocks) with staging-stride fixes.
//   - h staging: 128 u64/row (was 64 -> upper half of As was garbage => NaN)
//   - xawe staging: 64 u64/row (was 32)
//   - ALL backs publish flagA; fronts wait on all 32 (closes hnewb WAR chain)
//   Batches split into 2 independent groups of 16; back blocks do gates+LSTM+
//   h publish then immediately h@Whh + XO-slice for next step (same block).
//   Fronts do attention only. 2 cross-block handoffs per step. All inter-block
//   traffic via agent-scope relaxed atomics (LLC-coherent, fence-free).

typedef unsigned short ushort_t;
typedef __bf16 bf16x8 __attribute__((ext_vector_type(8)));
typedef float f32x4 __attribute__((ext_vector_type(4)));
typedef unsigned short ushort8 __attribute__((ext_vector_type(8)));
typedef unsigned short ushort4v __attribute__((ext_vector_type(4)));
typedef unsigned long long u64_t;

union FragU { ushort8 u; bf16x8 b; };

__device__ __forceinline__ unsigned short f2bu(float f){
  union { float f; unsigned int i; } c; c.f = f;
  unsigned int x = c.i;
  unsigned int r = x + 0x7fffu + ((x >> 16) & 1u);
  return (unsigned short)(r >> 16);
}
__device__ __forceinline__ float bu2f(unsigned short u){
  union { unsigned int i; float f; } c; c.i = ((unsigned int)u) << 16; return c.f;
}
__device__ __forceinline__ float sigm(float x){ return 1.f/(1.f+__expf(-x)); }
__device__ __forceinline__ float ftanh(float x){ float e = __expf(2.f*x); return 1.f - 2.f/(e+1.f); }

// coherent (LLC) access helpers: agent-scope relaxed atomics bypass the
// non-coherent per-XCD L2. __syncthreads() drains vmcnt -> release ordering.
__device__ __forceinline__ u64_t coh_ld64(const u64_t* p){
  return __hip_atomic_load(p, __ATOMIC_RELAXED, __HIP_MEMORY_SCOPE_AGENT);
}
__device__ __forceinline__ void coh_st64(u64_t* p, u64_t v){
  __hip_atomic_store(p, v, __ATOMIC_RELAXED, __HIP_MEMORY_SCOPE_AGENT);
}
__device__ __forceinline__ float coh_ldf(const float* p){
  return __hip_atomic_load(p, __ATOMIC_RELAXED, __HIP_MEMORY_SCOPE_AGENT);
}
__device__ __forceinline__ void coh_stf(float* p, float v){
  __hip_atomic_store(p, v, __ATOMIC_RELAXED, __HIP_MEMORY_SCOPE_AGENT);
}
__device__ __forceinline__ int coh_ldi(const int* p){
  return __hip_atomic_load(p, __ATOMIC_RELAXED, __HIP_MEMORY_SCOPE_AGENT);
}
__device__ __forceinline__ void coh_sti(int* p, int v){
  __hip_atomic_store(p, v, __ATOMIC_RELAXED, __HIP_MEMORY_SCOPE_AGENT);
}

// ---- transpose + fp32->bf16; optional dest-row permute r=d*4+g (for 2048-col gate mats) ---
__global__ __launch_bounds__(256) void k_cvtT(const float* __restrict__ src, int C,
                                              ushort_t* __restrict__ dst, int ldd, int perm){
  __shared__ float tile[32][33];
  int c0 = blockIdx.x*32, r0 = blockIdx.y*32;
  int tx = threadIdx.x & 31, ty = threadIdx.x >> 5;
  #pragma unroll
  for (int i=0;i<4;i++){ int r = ty + i*8; tile[r][tx] = src[(size_t)(r0+r)*C + c0+tx]; }
  __syncthreads();
  #pragma unroll
  for (int i=0;i<4;i++){
    int c = ty + i*8;
    int row = c0 + c;
    if (perm) row = ((row & 511) << 2) | (row >> 9);   // g*512+d -> d*4+g
    dst[(size_t)row*ldd + r0+tx] = f2bu(tile[tx][c]);
  }
}

// ---- elementwise fp32 -> bf16 -------------------------------------------------------------
__global__ __launch_bounds__(256) void k_cvt4(const float* __restrict__ src,
                                              ushort_t* __restrict__ dst, int n4){
  int i = blockIdx.x*256 + threadIdx.x;
  if (i < n4){
    float4 v = ((const float4*)src)[i];
    ushort4v o; o.x=f2bu(v.x); o.y=f2bu(v.y); o.z=f2bu(v.z); o.w=f2bu(v.w);
    ((ushort4v*)dst)[i] = o;
  }
}

// ---- misc: int outputs, declen, biases, zero flags ----------------------------------------
__global__ __launch_bounds__(256) void k_misc(const int* __restrict__ cap, const int* __restrict__ lens,
                      const float* __restrict__ bdec, const float* __restrict__ bfb,
                      const float* __restrict__ bih, const float* __restrict__ bhh,
                      float* out_cap, float* out_dl, int* declen,
                      float* xbias, float* bihR, int* flags){
  int tid = blockIdx.x*256 + threadIdx.x;
  if (tid < 256) flags[tid] = 0;
  if (tid < 32*52) out_cap[tid] = (float)cap[tid];
  if (tid < 32){ int dl = lens[tid]-1; out_dl[tid] = (float)dl; declen[tid] = dl; }
  if (tid < 768) xbias[tid] = (tid<512) ? bdec[tid] : bfb[tid-512];
  if (tid < 2048){
    int c = (tid&3)*512 + (tid>>2);   // reordered col r=d*4+g <- original c=g*512+d
    bihR[tid] = bih[c] + bhh[c];      // bhh folded in
  }
}

// ---- init: mean_enc -> h0 (bf16), c0 (fp32) -----------------------------------------------
__global__ __launch_bounds__(256) void k_init(const float* __restrict__ enc,
                     const float* __restrict__ Wih_, const float* __restrict__ bih_,
                     const float* __restrict__ Wic_, const float* __restrict__ bic_,
                     ushort_t* __restrict__ hnewb, float* __restrict__ cbuf){
  int b = blockIdx.x, tid = threadIdx.x;
  __shared__ float mean_s[256];
  const float* eb = enc + (size_t)b*196*256;
  float s = 0.f;
  for (int p=0;p<196;p++) s += eb[p*256 + tid];
  mean_s[tid] = s * (1.f/196.f);
  __syncthreads();
  float h0=0.f,h1=0.f,c0=0.f,c1=0.f;
  for (int k=0;k<256;k++){
    float m = mean_s[k];
    h0 += m*Wih_[k*512+tid];      h1 += m*Wih_[k*512+tid+256];
    c0 += m*Wic_[k*512+tid];      c1 += m*Wic_[k*512+tid+256];
  }
  hnewb[b*512+tid]     = f2bu(h0 + bih_[tid]);
  hnewb[b*512+tid+256] = f2bu(h1 + bih_[tid+256]);
  cbuf[b*512+tid]      = c0 + bic_[tid];
  cbuf[b*512+tid+256]  = c1 + bic_[tid+256];
}

// ---- gather embedding rows -> bf16 --------------------------------------------------------
__global__ __launch_bounds__(256) void k_gather(const int* __restrict__ cap,
                                                const float* __restrict__ emb,
                                                ushort_t* __restrict__ erowsb){
  int row = blockIdx.x; int b = row/51, t = row%51;
  int tok = cap[b*52 + t];
  const float* src = emb + (size_t)tok*512;
  ushort_t* dst = erowsb + (size_t)row*512;
  dst[threadIdx.x]       = f2bu(src[threadIdx.x]);
  dst[threadIdx.x + 256] = f2bu(src[threadIdx.x + 256]);
}

// ---- generic bf16 MFMA GEMM (128x128 tile); optional XCD-aware flat mapping ---------------
#define LDT 40
__global__ __launch_bounds__(256)
void k_gemm(const ushort_t* __restrict__ Ag, int lda,
            const ushort_t* __restrict__ Bg, int ldb,
            int Mrows, int Ncols, int K,
            const float* __restrict__ bias,
            float* __restrict__ outF, ushort_t* __restrict__ outH, int ldo,
            const int* __restrict__ declen,
            int Mtiles, int Ntiles, int xcdswz)
{
  __shared__ ushort_t As[128*LDT];
  __shared__ ushort_t Bs[128*LDT];
  int m0, n0;
  if (xcdswz){
    int l = blockIdx.x; int xcd = l & 7; int i = l >> 3;
    int mt = i % Mtiles; int ns = i / Mtiles;
    int nt = ns*8 + xcd;
    if (nt >= Ntiles) return;
    m0 = mt*128; n0 = nt*128;
  } else {
    m0 = blockIdx.y*128; n0 = blockIdx.x*128;
  }
  int tid = threadIdx.x;
  int wave = tid>>6, lane = tid&63;
  int wm = wave>>1, wn = wave&1;
  int q = lane>>4, r = lane&15;
  f32x4 acc[4][4];
  f32x4 zero4 = {0.f,0.f,0.f,0.f};
  #pragma unroll
  for(int i=0;i<4;i++){ acc[i][0]=zero4; acc[i][1]=zero4; acc[i][2]=zero4; acc[i][3]=zero4; }

  for (int k0=0; k0<K; k0+=32){
    __syncthreads();
    #pragma unroll
    for (int c=tid; c<512; c+=256){
      int row = c>>2, ko = (c&3)*8;
      ushort8 v = {0,0,0,0,0,0,0,0};
      if (m0+row < Mrows) v = *(const ushort8*)(Ag + (size_t)(m0+row)*lda + k0 + ko);
      *(ushort8*)(As + row*LDT + ko) = v;
      ushort8 wv = {0,0,0,0,0,0,0,0};
      if (n0+row < Ncols) wv = *(const ushort8*)(Bg + (size_t)(n0+row)*ldb + k0 + ko);
      *(ushort8*)(Bs + row*LDT + ko) = wv;
    }
    __syncthreads();
    FragU a[4], bb[4];
    #pragma unroll
    for(int i=0;i<4;i++){
      a[i].u  = *(const ushort8*)(As + (64*wm + 16*i + r)*LDT + 8*q);
      bb[i].u = *(const ushort8*)(Bs + (64*wn + 16*i + r)*LDT + 8*q);
    }
    #pragma unroll
    for(int i=0;i<4;i++)
      #pragma unroll
      for(int j=0;j<4;j++)
        acc[i][j] = __builtin_amdgcn_mfma_f32_16x16x32_bf16(a[i].b, bb[j].b, acc[i][j], 0,0,0);
  }
  #pragma unroll
  for(int i=0;i<4;i++){
    int rowbase = m0 + 64*wm + 16*i + q*4;
    #pragma unroll
    for(int j=0;j<4;j++){
      int col = n0 + 64*wn + 16*j + r;
      if (col >= Ncols) continue;
      float bv = bias ? bias[col] : 0.f;
      #pragma unroll
      for(int rr=0;rr<4;rr++){
        int row = rowbase + rr;
        if (row >= Mrows) continue;
        float v = acc[i][j][rr] + bv;
        if (declen){ int tt = row % 51; int b = row / 51; if (tt >= declen[b]) v = 0.f; }
        if (outF) outF[(size_t)row*ldo + col] = v;
        else      outH[(size_t)row*ldo + col] = f2bu(v);
      }
    }
  }
}

// ---- persistent fused step loop: 96 blocks (32 fronts + 64 backs, 2 groups) ---------------
__global__ __launch_bounds__(256)
void k_steps(const ushort_t* __restrict__ XWT768, const ushort_t* __restrict__ WHCp,
             const float* __restrict__ xbias,
             const ushort_t* __restrict__ att1b, const float* __restrict__ wfull,
             const ushort_t* __restrict__ encb, const ushort_t* __restrict__ eihR,
             const int* __restrict__ declen,
             ushort_t* __restrict__ hnewb, float* __restrict__ cbuf,
             float* __restrict__ XO,
             ushort_t* __restrict__ xaweb, ushort_t* __restrict__ hallb,
             float* __restrict__ out_alph, int* flags)
{
  __shared__ char pool[150272];
  int blk = blockIdx.x, tid = threadIdx.x;
  int wave = tid>>6, lane = tid&63;
  int q = lane>>4, r = lane&15;

  int* flagA = flags;        // [2][32] backs' step-head done (XO ready for jj<24)
  int* flagC = flags + 64;   // [2][32] backs' h-slice ready
  int* flagB = flags + 128;  // [32]    fronts' xawe ready (per batch)

  if (blk < 32){
    // ================= FRONT: attention for batch b =================
    int b = blk, g = b>>4;
    float*    att2_s  = (float*)pool;             // 512
    float*    wf_s    = (float*)(pool + 2048);    // 512
    float*    alpha_s = (float*)(pool + 4096);    // 196 (pad to 200)
    float*    red_s   = (float*)(pool + 4928);    // 24 floats
    ushort_t* xst     = (ushort_t*)(pool + 5056); // 256 shorts
    for (int i=tid;i<512;i+=256) wf_s[i] = wfull[i];
    __syncthreads();

    for (int t=0;t<51;t++){
      if (tid < 32) while (coh_ldi(flagA + g*32 + tid) < t+1) {}
      __syncthreads();
      for (int i=tid;i<512;i+=256) att2_s[i] = coh_ldf(XO + (size_t)b*768 + i);
      __syncthreads();
      float av = -1e30f;
      if (tid < 196){
        const ushort_t* arow = att1b + ((size_t)b*196 + tid)*512;
        float s0=0.f,s1=0.f,s2=0.f,s3=0.f;
        for (int k=0;k<512;k+=8){
          ushort8 v = *(const ushort8*)(arow + k);
          s0 += fmaxf(bu2f(v[0]) + att2_s[k+0], 0.f)*wf_s[k+0];
          s1 += fmaxf(bu2f(v[1]) + att2_s[k+1], 0.f)*wf_s[k+1];
          s2 += fmaxf(bu2f(v[2]) + att2_s[k+2], 0.f)*wf_s[k+2];
          s3 += fmaxf(bu2f(v[3]) + att2_s[k+3], 0.f)*wf_s[k+3];
          s0 += fmaxf(bu2f(v[4]) + att2_s[k+4], 0.f)*wf_s[k+4];
          s1 += fmaxf(bu2f(v[5]) + att2_s[k+5], 0.f)*wf_s[k+5];
          s2 += fmaxf(bu2f(v[6]) + att2_s[k+6], 0.f)*wf_s[k+6];
          s3 += fmaxf(bu2f(v[7]) + att2_s[k+7], 0.f)*wf_s[k+7];
        }
        av = (s0+s1)+(s2+s3);
      }
      float m = av;
      #pragma unroll
      for (int off=32;off>0;off>>=1) m = fmaxf(m, __shfl_down(m, off, 64));
      if ((tid&63)==0) red_s[tid>>6] = m;
      __syncthreads();
      if (tid==0) red_s[16] = fmaxf(fmaxf(red_s[0],red_s[1]), fmaxf(red_s[2],red_s[3]));
      __syncthreads();
      float gmax = red_s[16];
      float ev = (tid<196) ? __expf(av - gmax) : 0.f;
      float ssum = ev;
      #pragma unroll
      for (int off=32;off>0;off>>=1) ssum += __shfl_down(ssum, off, 64);
      if ((tid&63)==0) red_s[20+(tid>>6)] = ssum;
      __syncthreads();
      if (tid==0) red_s[17] = red_s[20]+red_s[21]+red_s[22]+red_s[23];
      __syncthreads();
      float inv = 1.f/red_s[17];
      int mask = (t < declen[b]) ? 1 : 0;
      if (tid<196){
        float al = ev*inv;
        alpha_s[tid] = al;
        out_alph[((size_t)b*51 + t)*196 + tid] = mask ? al : 0.f;
      }
      __syncthreads();
      const ushort_t* eb = encb + (size_t)b*196*256;
      float aw0 = 0.f, aw1 = 0.f;
      for (int p=0;p<196;p+=2){
        aw0 += alpha_s[p]  *bu2f(eb[(size_t)p*256 + tid]);
        aw1 += alpha_s[p+1]*bu2f(eb[(size_t)(p+1)*256 + tid]);
      }
      float gate = sigm(coh_ldf(XO + (size_t)b*768 + 512 + tid));
      xst[tid] = f2bu(gate*(aw0+aw1));
      __syncthreads();
      if (tid < 64){
        u64_t v = *(const u64_t*)(xst + tid*4);
        coh_st64((u64_t*)(xaweb + (size_t)b*256) + tid, v);
      }
      __syncthreads();                               // drain xawe stores
      if (tid==0) coh_sti(flagB + b, t+1);
    }
  } else {
    // ================= BACK: gates + LSTM + h publish, then A-inline =================
    int j = blk-32, g = j>>5, jj = j&31;
    int b0 = g*16;
    int n0b = jj*64;          // gate-col base (reordered d*4+gate layout)
    int n0x = jj*32;          // XO-col base (only jj<24)
    ushort_t* Wh = (ushort_t*)pool;              // [64][520]  Whh^T slice
    ushort_t* Wc = (ushort_t*)(pool + 66560);    // [64][264]  WihBot^T slice
    ushort_t* Wx = (ushort_t*)(pool + 100352);   // [32][520]  XWT slice (jj<24)
    ushort_t* As = (ushort_t*)(pool + 133632);   // [16][520] h-stage / [16][264] xawe-stage
    float*    gl = (float*)(pool + 142080);      // [16][64]
    ushort_t* hst= (ushort_t*)(pool + 146176);   // 256 shorts

    for (int i=tid; i<64*64; i+=256){ int row=i>>6, ko=(i&63)*8;
      *(ushort8*)(Wh + row*520 + ko) = *(const ushort8*)(WHCp + (size_t)(n0b+row)*768 + ko); }
    for (int i=tid; i<64*32; i+=256){ int row=i>>5, ko=(i&31)*8;
      *(ushort8*)(Wc + row*264 + ko) = *(const ushort8*)(WHCp + (size_t)(n0b+row)*768 + 512 + ko); }
    if (jj < 24)
      for (int i=tid; i<32*64; i+=256){ int row=i>>6, ko=(i&63)*8;
        *(ushort8*)(Wx + row*520 + ko) = *(const ushort8*)(XWT768 + (size_t)(n0x+row)*512 + ko); }
    __syncthreads();

    // ---- prologue: h0 -> gwh(t=0) + XO(t=0) + hprev ----
    f32x4 gwh = {0.f,0.f,0.f,0.f};
    float hprev;
    {
      const u64_t* H8 = (const u64_t*)(hnewb + (size_t)b0*512);   // 128 u64 per batch row
      for (int i=tid; i<16*128; i+=256){ int row=i>>7, k4=i&127;
        *(u64_t*)(As + row*520 + k4*4) = coh_ld64(H8 + row*128 + k4); }
      __syncthreads();
      hprev = bu2f(As[(tid>>4)*520 + jj*16 + (tid&15)]);
      f32x4 xo = {0.f,0.f,0.f,0.f};
      #pragma unroll
      for (int kc=0;kc<512;kc+=32){
        FragU a,bw; a.u = *(const ushort8*)(As + r*520 + kc + 8*q);
        bw.u = *(const ushort8*)(Wh + (wave*16 + r)*520 + kc + 8*q);
        gwh = __builtin_amdgcn_mfma_f32_16x16x32_bf16(a.b, bw.b, gwh, 0,0,0);
        if (wave < 2){
          FragU bx; bx.u = *(const ushort8*)(Wx + (wave*16 + r)*520 + kc + 8*q);
          xo = __builtin_amdgcn_mfma_f32_16x16x32_bf16(a.b, bx.b, xo, 0,0,0);
        }
      }
      if (jj<24 && wave<2){
        int col = n0x + wave*16 + r;  float bv = xbias[col];
        #pragma unroll
        for (int rr=0;rr<4;rr++)
          coh_stf(XO + (size_t)(b0 + 4*q + rr)*768 + col, xo[rr] + bv);
      }
      __syncthreads();                               // drain XO stores
      if (tid==0) coh_sti(flagA + g*32 + jj, 1);
    }

    for (int t=0;t<51;t++){
      // eihR prefetch (static, dependency-free)
      float eih[4];
      #pragma unroll
      for (int rr=0;rr<4;rr++){
        int row = 4*q + rr;
        eih[rr] = bu2f(eihR[((size_t)(b0+row)*51 + t)*2048 + n0b + wave*16 + r]);
      }
      // ---- C: wait xawe of this group ----
      if (tid < 16) while (coh_ldi(flagB + b0 + tid) < t+1) {}
      __syncthreads();
      const u64_t* X8 = (const u64_t*)(xaweb + (size_t)b0*256);   // 64 u64 per batch row
      for (int i=tid; i<16*64; i+=256){ int row=i>>6, k4=i&63;
        *(u64_t*)(As + row*264 + k4*4) = coh_ld64(X8 + row*64 + k4); }
      __syncthreads();
      f32x4 cc = {0.f,0.f,0.f,0.f};
      #pragma unroll
      for (int kc=0;kc<256;kc+=32){
        FragU a,bw; a.u = *(const ushort8*)(As + r*264 + kc + 8*q);
        bw.u = *(const ushort8*)(Wc + (wave*16 + r)*264 + kc + 8*q);
        cc = __builtin_amdgcn_mfma_f32_16x16x32_bf16(a.b, bw.b, cc, 0,0,0);
      }
      #pragma unroll
      for (int rr=0;rr<4;rr++)
        gl[(4*q+rr)*64 + wave*16 + r] = gwh[rr] + cc[rr] + eih[rr];
      __syncthreads();
      // LSTM: one (batch,d) item per thread
      int bl = tid>>4, dd = tid&15;
      int b = b0 + bl, d = jj*16 + dd;
      float gi = gl[bl*64 + dd*4+0], gf = gl[bl*64 + dd*4+1];
      float gg = gl[bl*64 + dd*4+2], go = gl[bl*64 + dd*4+3];
      float cold = cbuf[(size_t)b*512 + d];
      float cnew = sigm(gf)*cold + sigm(gi)*ftanh(gg);
      float hnew = sigm(go)*ftanh(cnew);
      hallb[((size_t)b*51 + t)*512 + d] = f2bu(hnew);
      bool upd = (t < declen[b]);
      if (upd) cbuf[(size_t)b*512 + d] = cnew;
      float hkeep = upd ? hnew : hprev;
      hprev = hkeep;
      hst[bl*16 + dd] = f2bu(hkeep);
      __syncthreads();
      if (tid < 64){
        u64_t v = *(const u64_t*)(hst + tid*4);
        int bl2 = tid>>2;
        coh_st64((u64_t*)(hnewb + (size_t)(b0+bl2)*512 + jj*16) + (tid&3), v);
      }
      __syncthreads();                               // drain h stores
      if (tid==0) coh_sti(flagC + g*32 + jj, t+1);
      if (t == 50) break;

      // ---- A-inline: wait all h-slices, load h, gwh(t+1) + XO(t+1) ----
      if (tid < 32) while (coh_ldi(flagC + g*32 + tid) < t+1) {}
      __syncthreads();
      const u64_t* H8 = (const u64_t*)(hnewb + (size_t)b0*512);   // 128 u64 per batch row
      for (int i=tid; i<16*128; i+=256){ int row=i>>7, k4=i&127;
        *(u64_t*)(As + row*520 + k4*4) = coh_ld64(H8 + row*128 + k4); }
      __syncthreads();
      gwh = (f32x4){0.f,0.f,0.f,0.f};
      f32x4 xo = {0.f,0.f,0.f,0.f};
      #pragma unroll
      for (int kc=0;kc<512;kc+=32){
        FragU a,bw; a.u = *(const ushort8*)(As + r*520 + kc + 8*q);
        bw.u = *(const ushort8*)(Wh + (wave*16 + r)*520 + kc + 8*q);
        gwh = __builtin_amdgcn_mfma_f32_16x16x32_bf16(a.b, bw.b, gwh, 0,0,0);
        if (wave < 2){
          FragU bx; bx.u = *(const ushort8*)(Wx + (wave*16 + r)*520 + kc + 8*q);
          xo = __builtin_amdgcn_mfma_f32_16x16x32_bf16(a.b, bx.b, xo, 0,0,0);
        }
      }
      if (jj<24 && wave<2){
        int col = n0x + wave*16 + r;  float bv = xbias[col];
        #pragma unroll
        for (int rr=0;rr<4;rr++)
          coh_stf(XO + (size_t)(b0 + 4*q + rr)*768 + col, xo[rr] + bv);
      }
      __syncthreads();                               // drain XO stores
      if (tid==0) coh_sti(flagA + g*32 + jj, t+2);
    }
  }
}

// -------------------------------------------------------------------------------------------
extern "C" void kernel_launch(void* const* d_in, const int* in_sizes, int n_in,
                              void* d_out, int out_size, void* d_ws, size_t ws_size,
                              hipStream_t stream)
{
  const float* enc   = (const float*)d_in[0];
  const int*   cap   = (const int*)d_in[1];
  const int*   lens  = (const int*)d_in[2];
  const float* Wenc  = (const float*)d_in[3];
  const float* benc  = (const float*)d_in[4];
  const float* Wdec  = (const float*)d_in[5];
  const float* bdec  = (const float*)d_in[6];
  const float* Wfull = (const float*)d_in[7];
  // d_in[8] = b_full_att: softmax-invariant, skipped
  const float* emb   = (const float*)d_in[9];
  const float* Wih   = (const float*)d_in[10];
  const float* bih   = (const float*)d_in[11];
  const float* Whh   = (const float*)d_in[12];
  const float* bhh   = (const float*)d_in[13];
  const float* Winh  = (const float*)d_in[14];
  const float* binh  = (const float*)d_in[15];
  const float* Winc  = (const float*)d_in[16];
  const float* binc  = (const float*)d_in[17];
  const float* Wfb   = (const float*)d_in[18];
  const float* bfb   = (const float*)d_in[19];
  const float* Wfc   = (const float*)d_in[20];
  const float* bfc   = (const float*)d_in[21];
  float* out = (float*)d_out;

  char* w = (char*)d_ws;
  size_t off = 0;
  auto alloc = [&](size_t bytes)->char*{ char* p = w + off; off += (bytes + 255) & ~(size_t)255; return p; };
  ushort_t* WfcT    = (ushort_t*)alloc(20000ull*512*2);  // [20000][512]
  ushort_t* WHCp    = (ushort_t*)alloc(2048ull*768*2);   // rows r=d*4+g; k: [Whh^T | WihBot^T]
  ushort_t* WihTopTp= (ushort_t*)alloc(2048ull*512*2);   // rows r=d*4+g
  ushort_t* XWT768  = (ushort_t*)alloc(768ull*512*2);    // [Wdec^T ; Wfb^T]
  ushort_t* WencT   = (ushort_t*)alloc(512ull*256*2);
  ushort_t* encb    = (ushort_t*)alloc(32ull*196*256*2);
  ushort_t* erowsb  = (ushort_t*)alloc(1632ull*512*2);
  ushort_t* att1b   = (ushort_t*)alloc(6272ull*512*2);
  ushort_t* eihR    = (ushort_t*)alloc(1632ull*2048*2);  // cols r=d*4+g, incl. b_ih + b_hh
  ushort_t* hallb   = (ushort_t*)alloc(1632ull*512*2);
  ushort_t* hnewb   = (ushort_t*)alloc(32ull*512*2);
  ushort_t* xaweb   = (ushort_t*)alloc(32ull*256*2);
  float*    XO      = (float*)alloc(32ull*768*4);
  float*    cbuf    = (float*)alloc(32ull*512*4);
  float*    xbias   = (float*)alloc(768*4);
  float*    bihR    = (float*)alloc(2048*4);
  int*      declen  = (int*)alloc(32*4);
  int*      flags   = (int*)alloc(1024);                 // 256 ints: A[2][32] C[2][32] B[32]

  float* out_preds = out;                        // 32*51*20000
  float* out_cap   = out + 32640000ull;          // 32*52
  float* out_dl    = out_cap + 1664;             // 32
  float* out_alph  = out_dl + 32;                // 32*51*196

  // ---- preamble ----
  k_cvtT<<<dim3(625,16),256,0,stream>>>(Wfc, 20000, WfcT, 512, 0);
  k_cvtT<<<dim3(64,16), 256,0,stream>>>(Whh, 2048, WHCp, 768, 1);                     // k 0..511
  k_cvtT<<<dim3(64,8),  256,0,stream>>>(Wih + 512ull*2048, 2048, WHCp + 512, 768, 1); // k 512..767
  k_cvtT<<<dim3(64,16), 256,0,stream>>>(Wih, 2048, WihTopTp, 512, 1);
  k_cvtT<<<dim3(16,16), 256,0,stream>>>(Wdec, 512, XWT768, 512, 0);
  k_cvtT<<<dim3(8,16),  256,0,stream>>>(Wfb, 256, XWT768 + 512ull*512, 512, 0);
  k_cvtT<<<dim3(16,8),  256,0,stream>>>(Wenc, 512, WencT, 256, 0);
  k_cvt4<<<1568,256,0,stream>>>(enc, encb, 401408);
  k_misc<<<8,256,0,stream>>>(cap, lens, bdec, bfb, bih, bhh, out_cap, out_dl, declen,
                             xbias, bihR, flags);
  k_init<<<32,256,0,stream>>>(enc, Winh, binh, Winc, binc, hnewb, cbuf);
  k_gather<<<1632,256,0,stream>>>(cap, emb, erowsb);
  // att1b = encb @ WencT^T + benc  (6272 x 512, K=256) -> bf16
  k_gemm<<<dim3(4,49),256,0,stream>>>(encb, 256, WencT, 256, 6272, 512, 256,
                                      benc, nullptr, att1b, 512, nullptr, 0,0,0);
  // eihR = erowsb @ WihTopTp^T + (bih+bhh reordered)  (1632 x 2048(reord), K=512) -> bf16
  k_gemm<<<dim3(16,13),256,0,stream>>>(erowsb, 512, WihTopTp, 512, 1632, 2048, 512,
                                       bihR, nullptr, eihR, 2048, nullptr, 0,0,0);

  // ---- fused 51-step recurrence: ONE launch, 96 blocks, dual staggered pipelines ----
  k_steps<<<96,256,0,stream>>>(XWT768, WHCp, xbias, att1b, Wfull, encb, eihR, declen,
                               hnewb, cbuf, XO, xaweb, hallb, out_alph, flags);

  // ---- preds = hallb @ WfcT^T + bfc (masked). M=1632, N=20000, K=512; XCD-aware mapping ---
  k_gemm<<<2080,256,0,stream>>>(hallb, 512, WfcT, 512, 1632, 20000, 512,
                                bfc, out_preds, nullptr, 20000, declen, 13, 157, 1);
}

// Round 6
// 1542.938 us; speedup vs baseline: 1.5511x; 1.1052x over previous
//
#include <hip/hip_runtime.h>
#include <hip/hip_bf16.h>
#include <math.h>
#include <stddef.h>

// B=32, P=196, E=256, A=512, M=512, D=512, V=20000, L=52, T=51
// R6: R5 dual-group pipeline + sync-fabric decontention.
//   - every flag padded to its own 128B cacheline (32 ints apart)
//   - s_sleep(2) backoff in all poll loops (cuts MALL poll flood)
//   - XO handoff coalesced: operand-swapped MFMA -> per-thread 2x8B contiguous
//     coherent stores; fronts stage all 768 floats with 8B coherent loads
//   Structure unchanged: 96 blocks = 32 fronts (attention, 1/batch) +
//   64 backs (gates+LSTM+h publish, then h@Whh + XO-slice inline).

typedef unsigned short ushort_t;
typedef __bf16 bf16x8 __attribute__((ext_vector_type(8)));
typedef float f32x4 __attribute__((ext_vector_type(4)));
typedef unsigned short ushort8 __attribute__((ext_vector_type(8)));
typedef unsigned short ushort4v __attribute__((ext_vector_type(4)));
typedef unsigned long long u64_t;

union FragU { ushort8 u; bf16x8 b; };

__device__ __forceinline__ unsigned short f2bu(float f){
  union { float f; unsigned int i; } c; c.f = f;
  unsigned int x = c.i;
  unsigned int r = x + 0x7fffu + ((x >> 16) & 1u);
  return (unsigned short)(r >> 16);
}
__device__ __forceinline__ float bu2f(unsigned short u){
  union { unsigned int i; float f; } c; c.i = ((unsigned int)u) << 16; return c.f;
}
__device__ __forceinline__ float sigm(float x){ return 1.f/(1.f+__expf(-x)); }
__device__ __forceinline__ float ftanh(float x){ float e = __expf(2.f*x); return 1.f - 2.f/(e+1.f); }

// coherent (LLC) access helpers: agent-scope relaxed atomics bypass the
// non-coherent per-XCD L2. __syncthreads() drains vmcnt -> release ordering.
__device__ __forceinline__ u64_t coh_ld64(const u64_t* p){
  return __hip_atomic_load(p, __ATOMIC_RELAXED, __HIP_MEMORY_SCOPE_AGENT);
}
__device__ __forceinline__ void coh_st64(u64_t* p, u64_t v){
  __hip_atomic_store(p, v, __ATOMIC_RELAXED, __HIP_MEMORY_SCOPE_AGENT);
}
__device__ __forceinline__ int coh_ldi(const int* p){
  return __hip_atomic_load(p, __ATOMIC_RELAXED, __HIP_MEMORY_SCOPE_AGENT);
}
__device__ __forceinline__ void coh_sti(int* p, int v){
  __hip_atomic_store(p, v, __ATOMIC_RELAXED, __HIP_MEMORY_SCOPE_AGENT);
}

// flag f lives at flags[f*32] (one 128B line per flag)
#define FLG(f) ((f)*32)

// ---- transpose + fp32->bf16; optional dest-row permute r=d*4+g (for 2048-col gate mats) ---
__global__ __launch_bounds__(256) void k_cvtT(const float* __restrict__ src, int C,
                                              ushort_t* __restrict__ dst, int ldd, int perm){
  __shared__ float tile[32][33];
  int c0 = blockIdx.x*32, r0 = blockIdx.y*32;
  int tx = threadIdx.x & 31, ty = threadIdx.x >> 5;
  #pragma unroll
  for (int i=0;i<4;i++){ int r = ty + i*8; tile[r][tx] = src[(size_t)(r0+r)*C + c0+tx]; }
  __syncthreads();
  #pragma unroll
  for (int i=0;i<4;i++){
    int c = ty + i*8;
    int row = c0 + c;
    if (perm) row = ((row & 511) << 2) | (row >> 9);   // g*512+d -> d*4+g
    dst[(size_t)row*ldd + r0+tx] = f2bu(tile[tx][c]);
  }
}

// ---- elementwise fp32 -> bf16 -------------------------------------------------------------
__global__ __launch_bounds__(256) void k_cvt4(const float* __restrict__ src,
                                              ushort_t* __restrict__ dst, int n4){
  int i = blockIdx.x*256 + threadIdx.x;
  if (i < n4){
    float4 v = ((const float4*)src)[i];
    ushort4v o; o.x=f2bu(v.x); o.y=f2bu(v.y); o.z=f2bu(v.z); o.w=f2bu(v.w);
    ((ushort4v*)dst)[i] = o;
  }
}

// ---- misc: int outputs, declen, biases, zero flags ----------------------------------------
__global__ __launch_bounds__(256) void k_misc(const int* __restrict__ cap, const int* __restrict__ lens,
                      const float* __restrict__ bdec, const float* __restrict__ bfb,
                      const float* __restrict__ bih, const float* __restrict__ bhh,
                      float* out_cap, float* out_dl, int* declen,
                      float* xbias, float* bihR, int* flags){
  int tid = blockIdx.x*256 + threadIdx.x;
  for (int i=tid; i<5120; i+=2048) flags[i] = 0;
  if (tid < 32*52) out_cap[tid] = (float)cap[tid];
  if (tid < 32){ int dl = lens[tid]-1; out_dl[tid] = (float)dl; declen[tid] = dl; }
  if (tid < 768) xbias[tid] = (tid<512) ? bdec[tid] : bfb[tid-512];
  if (tid < 2048){
    int c = (tid&3)*512 + (tid>>2);   // reordered col r=d*4+g <- original c=g*512+d
    bihR[tid] = bih[c] + bhh[c];      // bhh folded in
  }
}

// ---- init: mean_enc -> h0 (bf16), c0 (fp32) -----------------------------------------------
__global__ __launch_bounds__(256) void k_init(const float* __restrict__ enc,
                     const float* __restrict__ Wih_, const float* __restrict__ bih_,
                     const float* __restrict__ Wic_, const float* __restrict__ bic_,
                     ushort_t* __restrict__ hnewb, float* __restrict__ cbuf){
  int b = blockIdx.x, tid = threadIdx.x;
  __shared__ float mean_s[256];
  const float* eb = enc + (size_t)b*196*256;
  float s = 0.f;
  for (int p=0;p<196;p++) s += eb[p*256 + tid];
  mean_s[tid] = s * (1.f/196.f);
  __syncthreads();
  float h0=0.f,h1=0.f,c0=0.f,c1=0.f;
  for (int k=0;k<256;k++){
    float m = mean_s[k];
    h0 += m*Wih_[k*512+tid];      h1 += m*Wih_[k*512+tid+256];
    c0 += m*Wic_[k*512+tid];      c1 += m*Wic_[k*512+tid+256];
  }
  hnewb[b*512+tid]     = f2bu(h0 + bih_[tid]);
  hnewb[b*512+tid+256] = f2bu(h1 + bih_[tid+256]);
  cbuf[b*512+tid]      = c0 + bic_[tid];
  cbuf[b*512+tid+256]  = c1 + bic_[tid+256];
}

// ---- gather embedding rows -> bf16 --------------------------------------------------------
__global__ __launch_bounds__(256) void k_gather(const int* __restrict__ cap,
                                                const float* __restrict__ emb,
                                                ushort_t* __restrict__ erowsb){
  int row = blockIdx.x; int b = row/51, t = row%51;
  int tok = cap[b*52 + t];
  const float* src = emb + (size_t)tok*512;
  ushort_t* dst = erowsb + (size_t)row*512;
  dst[threadIdx.x]       = f2bu(src[threadIdx.x]);
  dst[threadIdx.x + 256] = f2bu(src[threadIdx.x + 256]);
}

// ---- generic bf16 MFMA GEMM (128x128 tile); optional XCD-aware flat mapping ---------------
#define LDT 40
__global__ __launch_bounds__(256)
void k_gemm(const ushort_t* __restrict__ Ag, int lda,
            const ushort_t* __restrict__ Bg, int ldb,
            int Mrows, int Ncols, int K,
            const float* __restrict__ bias,
            float* __restrict__ outF, ushort_t* __restrict__ outH, int ldo,
            const int* __restrict__ declen,
            int Mtiles, int Ntiles, int xcdswz)
{
  __shared__ ushort_t As[128*LDT];
  __shared__ ushort_t Bs[128*LDT];
  int m0, n0;
  if (xcdswz){
    int l = blockIdx.x; int xcd = l & 7; int i = l >> 3;
    int mt = i % Mtiles; int ns = i / Mtiles;
    int nt = ns*8 + xcd;
    if (nt >= Ntiles) return;
    m0 = mt*128; n0 = nt*128;
  } else {
    m0 = blockIdx.y*128; n0 = blockIdx.x*128;
  }
  int tid = threadIdx.x;
  int wave = tid>>6, lane = tid&63;
  int wm = wave>>1, wn = wave&1;
  int q = lane>>4, r = lane&15;
  f32x4 acc[4][4];
  f32x4 zero4 = {0.f,0.f,0.f,0.f};
  #pragma unroll
  for(int i=0;i<4;i++){ acc[i][0]=zero4; acc[i][1]=zero4; acc[i][2]=zero4; acc[i][3]=zero4; }

  for (int k0=0; k0<K; k0+=32){
    __syncthreads();
    #pragma unroll
    for (int c=tid; c<512; c+=256){
      int row = c>>2, ko = (c&3)*8;
      ushort8 v = {0,0,0,0,0,0,0,0};
      if (m0+row < Mrows) v = *(const ushort8*)(Ag + (size_t)(m0+row)*lda + k0 + ko);
      *(ushort8*)(As + row*LDT + ko) = v;
      ushort8 wv = {0,0,0,0,0,0,0,0};
      if (n0+row < Ncols) wv = *(const ushort8*)(Bg + (size_t)(n0+row)*ldb + k0 + ko);
      *(ushort8*)(Bs + row*LDT + ko) = wv;
    }
    __syncthreads();
    FragU a[4], bb[4];
    #pragma unroll
    for(int i=0;i<4;i++){
      a[i].u  = *(const ushort8*)(As + (64*wm + 16*i + r)*LDT + 8*q);
      bb[i].u = *(const ushort8*)(Bs + (64*wn + 16*i + r)*LDT + 8*q);
    }
    #pragma unroll
    for(int i=0;i<4;i++)
      #pragma unroll
      for(int j=0;j<4;j++)
        acc[i][j] = __builtin_amdgcn_mfma_f32_16x16x32_bf16(a[i].b, bb[j].b, acc[i][j], 0,0,0);
  }
  #pragma unroll
  for(int i=0;i<4;i++){
    int rowbase = m0 + 64*wm + 16*i + q*4;
    #pragma unroll
    for(int j=0;j<4;j++){
      int col = n0 + 64*wn + 16*j + r;
      if (col >= Ncols) continue;
      float bv = bias ? bias[col] : 0.f;
      #pragma unroll
      for(int rr=0;rr<4;rr++){
        int row = rowbase + rr;
        if (row >= Mrows) continue;
        float v = acc[i][j][rr] + bv;
        if (declen){ int tt = row % 51; int b = row / 51; if (tt >= declen[b]) v = 0.f; }
        if (outF) outF[(size_t)row*ldo + col] = v;
        else      outH[(size_t)row*ldo + col] = f2bu(v);
      }
    }
  }
}

// ---- persistent fused step loop: 96 blocks (32 fronts + 64 backs, 2 groups) ---------------
__global__ __launch_bounds__(256)
void k_steps(const ushort_t* __restrict__ XWT768, const ushort_t* __restrict__ WHCp,
             const float* __restrict__ xbias,
             const ushort_t* __restrict__ att1b, const float* __restrict__ wfull,
             const ushort_t* __restrict__ encb, const ushort_t* __restrict__ eihR,
             const int* __restrict__ declen,
             ushort_t* __restrict__ hnewb, float* __restrict__ cbuf,
             float* __restrict__ XO,
             ushort_t* __restrict__ xaweb, ushort_t* __restrict__ hallb,
             float* __restrict__ out_alph, int* flags)
{
  __shared__ char pool[150272];
  int blk = blockIdx.x, tid = threadIdx.x;
  int wave = tid>>6, lane = tid&63;
  int q = lane>>4, r = lane&15;

  // flag ids (each on its own 128B line via FLG): A: 0..63, C: 64..127, B: 128..159
  if (blk < 32){
    // ================= FRONT: attention for batch b =================
    int b = blk, g = b>>4;
    float*    att2_s  = (float*)pool;             // 768 floats (att2 | gate-pre)
    float*    wf_s    = (float*)(pool + 3072);    // 512
    float*    alpha_s = (float*)(pool + 5120);    // 196 (pad to 200)
    float*    red_s   = (float*)(pool + 5952);    // 24 floats
    ushort_t* xst     = (ushort_t*)(pool + 6144); // 256 shorts
    for (int i=tid;i<512;i+=256) wf_s[i] = wfull[i];
    __syncthreads();

    for (int t=0;t<51;t++){
      if (tid < 32) while (coh_ldi(flags + FLG(g*32 + tid)) < t+1) __builtin_amdgcn_s_sleep(2);
      __syncthreads();
      {
        const u64_t* src = (const u64_t*)(XO + (size_t)b*768);
        for (int i=tid;i<384;i+=256) ((u64_t*)att2_s)[i] = coh_ld64(src + i);
      }
      __syncthreads();
      float av = -1e30f;
      if (tid < 196){
        const ushort_t* arow = att1b + ((size_t)b*196 + tid)*512;
        float s0=0.f,s1=0.f,s2=0.f,s3=0.f;
        for (int k=0;k<512;k+=8){
          ushort8 v = *(const ushort8*)(arow + k);
          s0 += fmaxf(bu2f(v[0]) + att2_s[k+0], 0.f)*wf_s[k+0];
          s1 += fmaxf(bu2f(v[1]) + att2_s[k+1], 0.f)*wf_s[k+1];
          s2 += fmaxf(bu2f(v[2]) + att2_s[k+2], 0.f)*wf_s[k+2];
          s3 += fmaxf(bu2f(v[3]) + att2_s[k+3], 0.f)*wf_s[k+3];
          s0 += fmaxf(bu2f(v[4]) + att2_s[k+4], 0.f)*wf_s[k+4];
          s1 += fmaxf(bu2f(v[5]) + att2_s[k+5], 0.f)*wf_s[k+5];
          s2 += fmaxf(bu2f(v[6]) + att2_s[k+6], 0.f)*wf_s[k+6];
          s3 += fmaxf(bu2f(v[7]) + att2_s[k+7], 0.f)*wf_s[k+7];
        }
        av = (s0+s1)+(s2+s3);
      }
      float m = av;
      #pragma unroll
      for (int off=32;off>0;off>>=1) m = fmaxf(m, __shfl_down(m, off, 64));
      if ((tid&63)==0) red_s[tid>>6] = m;
      __syncthreads();
      if (tid==0) red_s[16] = fmaxf(fmaxf(red_s[0],red_s[1]), fmaxf(red_s[2],red_s[3]));
      __syncthreads();
      float gmax = red_s[16];
      float ev = (tid<196) ? __expf(av - gmax) : 0.f;
      float ssum = ev;
      #pragma unroll
      for (int off=32;off>0;off>>=1) ssum += __shfl_down(ssum, off, 64);
      if ((tid&63)==0) red_s[20+(tid>>6)] = ssum;
      __syncthreads();
      if (tid==0) red_s[17] = red_s[20]+red_s[21]+red_s[22]+red_s[23];
      __syncthreads();
      float inv = 1.f/red_s[17];
      int mask = (t < declen[b]) ? 1 : 0;
      if (tid<196){
        float al = ev*inv;
        alpha_s[tid] = al;
        out_alph[((size_t)b*51 + t)*196 + tid] = mask ? al : 0.f;
      }
      __syncthreads();
      const ushort_t* eb = encb + (size_t)b*196*256;
      float aw0 = 0.f, aw1 = 0.f;
      for (int p=0;p<196;p+=2){
        aw0 += alpha_s[p]  *bu2f(eb[(size_t)p*256 + tid]);
        aw1 += alpha_s[p+1]*bu2f(eb[(size_t)(p+1)*256 + tid]);
      }
      float gate = sigm(att2_s[512 + tid]);
      xst[tid] = f2bu(gate*(aw0+aw1));
      __syncthreads();
      if (tid < 64){
        u64_t v = *(const u64_t*)(xst + tid*4);
        coh_st64((u64_t*)(xaweb + (size_t)b*256) + tid, v);
      }
      __syncthreads();                               // drain xawe stores
      if (tid==0) coh_sti(flags + FLG(128 + b), t+1);
    }
  } else {
    // ================= BACK: gates + LSTM + h publish, then A-inline =================
    int j = blk-32, g = j>>5, jj = j&31;
    int b0 = g*16;
    int n0b = jj*64;          // gate-col base (reordered d*4+gate layout)
    int n0x = jj*32;          // XO-col base (only jj<24)
    ushort_t* Wh = (ushort_t*)pool;              // [64][520]  Whh^T slice
    ushort_t* Wc = (ushort_t*)(pool + 66560);    // [64][264]  WihBot^T slice
    ushort_t* Wx = (ushort_t*)(pool + 100352);   // [32][520]  XWT slice (jj<24)
    ushort_t* As = (ushort_t*)(pool + 133632);   // [16][520] h-stage / [16][264] xawe-stage
    float*    gl = (float*)(pool + 142080);      // [16][64]
    ushort_t* hst= (ushort_t*)(pool + 146176);   // 256 shorts

    for (int i=tid; i<64*64; i+=256){ int row=i>>6, ko=(i&63)*8;
      *(ushort8*)(Wh + row*520 + ko) = *(const ushort8*)(WHCp + (size_t)(n0b+row)*768 + ko); }
    for (int i=tid; i<64*32; i+=256){ int row=i>>5, ko=(i&31)*8;
      *(ushort8*)(Wc + row*264 + ko) = *(const ushort8*)(WHCp + (size_t)(n0b+row)*768 + 512 + ko); }
    if (jj < 24)
      for (int i=tid; i<32*64; i+=256){ int row=i>>6, ko=(i&63)*8;
        *(ushort8*)(Wx + row*520 + ko) = *(const ushort8*)(XWT768 + (size_t)(n0x+row)*512 + ko); }
    __syncthreads();

    // ---- prologue: h0 -> gwh(t=0) + XO(t=0) + hprev ----
    f32x4 gwh = {0.f,0.f,0.f,0.f};
    float hprev;
    {
      const u64_t* H8 = (const u64_t*)(hnewb + (size_t)b0*512);   // 128 u64 per batch row
      for (int i=tid; i<16*128; i+=256){ int row=i>>7, k4=i&127;
        *(u64_t*)(As + row*520 + k4*4) = coh_ld64(H8 + row*128 + k4); }
      __syncthreads();
      hprev = bu2f(As[(tid>>4)*520 + jj*16 + (tid&15)]);
      f32x4 xo = {0.f,0.f,0.f,0.f};
      #pragma unroll
      for (int kc=0;kc<512;kc+=32){
        FragU a,bw; a.u = *(const ushort8*)(As + r*520 + kc + 8*q);
        bw.u = *(const ushort8*)(Wh + (wave*16 + r)*520 + kc + 8*q);
        gwh = __builtin_amdgcn_mfma_f32_16x16x32_bf16(a.b, bw.b, gwh, 0,0,0);
        if (wave < 2){
          FragU bx; bx.u = *(const ushort8*)(Wx + (wave*16 + r)*520 + kc + 8*q);
          xo = __builtin_amdgcn_mfma_f32_16x16x32_bf16(bx.b, a.b, xo, 0,0,0);  // swapped: out[b=r][4 cols]
        }
      }
      if (jj<24 && wave<2){
        int col0 = n0x + wave*16 + 4*q;
        float vv[4];
        #pragma unroll
        for (int rr=0;rr<4;rr++) vv[rr] = xo[rr] + xbias[col0+rr];
        u64_t* dst = (u64_t*)(XO + (size_t)(b0 + r)*768 + col0);
        coh_st64(dst+0, ((const u64_t*)vv)[0]);
        coh_st64(dst+1, ((const u64_t*)vv)[1]);
      }
      __syncthreads();                               // drain XO stores
      if (tid==0) coh_sti(flags + FLG(g*32 + jj), 1);
    }

    for (int t=0;t<51;t++){
      // eihR prefetch (static, dependency-free)
      float eih[4];
      #pragma unroll
      for (int rr=0;rr<4;rr++){
        int row = 4*q + rr;
        eih[rr] = bu2f(eihR[((size_t)(b0+row)*51 + t)*2048 + n0b + wave*16 + r]);
      }
      // ---- C: wait xawe of this group ----
      if (tid < 16) while (coh_ldi(flags + FLG(128 + b0 + tid)) < t+1) __builtin_amdgcn_s_sleep(2);
      __syncthreads();
      const u64_t* X8 = (const u64_t*)(xaweb + (size_t)b0*256);   // 64 u64 per batch row
      for (int i=tid; i<16*64; i+=256){ int row=i>>6, k4=i&63;
        *(u64_t*)(As + row*264 + k4*4) = coh_ld64(X8 + row*64 + k4); }
      __syncthreads();
      f32x4 cc = {0.f,0.f,0.f,0.f};
      #pragma unroll
      for (int kc=0;kc<256;kc+=32){
        FragU a,bw; a.u = *(const ushort8*)(As + r*264 + kc + 8*q);
        bw.u = *(const ushort8*)(Wc + (wave*16 + r)*264 + kc + 8*q);
        cc = __builtin_amdgcn_mfma_f32_16x16x32_bf16(a.b, bw.b, cc, 0,0,0);
      }
      #pragma unroll
      for (int rr=0;rr<4;rr++)
        gl[(4*q+rr)*64 + wave*16 + r] = gwh[rr] + cc[rr] + eih[rr];
      __syncthreads();
      // LSTM: one (batch,d) item per thread
      int bl = tid>>4, dd = tid&15;
      int b = b0 + bl, d = jj*16 + dd;
      float gi = gl[bl*64 + dd*4+0], gf = gl[bl*64 + dd*4+1];
      float gg = gl[bl*64 + dd*4+2], go = gl[bl*64 + dd*4+3];
      float cold = cbuf[(size_t)b*512 + d];
      float cnew = sigm(gf)*cold + sigm(gi)*ftanh(gg);
      float hnew = sigm(go)*ftanh(cnew);
      hallb[((size_t)b*51 + t)*512 + d] = f2bu(hnew);
      bool upd = (t < declen[b]);
      if (upd) cbuf[(size_t)b*512 + d] = cnew;
      float hkeep = upd ? hnew : hprev;
      hprev = hkeep;
      hst[bl*16 + dd] = f2bu(hkeep);
      __syncthreads();
      if (tid < 64){
        u64_t v = *(const u64_t*)(hst + tid*4);
        int bl2 = tid>>2;
        coh_st64((u64_t*)(hnewb + (size_t)(b0+bl2)*512 + jj*16) + (tid&3), v);
      }
      __syncthreads();                               // drain h stores
      if (tid==0) coh_sti(flags + FLG(64 + g*32 + jj), t+1);
      if (t == 50) break;

      // ---- A-inline: wait all h-slices, load h, gwh(t+1) + XO(t+1) ----
      if (tid < 32) while (coh_ldi(flags + FLG(64 + g*32 + tid)) < t+1) __builtin_amdgcn_s_sleep(2);
      __syncthreads();
      const u64_t* H8 = (const u64_t*)(hnewb + (size_t)b0*512);   // 128 u64 per batch row
      for (int i=tid; i<16*128; i+=256){ int row=i>>7, k4=i&127;
        *(u64_t*)(As + row*520 + k4*4) = coh_ld64(H8 + row*128 + k4); }
      __syncthreads();
      gwh = (f32x4){0.f,0.f,0.f,0.f};
      f32x4 xo = {0.f,0.f,0.f,0.f};
      #pragma unroll
      for (int kc=0;kc<512;kc+=32){
        FragU a,bw; a.u = *(const ushort8*)(As + r*520 + kc + 8*q);
        bw.u = *(const ushort8*)(Wh + (wave*16 + r)*520 + kc + 8*q);
        gwh = __builtin_amdgcn_mfma_f32_16x16x32_bf16(a.b, bw.b, gwh, 0,0,0);
        if (wave < 2){
          FragU bx; bx.u = *(const ushort8*)(Wx + (wave*16 + r)*520 + kc + 8*q);
          xo = __builtin_amdgcn_mfma_f32_16x16x32_bf16(bx.b, a.b, xo, 0,0,0);  // swapped
        }
      }
      if (jj<24 && wave<2){
        int col0 = n0x + wave*16 + 4*q;
        float vv[4];
        #pragma unroll
        for (int rr=0;rr<4;rr++) vv[rr] = xo[rr] + xbias[col0+rr];
        u64_t* dst = (u64_t*)(XO + (size_t)(b0 + r)*768 + col0);
        coh_st64(dst+0, ((const u64_t*)vv)[0]);
        coh_st64(dst+1, ((const u64_t*)vv)[1]);
      }
      __syncthreads();                               // drain XO stores
      if (tid==0) coh_sti(flags + FLG(g*32 + jj), t+2);
    }
  }
}

// -------------------------------------------------------------------------------------------
extern "C" void kernel_launch(void* const* d_in, const int* in_sizes, int n_in,
                              void* d_out, int out_size, void* d_ws, size_t ws_size,
                              hipStream_t stream)
{
  const float* enc   = (const float*)d_in[0];
  const int*   cap   = (const int*)d_in[1];
  const int*   lens  = (const int*)d_in[2];
  const float* Wenc  = (const float*)d_in[3];
  const float* benc  = (const float*)d_in[4];
  const float* Wdec  = (const float*)d_in[5];
  const float* bdec  = (const float*)d_in[6];
  const float* Wfull = (const float*)d_in[7];
  // d_in[8] = b_full_att: softmax-invariant, skipped
  const float* emb   = (const float*)d_in[9];
  const float* Wih   = (const float*)d_in[10];
  const float* bih   = (const float*)d_in[11];
  const float* Whh   = (const float*)d_in[12];
  const float* bhh   = (const float*)d_in[13];
  const float* Winh  = (const float*)d_in[14];
  const float* binh  = (const float*)d_in[15];
  const float* Winc  = (const float*)d_in[16];
  const float* binc  = (const float*)d_in[17];
  const float* Wfb   = (const float*)d_in[18];
  const float* bfb   = (const float*)d_in[19];
  const float* Wfc   = (const float*)d_in[20];
  const float* bfc   = (const float*)d_in[21];
  float* out = (float*)d_out;

  char* w = (char*)d_ws;
  size_t off = 0;
  auto alloc = [&](size_t bytes)->char*{ char* p = w + off; off += (bytes + 255) & ~(size_t)255; return p; };
  ushort_t* WfcT    = (ushort_t*)alloc(20000ull*512*2);  // [20000][512]
  ushort_t* WHCp    = (ushort_t*)alloc(2048ull*768*2);   // rows r=d*4+g; k: [Whh^T | WihBot^T]
  ushort_t* WihTopTp= (ushort_t*)alloc(2048ull*512*2);   // rows r=d*4+g
  ushort_t* XWT768  = (ushort_t*)alloc(768ull*512*2);    // [Wdec^T ; Wfb^T]
  ushort_t* WencT   = (ushort_t*)alloc(512ull*256*2);
  ushort_t* encb    = (ushort_t*)alloc(32ull*196*256*2);
  ushort_t* erowsb  = (ushort_t*)alloc(1632ull*512*2);
  ushort_t* att1b   = (ushort_t*)alloc(6272ull*512*2);
  ushort_t* eihR    = (ushort_t*)alloc(1632ull*2048*2);  // cols r=d*4+g, incl. b_ih + b_hh
  ushort_t* hallb   = (ushort_t*)alloc(1632ull*512*2);
  ushort_t* hnewb   = (ushort_t*)alloc(32ull*512*2);
  ushort_t* xaweb   = (ushort_t*)alloc(32ull*256*2);
  float*    XO      = (float*)alloc(32ull*768*4);
  float*    cbuf    = (float*)alloc(32ull*512*4);
  float*    xbias   = (float*)alloc(768*4);
  float*    bihR    = (float*)alloc(2048*4);
  int*      declen  = (int*)alloc(32*4);
  int*      flags   = (int*)alloc(20480);                // 160 flags x 128B line each

  float* out_preds = out;                        // 32*51*20000
  float* out_cap   = out + 32640000ull;          // 32*52
  float* out_dl    = out_cap + 1664;             // 32
  float* out_alph  = out_dl + 32;                // 32*51*196

  // ---- preamble ----
  k_cvtT<<<dim3(625,16),256,0,stream>>>(Wfc, 20000, WfcT, 512, 0);
  k_cvtT<<<dim3(64,16), 256,0,stream>>>(Whh, 2048, WHCp, 768, 1);                     // k 0..511
  k_cvtT<<<dim3(64,8),  256,0,stream>>>(Wih + 512ull*2048, 2048, WHCp + 512, 768, 1); // k 512..767
  k_cvtT<<<dim3(64,16), 256,0,stream>>>(Wih, 2048, WihTopTp, 512, 1);
  k_cvtT<<<dim3(16,16), 256,0,stream>>>(Wdec, 512, XWT768, 512, 0);
  k_cvtT<<<dim3(8,16),  256,0,stream>>>(Wfb, 256, XWT768 + 512ull*512, 512, 0);
  k_cvtT<<<dim3(16,8),  256,0,stream>>>(Wenc, 512, WencT, 256, 0);
  k_cvt4<<<1568,256,0,stream>>>(enc, encb, 401408);
  k_misc<<<8,256,0,stream>>>(cap, lens, bdec, bfb, bih, bhh, out_cap, out_dl, declen,
                             xbias, bihR, flags);
  k_init<<<32,256,0,stream>>>(enc, Winh, binh, Winc, binc, hnewb, cbuf);
  k_gather<<<1632,256,0,stream>>>(cap, emb, erowsb);
  // att1b = encb @ WencT^T + benc  (6272 x 512, K=256) -> bf16
  k_gemm<<<dim3(4,49),256,0,stream>>>(encb, 256, WencT, 256, 6272, 512, 256,
                                      benc, nullptr, att1b, 512, nullptr, 0,0,0);
  // eihR = erowsb @ WihTopTp^T + (bih+bhh reordered)  (1632 x 2048(reord), K=512) -> bf16
  k_gemm<<<dim3(16,13),256,0,stream>>>(erowsb, 512, WihTopTp, 512, 1632, 2048, 512,
                                       bihR, nullptr, eihR, 2048, nullptr, 0,0,0);

  // ---- fused 51-step recurrence: ONE launch, 96 blocks, dual pipelines ----
  k_steps<<<96,256,0,stream>>>(XWT768, WHCp, xbias, att1b, Wfull, encb, eihR, declen,
                               hnewb, cbuf, XO, xaweb, hallb, out_alph, flags);

  // ---- preds = hallb @ WfcT^T + bfc (masked). M=1632, N=20000, K=512; XCD-aware mapping ---
  k_gemm<<<2080,256,0,stream>>>(hallb, 512, WfcT, 512, 1632, 20000, 512,
                                bfc, out_preds, nullptr, 20000, declen, 13, 157, 1);
}

// Round 8
// 1165.088 us; speedup vs baseline: 2.0541x; 1.3243x over previous
//
#include <hip/hip_runtime.h>
#include <hip/hip_bf16.h>
#include <math.h>
#include <stddef.h>

// B=32, P=196, E=256, A=512, M=512, D=512, V=20000, L=52, T=51
// R8: R7 with the PRED hallb-staging stride fixed (32x128 u64, was 32x64 ->
//     upper half of As2 was garbage => NaN in preds).
//   blk 0-31   FRONT: attention for batch b (8 waves; dot/awe 2-way split)
//   blk 32-95  BACK:  gates+LSTM+h publish, then xo-FIRST A-inline (early flagA)
//   blk 96-252 PRED:  consumer-only; per step t computes preds[32 x 128cols]
//              from coherently-published hallb (replaces the tail GEMM launch)

typedef unsigned short ushort_t;
typedef __bf16 bf16x8 __attribute__((ext_vector_type(8)));
typedef float f32x4 __attribute__((ext_vector_type(4)));
typedef unsigned short ushort8 __attribute__((ext_vector_type(8)));
typedef unsigned short ushort4v __attribute__((ext_vector_type(4)));
typedef unsigned long long u64_t;

union FragU { ushort8 u; bf16x8 b; };

__device__ __forceinline__ unsigned short f2bu(float f){
  union { float f; unsigned int i; } c; c.f = f;
  unsigned int x = c.i;
  unsigned int r = x + 0x7fffu + ((x >> 16) & 1u);
  return (unsigned short)(r >> 16);
}
__device__ __forceinline__ float bu2f(unsigned short u){
  union { unsigned int i; float f; } c; c.i = ((unsigned int)u) << 16; return c.f;
}
__device__ __forceinline__ float sigm(float x){ return 1.f/(1.f+__expf(-x)); }
__device__ __forceinline__ float ftanh(float x){ float e = __expf(2.f*x); return 1.f - 2.f/(e+1.f); }

__device__ __forceinline__ u64_t coh_ld64(const u64_t* p){
  return __hip_atomic_load(p, __ATOMIC_RELAXED, __HIP_MEMORY_SCOPE_AGENT);
}
__device__ __forceinline__ void coh_st64(u64_t* p, u64_t v){
  __hip_atomic_store(p, v, __ATOMIC_RELAXED, __HIP_MEMORY_SCOPE_AGENT);
}
__device__ __forceinline__ int coh_ldi(const int* p){
  return __hip_atomic_load(p, __ATOMIC_RELAXED, __HIP_MEMORY_SCOPE_AGENT);
}
__device__ __forceinline__ void coh_sti(int* p, int v){
  __hip_atomic_store(p, v, __ATOMIC_RELAXED, __HIP_MEMORY_SCOPE_AGENT);
}

// flag f lives at flags[f*32] (one 128B line per flag)
// ids: A 0..63 (backs: h-read-done / XO ready for jj<24), C 64..127 (h ready), B 128..159 (xawe)
#define FLG(f) ((f)*32)

// ---- transpose + fp32->bf16; optional dest-row permute r=d*4+g ----------------------------
__global__ __launch_bounds__(256) void k_cvtT(const float* __restrict__ src, int C,
                                              ushort_t* __restrict__ dst, int ldd, int perm){
  __shared__ float tile[32][33];
  int c0 = blockIdx.x*32, r0 = blockIdx.y*32;
  int tx = threadIdx.x & 31, ty = threadIdx.x >> 5;
  #pragma unroll
  for (int i=0;i<4;i++){ int r = ty + i*8; tile[r][tx] = src[(size_t)(r0+r)*C + c0+tx]; }
  __syncthreads();
  #pragma unroll
  for (int i=0;i<4;i++){
    int c = ty + i*8;
    int row = c0 + c;
    if (perm) row = ((row & 511) << 2) | (row >> 9);   // g*512+d -> d*4+g
    dst[(size_t)row*ldd + r0+tx] = f2bu(tile[tx][c]);
  }
}

// ---- elementwise fp32 -> bf16 -------------------------------------------------------------
__global__ __launch_bounds__(256) void k_cvt4(const float* __restrict__ src,
                                              ushort_t* __restrict__ dst, int n4){
  int i = blockIdx.x*256 + threadIdx.x;
  if (i < n4){
    float4 v = ((const float4*)src)[i];
    ushort4v o; o.x=f2bu(v.x); o.y=f2bu(v.y); o.z=f2bu(v.z); o.w=f2bu(v.w);
    ((ushort4v*)dst)[i] = o;
  }
}

// ---- misc: int outputs, declen, biases, zero flags ----------------------------------------
__global__ __launch_bounds__(256) void k_misc(const int* __restrict__ cap, const int* __restrict__ lens,
                      const float* __restrict__ bdec, const float* __restrict__ bfb,
                      const float* __restrict__ bih, const float* __restrict__ bhh,
                      float* out_cap, float* out_dl, int* declen,
                      float* xbias, float* bihR, int* flags){
  int tid = blockIdx.x*256 + threadIdx.x;
  for (int i=tid; i<5120; i+=2048) flags[i] = 0;
  if (tid < 32*52) out_cap[tid] = (float)cap[tid];
  if (tid < 32){ int dl = lens[tid]-1; out_dl[tid] = (float)dl; declen[tid] = dl; }
  if (tid < 768) xbias[tid] = (tid<512) ? bdec[tid] : bfb[tid-512];
  if (tid < 2048){
    int c = (tid&3)*512 + (tid>>2);   // reordered col r=d*4+g <- original c=g*512+d
    bihR[tid] = bih[c] + bhh[c];      // bhh folded in
  }
}

// ---- init: mean_enc -> h0 (bf16), c0 (fp32) -----------------------------------------------
__global__ __launch_bounds__(256) void k_init(const float* __restrict__ enc,
                     const float* __restrict__ Wih_, const float* __restrict__ bih_,
                     const float* __restrict__ Wic_, const float* __restrict__ bic_,
                     ushort_t* __restrict__ hnewb, float* __restrict__ cbuf){
  int b = blockIdx.x, tid = threadIdx.x;
  __shared__ float mean_s[256];
  const float* eb = enc + (size_t)b*196*256;
  float s = 0.f;
  for (int p=0;p<196;p++) s += eb[p*256 + tid];
  mean_s[tid] = s * (1.f/196.f);
  __syncthreads();
  float h0=0.f,h1=0.f,c0=0.f,c1=0.f;
  for (int k=0;k<256;k++){
    float m = mean_s[k];
    h0 += m*Wih_[k*512+tid];      h1 += m*Wih_[k*512+tid+256];
    c0 += m*Wic_[k*512+tid];      c1 += m*Wic_[k*512+tid+256];
  }
  hnewb[b*512+tid]     = f2bu(h0 + bih_[tid]);
  hnewb[b*512+tid+256] = f2bu(h1 + bih_[tid+256]);
  cbuf[b*512+tid]      = c0 + bic_[tid];
  cbuf[b*512+tid+256]  = c1 + bic_[tid+256];
}

// ---- gather embedding rows -> bf16 --------------------------------------------------------
__global__ __launch_bounds__(256) void k_gather(const int* __restrict__ cap,
                                                const float* __restrict__ emb,
                                                ushort_t* __restrict__ erowsb){
  int row = blockIdx.x; int b = row/51, t = row%51;
  int tok = cap[b*52 + t];
  const float* src = emb + (size_t)tok*512;
  ushort_t* dst = erowsb + (size_t)row*512;
  dst[threadIdx.x]       = f2bu(src[threadIdx.x]);
  dst[threadIdx.x + 256] = f2bu(src[threadIdx.x + 256]);
}

// ---- generic bf16 MFMA GEMM (128x128 tile); preamble only ---------------------------------
#define LDT 40
__global__ __launch_bounds__(256)
void k_gemm(const ushort_t* __restrict__ Ag, int lda,
            const ushort_t* __restrict__ Bg, int ldb,
            int Mrows, int Ncols, int K,
            const float* __restrict__ bias,
            float* __restrict__ outF, ushort_t* __restrict__ outH, int ldo)
{
  __shared__ ushort_t As[128*LDT];
  __shared__ ushort_t Bs[128*LDT];
  int m0 = blockIdx.y*128, n0 = blockIdx.x*128;
  int tid = threadIdx.x;
  int wave = tid>>6, lane = tid&63;
  int wm = wave>>1, wn = wave&1;
  int q = lane>>4, r = lane&15;
  f32x4 acc[4][4];
  f32x4 zero4 = {0.f,0.f,0.f,0.f};
  #pragma unroll
  for(int i=0;i<4;i++){ acc[i][0]=zero4; acc[i][1]=zero4; acc[i][2]=zero4; acc[i][3]=zero4; }

  for (int k0=0; k0<K; k0+=32){
    __syncthreads();
    #pragma unroll
    for (int c=tid; c<512; c+=256){
      int row = c>>2, ko = (c&3)*8;
      ushort8 v = {0,0,0,0,0,0,0,0};
      if (m0+row < Mrows) v = *(const ushort8*)(Ag + (size_t)(m0+row)*lda + k0 + ko);
      *(ushort8*)(As + row*LDT + ko) = v;
      ushort8 wv = {0,0,0,0,0,0,0,0};
      if (n0+row < Ncols) wv = *(const ushort8*)(Bg + (size_t)(n0+row)*ldb + k0 + ko);
      *(ushort8*)(Bs + row*LDT + ko) = wv;
    }
    __syncthreads();
    FragU a[4], bb[4];
    #pragma unroll
    for(int i=0;i<4;i++){
      a[i].u  = *(const ushort8*)(As + (64*wm + 16*i + r)*LDT + 8*q);
      bb[i].u = *(const ushort8*)(Bs + (64*wn + 16*i + r)*LDT + 8*q);
    }
    #pragma unroll
    for(int i=0;i<4;i++)
      #pragma unroll
      for(int j=0;j<4;j++)
        acc[i][j] = __builtin_amdgcn_mfma_f32_16x16x32_bf16(a[i].b, bb[j].b, acc[i][j], 0,0,0);
  }
  #pragma unroll
  for(int i=0;i<4;i++){
    int rowbase = m0 + 64*wm + 16*i + q*4;
    #pragma unroll
    for(int j=0;j<4;j++){
      int col = n0 + 64*wn + 16*j + r;
      if (col >= Ncols) continue;
      float bv = bias ? bias[col] : 0.f;
      #pragma unroll
      for(int rr=0;rr<4;rr++){
        int row = rowbase + rr;
        if (row >= Mrows) continue;
        float v = acc[i][j][rr] + bv;
        if (outF) outF[(size_t)row*ldo + col] = v;
        else      outH[(size_t)row*ldo + col] = f2bu(v);
      }
    }
  }
}

// ---- persistent fused step loop: 253 blocks x 512 threads ---------------------------------
__global__ __launch_bounds__(512)
void k_steps(const ushort_t* __restrict__ XWT768, const ushort_t* __restrict__ WHCp,
             const float* __restrict__ xbias,
             const ushort_t* __restrict__ att1b, const float* __restrict__ wfull,
             const ushort_t* __restrict__ encb, const ushort_t* __restrict__ eihR,
             const int* __restrict__ declen,
             ushort_t* __restrict__ hnewb, float* __restrict__ cbuf,
             float* __restrict__ XO,
             ushort_t* __restrict__ xaweb, ushort_t* __restrict__ hallb,
             float* __restrict__ out_alph,
             const ushort_t* __restrict__ WfcT, const float* __restrict__ bfc,
             float* __restrict__ out_preds, int* flags)
{
  __shared__ char pool[150272];
  int blk = blockIdx.x, tid = threadIdx.x;
  int wave = tid>>6, lane = tid&63;
  int q = lane>>4, r = lane&15;

  if (blk < 32){
    // ================= FRONT: attention for batch b =================
    int b = blk, g = b>>4;
    float*    att2_s = (float*)pool;               // 768
    float*    wf_s   = (float*)(pool + 3072);      // 512
    float*    part_s = (float*)(pool + 5120);      // 2 x 208
    float*    awep_s = (float*)(pool + 6848);      // 512
    float*    alpha_s= (float*)(pool + 8896);      // 200
    float*    red_s  = (float*)(pool + 9728);      // 32
    ushort_t* xst    = (ushort_t*)(pool + 9856);   // 256 shorts
    if (tid < 512) wf_s[tid] = wfull[tid];
    __syncthreads();

    for (int t=0;t<51;t++){
      if (tid < 32) while (coh_ldi(flags + FLG(g*32 + tid)) < t+1) __builtin_amdgcn_s_sleep(1);
      __syncthreads();
      {
        const u64_t* src = (const u64_t*)(XO + (size_t)b*768);
        if (tid < 384) ((u64_t*)att2_s)[tid] = coh_ld64(src + tid);
      }
      __syncthreads();
      // att dot, 2-way k-split
      {
        int ph = tid>>8, p = tid&255;
        if (p < 196){
          const ushort_t* arow = att1b + ((size_t)b*196 + p)*512 + ph*256;
          const float* a2 = att2_s + ph*256;
          const float* wf = wf_s + ph*256;
          float s0=0.f,s1=0.f,s2=0.f,s3=0.f;
          for (int k=0;k<256;k+=8){
            ushort8 v = *(const ushort8*)(arow + k);
            s0 += fmaxf(bu2f(v[0]) + a2[k+0], 0.f)*wf[k+0];
            s1 += fmaxf(bu2f(v[1]) + a2[k+1], 0.f)*wf[k+1];
            s2 += fmaxf(bu2f(v[2]) + a2[k+2], 0.f)*wf[k+2];
            s3 += fmaxf(bu2f(v[3]) + a2[k+3], 0.f)*wf[k+3];
            s0 += fmaxf(bu2f(v[4]) + a2[k+4], 0.f)*wf[k+4];
            s1 += fmaxf(bu2f(v[5]) + a2[k+5], 0.f)*wf[k+5];
            s2 += fmaxf(bu2f(v[6]) + a2[k+6], 0.f)*wf[k+6];
            s3 += fmaxf(bu2f(v[7]) + a2[k+7], 0.f)*wf[k+7];
          }
          part_s[ph*208 + p] = (s0+s1)+(s2+s3);
        }
      }
      __syncthreads();
      float av = -1e30f;
      if (tid < 196) av = part_s[tid] + part_s[208 + tid];
      float m = av;
      #pragma unroll
      for (int off=32;off>0;off>>=1) m = fmaxf(m, __shfl_down(m, off, 64));
      if ((tid&63)==0) red_s[tid>>6] = m;
      __syncthreads();
      if (tid==0){
        float mm = red_s[0];
        #pragma unroll
        for (int i=1;i<8;i++) mm = fmaxf(mm, red_s[i]);
        red_s[16] = mm;
      }
      __syncthreads();
      float gmax = red_s[16];
      float ev = (tid<196) ? __expf(av - gmax) : 0.f;
      float ssum = ev;
      #pragma unroll
      for (int off=32;off>0;off>>=1) ssum += __shfl_down(ssum, off, 64);
      if ((tid&63)==0) red_s[20+(tid>>6)] = ssum;
      __syncthreads();
      if (tid==0){
        float s = 0.f;
        #pragma unroll
        for (int i=0;i<8;i++) s += red_s[20+i];
        red_s[17] = s;
      }
      __syncthreads();
      float inv = 1.f/red_s[17];
      int mask = (t < declen[b]) ? 1 : 0;
      if (tid<196){
        float al = ev*inv;
        alpha_s[tid] = al;
        out_alph[((size_t)b*51 + t)*196 + tid] = mask ? al : 0.f;
      }
      __syncthreads();
      // awe, 2-way p-split
      {
        int e = tid&255, hh = tid>>8;
        const ushort_t* eb = encb + (size_t)b*196*256;
        float a0=0.f, a1=0.f;
        for (int pp=0;pp<98;pp+=2){
          int p0 = hh*98 + pp;
          a0 += alpha_s[p0]  *bu2f(eb[(size_t)p0*256 + e]);
          a1 += alpha_s[p0+1]*bu2f(eb[(size_t)(p0+1)*256 + e]);
        }
        awep_s[hh*256 + e] = a0+a1;
      }
      __syncthreads();
      if (tid < 256){
        float aw = awep_s[tid] + awep_s[256+tid];
        float gate = sigm(att2_s[512 + tid]);
        xst[tid] = f2bu(gate*aw);
      }
      __syncthreads();
      if (tid < 64){
        u64_t v = *(const u64_t*)(xst + tid*4);
        coh_st64((u64_t*)(xaweb + (size_t)b*256) + tid, v);
      }
      __syncthreads();                               // drain xawe stores
      if (tid==0) coh_sti(flags + FLG(128 + b), t+1);
    }
  } else if (blk < 96){
    // ================= BACK: gates+LSTM+publish, xo-first A-inline =================
    int j = blk-32, g = j>>5, jj = j&31;
    int b0 = g*16;
    int n0b = jj*64;          // gate-col base (reordered)
    int n0x = jj*32;          // XO-col base (jj<24)
    ushort_t* Wh = (ushort_t*)pool;              // [64][520]
    ushort_t* Wc = (ushort_t*)(pool + 66560);    // [64][264]
    ushort_t* Wx = (ushort_t*)(pool + 100352);   // [32][520]
    ushort_t* As = (ushort_t*)(pool + 133632);   // [16][520] stage
    float*    gl = (float*)(pool + 142080);      // [16][64]
    ushort_t* hst= (ushort_t*)(pool + 146176);   // 256
    ushort_t* hstA=(ushort_t*)(pool + 146688);   // 256

    for (int i=tid; i<64*64; i+=512){ int row=i>>6, ko=(i&63)*8;
      *(ushort8*)(Wh + row*520 + ko) = *(const ushort8*)(WHCp + (size_t)(n0b+row)*768 + ko); }
    for (int i=tid; i<64*32; i+=512){ int row=i>>5, ko=(i&31)*8;
      *(ushort8*)(Wc + row*264 + ko) = *(const ushort8*)(WHCp + (size_t)(n0b+row)*768 + 512 + ko); }
    if (jj < 24)
      for (int i=tid; i<32*64; i+=512){ int row=i>>6, ko=(i&63)*8;
        *(ushort8*)(Wx + row*520 + ko) = *(const ushort8*)(XWT768 + (size_t)(n0x+row)*512 + ko); }
    __syncthreads();

    f32x4 gwh = {0.f,0.f,0.f,0.f};
    float hprev = 0.f;
    // ---- prologue: stage h0, xo-first XO(0), then gwh(0) ----
    {
      const u64_t* H8 = (const u64_t*)(hnewb + (size_t)b0*512);
      for (int i=tid; i<2048; i+=512){ int row=i>>7, k4=i&127;
        *(u64_t*)(As + row*520 + k4*4) = coh_ld64(H8 + row*128 + k4); }
      __syncthreads();
      if (tid < 256) hprev = bu2f(As[(tid>>4)*520 + jj*16 + (tid&15)]);
      if (jj>=24 && tid==0) coh_sti(flags + FLG(g*32+jj), 1);
      if (jj<24 && wave<2){
        f32x4 xo = {0.f,0.f,0.f,0.f};
        for (int kc=0;kc<512;kc+=32){
          FragU a,bx;
          a.u  = *(const ushort8*)(As + r*520 + kc + 8*q);
          bx.u = *(const ushort8*)(Wx + (wave*16 + r)*520 + kc + 8*q);
          xo = __builtin_amdgcn_mfma_f32_16x16x32_bf16(bx.b, a.b, xo, 0,0,0);
        }
        int col0 = n0x + wave*16 + 4*q;
        float vv[4];
        #pragma unroll
        for (int rr=0;rr<4;rr++) vv[rr] = xo[rr] + xbias[col0+rr];
        u64_t* dst = (u64_t*)(XO + (size_t)(b0 + r)*768 + col0);
        coh_st64(dst+0, ((const u64_t*)vv)[0]);
        coh_st64(dst+1, ((const u64_t*)vv)[1]);
      }
      __syncthreads();                               // drain XO stores
      if (jj<24 && tid==0) coh_sti(flags + FLG(g*32+jj), 1);
      if (wave < 4){
        for (int kc=0;kc<512;kc+=32){
          FragU a,bw;
          a.u  = *(const ushort8*)(As + r*520 + kc + 8*q);
          bw.u = *(const ushort8*)(Wh + (wave*16 + r)*520 + kc + 8*q);
          gwh = __builtin_amdgcn_mfma_f32_16x16x32_bf16(a.b, bw.b, gwh, 0,0,0);
        }
      }
    }

    for (int t=0;t<51;t++){
      float eih[4] = {0.f,0.f,0.f,0.f};
      if (wave < 4){
        #pragma unroll
        for (int rr=0;rr<4;rr++){
          int row = 4*q + rr;
          eih[rr] = bu2f(eihR[((size_t)(b0+row)*51 + t)*2048 + n0b + wave*16 + r]);
        }
      }
      // ---- C: wait xawe ----
      if (tid < 16) while (coh_ldi(flags + FLG(128 + b0 + tid)) < t+1) __builtin_amdgcn_s_sleep(1);
      __syncthreads();
      const u64_t* X8 = (const u64_t*)(xaweb + (size_t)b0*256);
      for (int i=tid; i<1024; i+=512){ int row=i>>6, k4=i&63;
        *(u64_t*)(As + row*264 + k4*4) = coh_ld64(X8 + row*64 + k4); }
      __syncthreads();
      if (wave < 4){
        f32x4 cc = {0.f,0.f,0.f,0.f};
        for (int kc=0;kc<256;kc+=32){
          FragU a,bw;
          a.u  = *(const ushort8*)(As + r*264 + kc + 8*q);
          bw.u = *(const ushort8*)(Wc + (wave*16 + r)*264 + kc + 8*q);
          cc = __builtin_amdgcn_mfma_f32_16x16x32_bf16(a.b, bw.b, cc, 0,0,0);
        }
        #pragma unroll
        for (int rr=0;rr<4;rr++)
          gl[(4*q+rr)*64 + wave*16 + r] = gwh[rr] + cc[rr] + eih[rr];
      }
      __syncthreads();
      if (tid < 256){
        int bl = tid>>4, dd = tid&15;
        int bb = b0 + bl, d = jj*16 + dd;
        float gi = gl[bl*64 + dd*4+0], gf = gl[bl*64 + dd*4+1];
        float gg = gl[bl*64 + dd*4+2], go = gl[bl*64 + dd*4+3];
        float cold = cbuf[(size_t)bb*512 + d];
        float cnew = sigm(gf)*cold + sigm(gi)*ftanh(gg);
        float hnew = sigm(go)*ftanh(cnew);
        bool upd = (t < declen[bb]);
        if (upd) cbuf[(size_t)bb*512 + d] = cnew;
        float hkeep = upd ? hnew : hprev;
        hprev = hkeep;
        hst[tid]  = f2bu(hkeep);
        hstA[tid] = f2bu(hnew);
      }
      __syncthreads();
      if (tid < 64){
        int bl2 = tid>>2, o = tid&3;
        coh_st64((u64_t*)(hnewb + (size_t)(b0+bl2)*512 + jj*16) + o,
                 *(const u64_t*)(hst + tid*4));
        coh_st64((u64_t*)(hallb + ((size_t)((b0+bl2)*51 + t))*512 + jj*16) + o,
                 *(const u64_t*)(hstA + tid*4));
      }
      __syncthreads();                               // drain h/hallb stores
      if (tid==0) coh_sti(flags + FLG(64 + g*32 + jj), t+1);
      if (t == 50) break;

      // ---- A-inline for t+1: stage h, publish-read-done / xo-first, then gwh ----
      if (tid < 32) while (coh_ldi(flags + FLG(64 + g*32 + tid)) < t+1) __builtin_amdgcn_s_sleep(1);
      __syncthreads();
      const u64_t* H8 = (const u64_t*)(hnewb + (size_t)b0*512);
      for (int i=tid; i<2048; i+=512){ int row=i>>7, k4=i&127;
        *(u64_t*)(As + row*520 + k4*4) = coh_ld64(H8 + row*128 + k4); }
      __syncthreads();
      if (jj>=24 && tid==0) coh_sti(flags + FLG(g*32+jj), t+2);
      if (jj<24 && wave<2){
        f32x4 xo = {0.f,0.f,0.f,0.f};
        for (int kc=0;kc<512;kc+=32){
          FragU a,bx;
          a.u  = *(const ushort8*)(As + r*520 + kc + 8*q);
          bx.u = *(const ushort8*)(Wx + (wave*16 + r)*520 + kc + 8*q);
          xo = __builtin_amdgcn_mfma_f32_16x16x32_bf16(bx.b, a.b, xo, 0,0,0);
        }
        int col0 = n0x + wave*16 + 4*q;
        float vv[4];
        #pragma unroll
        for (int rr=0;rr<4;rr++) vv[rr] = xo[rr] + xbias[col0+rr];
        u64_t* dst = (u64_t*)(XO + (size_t)(b0 + r)*768 + col0);
        coh_st64(dst+0, ((const u64_t*)vv)[0]);
        coh_st64(dst+1, ((const u64_t*)vv)[1]);
      }
      __syncthreads();                               // drain XO stores
      if (jj<24 && tid==0) coh_sti(flags + FLG(g*32+jj), t+2);
      gwh = (f32x4){0.f,0.f,0.f,0.f};
      if (wave < 4){
        for (int kc=0;kc<512;kc+=32){
          FragU a,bw;
          a.u  = *(const ushort8*)(As + r*520 + kc + 8*q);
          bw.u = *(const ushort8*)(Wh + (wave*16 + r)*520 + kc + 8*q);
          gwh = __builtin_amdgcn_mfma_f32_16x16x32_bf16(a.b, bw.b, gwh, 0,0,0);
        }
      }
    }
  } else {
    // ================= PRED: per-step logits tile, consumer-only =================
    int cs = blk - 96;
    int n0 = cs*128;
    ushort_t* As2 = (ushort_t*)pool;             // [32][520]
    ushort_t* Bs2 = (ushort_t*)(pool + 66560);   // [128][40]
    int til0 = wave*2, til1 = wave*2+1;
    int mt0 = til0>>3, nt0 = til0&7;
    int mt1 = til1>>3, nt1 = til1&7;

    for (int t=0;t<51;t++){
      if (tid < 64) while (coh_ldi(flags + FLG(64 + tid)) < t+1) __builtin_amdgcn_s_sleep(4);
      __syncthreads();
      // stage A: 32 hallb rows for step t (coherent). 512 bf16 = 128 u64 per row!
      for (int i=tid; i<4096; i+=512){
        int row = i>>7, k4 = i&127;
        *(u64_t*)(As2 + row*520 + k4*4) =
          coh_ld64((const u64_t*)hallb + (size_t)(row*51 + t)*128 + k4);
      }
      __syncthreads();
      f32x4 acc0 = {0.f,0.f,0.f,0.f}, acc1 = {0.f,0.f,0.f,0.f};
      for (int kc=0; kc<512; kc+=32){
        {
          int row = tid>>2, ko = (tid&3)*8;
          ushort8 wv = {0,0,0,0,0,0,0,0};
          int gr = n0 + row;
          if (gr < 20000) wv = *(const ushort8*)(WfcT + (size_t)gr*512 + kc + ko);
          *(ushort8*)(Bs2 + row*40 + ko) = wv;
        }
        __syncthreads();
        FragU a0,b0f,a1,b1f;
        a0.u  = *(const ushort8*)(As2 + (mt0*16 + r)*520 + kc + 8*q);
        b0f.u = *(const ushort8*)(Bs2 + (nt0*16 + r)*40 + 8*q);
        acc0 = __builtin_amdgcn_mfma_f32_16x16x32_bf16(a0.b, b0f.b, acc0, 0,0,0);
        a1.u  = *(const ushort8*)(As2 + (mt1*16 + r)*520 + kc + 8*q);
        b1f.u = *(const ushort8*)(Bs2 + (nt1*16 + r)*40 + 8*q);
        acc1 = __builtin_amdgcn_mfma_f32_16x16x32_bf16(a1.b, b1f.b, acc1, 0,0,0);
        __syncthreads();
      }
      // epilogue: out_preds[(b*51+t)*20000 + col]
      {
        int colG = n0 + nt0*16 + r;
        if (colG < 20000){
          float bv = bfc[colG];
          #pragma unroll
          for (int rr=0;rr<4;rr++){
            int bidx = mt0*16 + 4*q + rr;
            float v = acc0[rr] + bv;
            if (t >= declen[bidx]) v = 0.f;
            out_preds[((size_t)(bidx*51 + t))*20000 + colG] = v;
          }
        }
      }
      {
        int colG = n0 + nt1*16 + r;
        if (colG < 20000){
          float bv = bfc[colG];
          #pragma unroll
          for (int rr=0;rr<4;rr++){
            int bidx = mt1*16 + 4*q + rr;
            float v = acc1[rr] + bv;
            if (t >= declen[bidx]) v = 0.f;
            out_preds[((size_t)(bidx*51 + t))*20000 + colG] = v;
          }
        }
      }
    }
  }
}

// -------------------------------------------------------------------------------------------
extern "C" void kernel_launch(void* const* d_in, const int* in_sizes, int n_in,
                              void* d_out, int out_size, void* d_ws, size_t ws_size,
                              hipStream_t stream)
{
  const float* enc   = (const float*)d_in[0];
  const int*   cap   = (const int*)d_in[1];
  const int*   lens  = (const int*)d_in[2];
  const float* Wenc  = (const float*)d_in[3];
  const float* benc  = (const float*)d_in[4];
  const float* Wdec  = (const float*)d_in[5];
  const float* bdec  = (const float*)d_in[6];
  const float* Wfull = (const float*)d_in[7];
  // d_in[8] = b_full_att: softmax-invariant, skipped
  const float* emb   = (const float*)d_in[9];
  const float* Wih   = (const float*)d_in[10];
  const float* bih   = (const float*)d_in[11];
  const float* Whh   = (const float*)d_in[12];
  const float* bhh   = (const float*)d_in[13];
  const float* Winh  = (const float*)d_in[14];
  const float* binh  = (const float*)d_in[15];
  const float* Winc  = (const float*)d_in[16];
  const float* binc  = (const float*)d_in[17];
  const float* Wfb   = (const float*)d_in[18];
  const float* bfb   = (const float*)d_in[19];
  const float* Wfc   = (const float*)d_in[20];
  const float* bfc   = (const float*)d_in[21];
  float* out = (float*)d_out;

  char* w = (char*)d_ws;
  size_t off = 0;
  auto alloc = [&](size_t bytes)->char*{ char* p = w + off; off += (bytes + 255) & ~(size_t)255; return p; };
  ushort_t* WfcT    = (ushort_t*)alloc(20000ull*512*2);  // [20000][512]
  ushort_t* WHCp    = (ushort_t*)alloc(2048ull*768*2);   // rows r=d*4+g; k: [Whh^T | WihBot^T]
  ushort_t* WihTopTp= (ushort_t*)alloc(2048ull*512*2);   // rows r=d*4+g
  ushort_t* XWT768  = (ushort_t*)alloc(768ull*512*2);    // [Wdec^T ; Wfb^T]
  ushort_t* WencT   = (ushort_t*)alloc(512ull*256*2);
  ushort_t* encb    = (ushort_t*)alloc(32ull*196*256*2);
  ushort_t* erowsb  = (ushort_t*)alloc(1632ull*512*2);
  ushort_t* att1b   = (ushort_t*)alloc(6272ull*512*2);
  ushort_t* eihR    = (ushort_t*)alloc(1632ull*2048*2);  // cols r=d*4+g, incl. b_ih + b_hh
  ushort_t* hallb   = (ushort_t*)alloc(1632ull*512*2);
  ushort_t* hnewb   = (ushort_t*)alloc(32ull*512*2);
  ushort_t* xaweb   = (ushort_t*)alloc(32ull*256*2);
  float*    XO      = (float*)alloc(32ull*768*4);
  float*    cbuf    = (float*)alloc(32ull*512*4);
  float*    xbias   = (float*)alloc(768*4);
  float*    bihR    = (float*)alloc(2048*4);
  int*      declen  = (int*)alloc(32*4);
  int*      flags   = (int*)alloc(20480);                // 160 flags x 128B line

  float* out_preds = out;                        // 32*51*20000
  float* out_cap   = out + 32640000ull;          // 32*52
  float* out_dl    = out_cap + 1664;             // 32
  float* out_alph  = out_dl + 32;                // 32*51*196

  // ---- preamble ----
  k_cvtT<<<dim3(625,16),256,0,stream>>>(Wfc, 20000, WfcT, 512, 0);
  k_cvtT<<<dim3(64,16), 256,0,stream>>>(Whh, 2048, WHCp, 768, 1);                     // k 0..511
  k_cvtT<<<dim3(64,8),  256,0,stream>>>(Wih + 512ull*2048, 2048, WHCp + 512, 768, 1); // k 512..767
  k_cvtT<<<dim3(64,16), 256,0,stream>>>(Wih, 2048, WihTopTp, 512, 1);
  k_cvtT<<<dim3(16,16), 256,0,stream>>>(Wdec, 512, XWT768, 512, 0);
  k_cvtT<<<dim3(8,16),  256,0,stream>>>(Wfb, 256, XWT768 + 512ull*512, 512, 0);
  k_cvtT<<<dim3(16,8),  256,0,stream>>>(Wenc, 512, WencT, 256, 0);
  k_cvt4<<<1568,256,0,stream>>>(enc, encb, 401408);
  k_misc<<<8,256,0,stream>>>(cap, lens, bdec, bfb, bih, bhh, out_cap, out_dl, declen,
                             xbias, bihR, flags);
  k_init<<<32,256,0,stream>>>(enc, Winh, binh, Winc, binc, hnewb, cbuf);
  k_gather<<<1632,256,0,stream>>>(cap, emb, erowsb);
  // att1b = encb @ WencT^T + benc  (6272 x 512, K=256) -> bf16
  k_gemm<<<dim3(4,49),256,0,stream>>>(encb, 256, WencT, 256, 6272, 512, 256,
                                      benc, nullptr, att1b, 512);
  // eihR = erowsb @ WihTopTp^T + (bih+bhh reordered)  (1632 x 2048(reord), K=512) -> bf16
  k_gemm<<<dim3(16,13),256,0,stream>>>(erowsb, 512, WihTopTp, 512, 1632, 2048, 512,
                                       bihR, nullptr, eihR, 2048);

  // ---- fused 51-step recurrence + in-kernel preds: ONE launch, 253 blocks x 512 thr ----
  k_steps<<<253,512,0,stream>>>(XWT768, WHCp, xbias, att1b, Wfull, encb, eihR, declen,
                                hnewb, cbuf, XO, xaweb, hallb, out_alph,
                                WfcT, bfc, out_preds, flags);
}

// Round 9
// 1115.973 us; speedup vs baseline: 2.1445x; 1.0440x over previous
//
#include <hip/hip_runtime.h>
#include <hip/hip_bf16.h>
#include <math.h>
#include <stddef.h>

// B=32, P=196, E=256, A=512, M=512, D=512, V=20000, L=52, T=51
// R9: R8 + preamble compaction + chain shave.
//   - Wfc->WfcT conversion moved into PRED prologue (each block converts its
//     own 128-row slice; off the critical chain; deletes the 10000-blk cvtT)
//   - 10 small preamble kernels fused into ONE k_pre1 (role-split by blockIdx)
//   - front softmax: 3 syncthreads (was 5); out_alph store deferred off-chain
//   Structure: 253 blocks x 512 thr: 0-31 FRONT attn, 32-95 BACK gates+LSTM+
//   xo-first A-inline, 96-252 PRED per-step logits consumers.

typedef unsigned short ushort_t;
typedef __bf16 bf16x8 __attribute__((ext_vector_type(8)));
typedef float f32x4 __attribute__((ext_vector_type(4)));
typedef unsigned short ushort8 __attribute__((ext_vector_type(8)));
typedef unsigned short ushort4v __attribute__((ext_vector_type(4)));
typedef unsigned long long u64_t;

union FragU { ushort8 u; bf16x8 b; };

__device__ __forceinline__ unsigned short f2bu(float f){
  union { float f; unsigned int i; } c; c.f = f;
  unsigned int x = c.i;
  unsigned int r = x + 0x7fffu + ((x >> 16) & 1u);
  return (unsigned short)(r >> 16);
}
__device__ __forceinline__ float bu2f(unsigned short u){
  union { unsigned int i; float f; } c; c.i = ((unsigned int)u) << 16; return c.f;
}
__device__ __forceinline__ float sigm(float x){ return 1.f/(1.f+__expf(-x)); }
__device__ __forceinline__ float ftanh(float x){ float e = __expf(2.f*x); return 1.f - 2.f/(e+1.f); }

__device__ __forceinline__ u64_t coh_ld64(const u64_t* p){
  return __hip_atomic_load(p, __ATOMIC_RELAXED, __HIP_MEMORY_SCOPE_AGENT);
}
__device__ __forceinline__ void coh_st64(u64_t* p, u64_t v){
  __hip_atomic_store(p, v, __ATOMIC_RELAXED, __HIP_MEMORY_SCOPE_AGENT);
}
__device__ __forceinline__ int coh_ldi(const int* p){
  return __hip_atomic_load(p, __ATOMIC_RELAXED, __HIP_MEMORY_SCOPE_AGENT);
}
__device__ __forceinline__ void coh_sti(int* p, int v){
  __hip_atomic_store(p, v, __ATOMIC_RELAXED, __HIP_MEMORY_SCOPE_AGENT);
}

// flag f lives at flags[f*32] (one 128B line per flag)
// ids: A 0..63 (backs: h-read-done / XO ready for jj<24), C 64..127 (h ready), B 128..159 (xawe)
#define FLG(f) ((f)*32)

// ================= fused preamble: role-split device bodies =================
__device__ __forceinline__ void d_cvtT(const float* __restrict__ src, int C,
                                       ushort_t* __restrict__ dst, int ldd, int perm,
                                       int bx, int by, int tid, float* tile /*32x33*/){
  int c0 = bx*32, r0 = by*32;
  int tx = tid & 31, ty = tid >> 5;
  #pragma unroll
  for (int i=0;i<4;i++){ int r = ty + i*8; tile[r*33+tx] = src[(size_t)(r0+r)*C + c0+tx]; }
  __syncthreads();
  #pragma unroll
  for (int i=0;i<4;i++){
    int c = ty + i*8;
    int row = c0 + c;
    if (perm) row = ((row & 511) << 2) | (row >> 9);   // g*512+d -> d*4+g
    dst[(size_t)row*ldd + r0+tx] = f2bu(tile[tx*33+c]);
  }
}

__global__ __launch_bounds__(256)
void k_pre1(const float* __restrict__ Whh, const float* __restrict__ Wih,
            const float* __restrict__ Wdec, const float* __restrict__ Wfb,
            const float* __restrict__ Wenc, const float* __restrict__ enc,
            const int* __restrict__ cap, const int* __restrict__ lens,
            const float* __restrict__ bdec, const float* __restrict__ bfb,
            const float* __restrict__ bih, const float* __restrict__ bhh,
            const float* __restrict__ Winh, const float* __restrict__ binh,
            const float* __restrict__ Winc, const float* __restrict__ binc,
            const float* __restrict__ emb,
            ushort_t* WHCp, ushort_t* WihTopTp, ushort_t* XWT768, ushort_t* WencT,
            ushort_t* encb, float* out_cap, float* out_dl, int* declen,
            float* xbias, float* bihR, int* flags,
            ushort_t* hnewb, float* cbuf, ushort_t* erowsb)
{
  __shared__ float smem_f[1056];
  int blk = blockIdx.x, tid = threadIdx.x;
  if (blk < 1024){        d_cvtT(Whh, 2048, WHCp, 768, 1, blk&63, blk>>6, tid, smem_f); }
  else if (blk < 1536){   int i=blk-1024; d_cvtT(Wih + 512ull*2048, 2048, WHCp+512, 768, 1, i&63, i>>6, tid, smem_f); }
  else if (blk < 2560){   int i=blk-1536; d_cvtT(Wih, 2048, WihTopTp, 512, 1, i&63, i>>6, tid, smem_f); }
  else if (blk < 2816){   int i=blk-2560; d_cvtT(Wdec, 512, XWT768, 512, 0, i&15, i>>4, tid, smem_f); }
  else if (blk < 2944){   int i=blk-2816; d_cvtT(Wfb, 256, XWT768 + 512ull*512, 512, 0, i&7, i>>3, tid, smem_f); }
  else if (blk < 3072){   int i=blk-2944; d_cvtT(Wenc, 512, WencT, 256, 0, i&15, i>>4, tid, smem_f); }
  else if (blk < 4640){   // enc fp32 -> bf16 (float4 granules)
    int i = (blk-3072)*256 + tid;
    if (i < 401408){
      float4 v = ((const float4*)enc)[i];
      ushort4v o; o.x=f2bu(v.x); o.y=f2bu(v.y); o.z=f2bu(v.z); o.w=f2bu(v.w);
      ((ushort4v*)encb)[i] = o;
    }
  }
  else if (blk < 4648){   // misc
    int gtid = (blk-4640)*256 + tid;
    for (int i=gtid; i<5120; i+=2048) flags[i] = 0;
    if (gtid < 32*52) out_cap[gtid] = (float)cap[gtid];
    if (gtid < 32){ int dl = lens[gtid]-1; out_dl[gtid] = (float)dl; declen[gtid] = dl; }
    if (gtid < 768) xbias[gtid] = (gtid<512) ? bdec[gtid] : bfb[gtid-512];
    if (gtid < 2048){
      int c = (gtid&3)*512 + (gtid>>2);
      bihR[gtid] = bih[c] + bhh[c];
    }
  }
  else if (blk < 4680){   // init: mean_enc -> h0 (bf16), c0 (fp32)
    int b = blk-4648;
    float* mean_s = smem_f;
    const float* eb = enc + (size_t)b*196*256;
    float s = 0.f;
    for (int p=0;p<196;p++) s += eb[p*256 + tid];
    mean_s[tid] = s * (1.f/196.f);
    __syncthreads();
    float h0=0.f,h1=0.f,c0=0.f,c1=0.f;
    for (int k=0;k<256;k++){
      float m = mean_s[k];
      h0 += m*Winh[k*512+tid];      h1 += m*Winh[k*512+tid+256];
      c0 += m*Winc[k*512+tid];      c1 += m*Winc[k*512+tid+256];
    }
    hnewb[b*512+tid]     = f2bu(h0 + binh[tid]);
    hnewb[b*512+tid+256] = f2bu(h1 + binh[tid+256]);
    cbuf[b*512+tid]      = c0 + binc[tid];
    cbuf[b*512+tid+256]  = c1 + binc[tid+256];
  }
  else {                  // gather embedding rows -> bf16
    int row = blk-4680;
    int b = row/51, t = row%51;
    int tok = cap[b*52 + t];
    const float* src = emb + (size_t)tok*512;
    ushort_t* dst = erowsb + (size_t)row*512;
    dst[tid]       = f2bu(src[tid]);
    dst[tid + 256] = f2bu(src[tid + 256]);
  }
}

// ---- generic bf16 MFMA GEMM (128x128 tile); preamble only ---------------------------------
#define LDT 40
__global__ __launch_bounds__(256)
void k_gemm(const ushort_t* __restrict__ Ag, int lda,
            const ushort_t* __restrict__ Bg, int ldb,
            int Mrows, int Ncols, int K,
            const float* __restrict__ bias,
            float* __restrict__ outF, ushort_t* __restrict__ outH, int ldo)
{
  __shared__ ushort_t As[128*LDT];
  __shared__ ushort_t Bs[128*LDT];
  int m0 = blockIdx.y*128, n0 = blockIdx.x*128;
  int tid = threadIdx.x;
  int wave = tid>>6, lane = tid&63;
  int wm = wave>>1, wn = wave&1;
  int q = lane>>4, r = lane&15;
  f32x4 acc[4][4];
  f32x4 zero4 = {0.f,0.f,0.f,0.f};
  #pragma unroll
  for(int i=0;i<4;i++){ acc[i][0]=zero4; acc[i][1]=zero4; acc[i][2]=zero4; acc[i][3]=zero4; }

  for (int k0=0; k0<K; k0+=32){
    __syncthreads();
    #pragma unroll
    for (int c=tid; c<512; c+=256){
      int row = c>>2, ko = (c&3)*8;
      ushort8 v = {0,0,0,0,0,0,0,0};
      if (m0+row < Mrows) v = *(const ushort8*)(Ag + (size_t)(m0+row)*lda + k0 + ko);
      *(ushort8*)(As + row*LDT + ko) = v;
      ushort8 wv = {0,0,0,0,0,0,0,0};
      if (n0+row < Ncols) wv = *(const ushort8*)(Bg + (size_t)(n0+row)*ldb + k0 + ko);
      *(ushort8*)(Bs + row*LDT + ko) = wv;
    }
    __syncthreads();
    FragU a[4], bb[4];
    #pragma unroll
    for(int i=0;i<4;i++){
      a[i].u  = *(const ushort8*)(As + (64*wm + 16*i + r)*LDT + 8*q);
      bb[i].u = *(const ushort8*)(Bs + (64*wn + 16*i + r)*LDT + 8*q);
    }
    #pragma unroll
    for(int i=0;i<4;i++)
      #pragma unroll
      for(int j=0;j<4;j++)
        acc[i][j] = __builtin_amdgcn_mfma_f32_16x16x32_bf16(a[i].b, bb[j].b, acc[i][j], 0,0,0);
  }
  #pragma unroll
  for(int i=0;i<4;i++){
    int rowbase = m0 + 64*wm + 16*i + q*4;
    #pragma unroll
    for(int j=0;j<4;j++){
      int col = n0 + 64*wn + 16*j + r;
      if (col >= Ncols) continue;
      float bv = bias ? bias[col] : 0.f;
      #pragma unroll
      for(int rr=0;rr<4;rr++){
        int row = rowbase + rr;
        if (row >= Mrows) continue;
        float v = acc[i][j][rr] + bv;
        if (outF) outF[(size_t)row*ldo + col] = v;
        else      outH[(size_t)row*ldo + col] = f2bu(v);
      }
    }
  }
}

// ---- persistent fused step loop: 253 blocks x 512 threads ---------------------------------
__global__ __launch_bounds__(512)
void k_steps(const ushort_t* __restrict__ XWT768, const ushort_t* __restrict__ WHCp,
             const float* __restrict__ xbias,
             const ushort_t* __restrict__ att1b, const float* __restrict__ wfull,
             const ushort_t* __restrict__ encb, const ushort_t* __restrict__ eihR,
             const int* __restrict__ declen,
             ushort_t* __restrict__ hnewb, float* __restrict__ cbuf,
             float* __restrict__ XO,
             ushort_t* __restrict__ xaweb, ushort_t* __restrict__ hallb,
             float* __restrict__ out_alph,
             const float* __restrict__ Wfc, ushort_t* __restrict__ WfcT,
             const float* __restrict__ bfc,
             float* __restrict__ out_preds, int* flags)
{
  __shared__ char pool[150272];
  int blk = blockIdx.x, tid = threadIdx.x;
  int wave = tid>>6, lane = tid&63;
  int q = lane>>4, r = lane&15;

  if (blk < 32){
    // ================= FRONT: attention for batch b =================
    int b = blk, g = b>>4;
    float*    att2_s = (float*)pool;               // 768
    float*    wf_s   = (float*)(pool + 3072);      // 512
    float*    part_s = (float*)(pool + 5120);      // 2 x 208
    float*    awep_s = (float*)(pool + 6848);      // 512
    float*    alpha_s= (float*)(pool + 8896);      // 200
    float*    red_s  = (float*)(pool + 9728);      // 32
    ushort_t* xst    = (ushort_t*)(pool + 9856);   // 256 shorts
    if (tid < 512) wf_s[tid] = wfull[tid];
    __syncthreads();

    for (int t=0;t<51;t++){
      if (tid < 32) while (coh_ldi(flags + FLG(g*32 + tid)) < t+1) __builtin_amdgcn_s_sleep(1);
      __syncthreads();
      {
        const u64_t* src = (const u64_t*)(XO + (size_t)b*768);
        if (tid < 384) ((u64_t*)att2_s)[tid] = coh_ld64(src + tid);
      }
      __syncthreads();
      // att dot, 2-way k-split
      {
        int ph = tid>>8, p = tid&255;
        if (p < 196){
          const ushort_t* arow = att1b + ((size_t)b*196 + p)*512 + ph*256;
          const float* a2 = att2_s + ph*256;
          const float* wf = wf_s + ph*256;
          float s0=0.f,s1=0.f,s2=0.f,s3=0.f;
          for (int k=0;k<256;k+=8){
            ushort8 v = *(const ushort8*)(arow + k);
            s0 += fmaxf(bu2f(v[0]) + a2[k+0], 0.f)*wf[k+0];
            s1 += fmaxf(bu2f(v[1]) + a2[k+1], 0.f)*wf[k+1];
            s2 += fmaxf(bu2f(v[2]) + a2[k+2], 0.f)*wf[k+2];
            s3 += fmaxf(bu2f(v[3]) + a2[k+3], 0.f)*wf[k+3];
            s0 += fmaxf(bu2f(v[4]) + a2[k+4], 0.f)*wf[k+4];
            s1 += fmaxf(bu2f(v[5]) + a2[k+5], 0.f)*wf[k+5];
            s2 += fmaxf(bu2f(v[6]) + a2[k+6], 0.f)*wf[k+6];
            s3 += fmaxf(bu2f(v[7]) + a2[k+7], 0.f)*wf[k+7];
          }
          part_s[ph*208 + p] = (s0+s1)+(s2+s3);
        }
      }
      __syncthreads();
      float av = -1e30f;
      if (tid < 196) av = part_s[tid] + part_s[208 + tid];
      float m = av;
      #pragma unroll
      for (int off=32;off>0;off>>=1) m = fmaxf(m, __shfl_down(m, off, 64));
      if ((tid&63)==0) red_s[tid>>6] = m;
      __syncthreads();
      float gmax = red_s[0];
      #pragma unroll
      for (int i=1;i<8;i++) gmax = fmaxf(gmax, red_s[i]);
      float ev = (tid<196) ? __expf(av - gmax) : 0.f;
      float ssum = ev;
      #pragma unroll
      for (int off=32;off>0;off>>=1) ssum += __shfl_down(ssum, off, 64);
      if ((tid&63)==0) red_s[8+(tid>>6)] = ssum;
      __syncthreads();
      float stot = red_s[8];
      #pragma unroll
      for (int i=9;i<16;i++) stot += red_s[i];
      float inv = 1.f/stot;
      float al = (tid<196) ? ev*inv : 0.f;
      if (tid<196) alpha_s[tid] = al;
      __syncthreads();
      // awe, 2-way p-split
      {
        int e = tid&255, hh = tid>>8;
        const ushort_t* eb = encb + (size_t)b*196*256;
        float a0=0.f, a1=0.f;
        for (int pp=0;pp<98;pp+=2){
          int p0 = hh*98 + pp;
          a0 += alpha_s[p0]  *bu2f(eb[(size_t)p0*256 + e]);
          a1 += alpha_s[p0+1]*bu2f(eb[(size_t)(p0+1)*256 + e]);
        }
        awep_s[hh*256 + e] = a0+a1;
      }
      __syncthreads();
      if (tid < 256){
        float aw = awep_s[tid] + awep_s[256+tid];
        float gate = sigm(att2_s[512 + tid]);
        xst[tid] = f2bu(gate*aw);
      }
      __syncthreads();
      if (tid < 64){
        u64_t v = *(const u64_t*)(xst + tid*4);
        coh_st64((u64_t*)(xaweb + (size_t)b*256) + tid, v);
      }
      __syncthreads();                               // drain xawe stores
      if (tid==0) coh_sti(flags + FLG(128 + b), t+1);
      // deferred, off-chain: alpha output
      if (tid<196){
        int mask = (t < declen[b]) ? 1 : 0;
        out_alph[((size_t)b*51 + t)*196 + tid] = mask ? al : 0.f;
      }
    }
  } else if (blk < 96){
    // ================= BACK: gates+LSTM+publish, xo-first A-inline =================
    int j = blk-32, g = j>>5, jj = j&31;
    int b0 = g*16;
    int n0b = jj*64;          // gate-col base (reordered)
    int n0x = jj*32;          // XO-col base (jj<24)
    ushort_t* Wh = (ushort_t*)pool;              // [64][520]
    ushort_t* Wc = (ushort_t*)(pool + 66560);    // [64][264]
    ushort_t* Wx = (ushort_t*)(pool + 100352);   // [32][520]
    ushort_t* As = (ushort_t*)(pool + 133632);   // [16][520] stage
    float*    gl = (float*)(pool + 142080);      // [16][64]
    ushort_t* hst= (ushort_t*)(pool + 146176);   // 256
    ushort_t* hstA=(ushort_t*)(pool + 146688);   // 256

    for (int i=tid; i<64*64; i+=512){ int row=i>>6, ko=(i&63)*8;
      *(ushort8*)(Wh + row*520 + ko) = *(const ushort8*)(WHCp + (size_t)(n0b+row)*768 + ko); }
    for (int i=tid; i<64*32; i+=512){ int row=i>>5, ko=(i&31)*8;
      *(ushort8*)(Wc + row*264 + ko) = *(const ushort8*)(WHCp + (size_t)(n0b+row)*768 + 512 + ko); }
    if (jj < 24)
      for (int i=tid; i<32*64; i+=512){ int row=i>>6, ko=(i&63)*8;
        *(ushort8*)(Wx + row*520 + ko) = *(const ushort8*)(XWT768 + (size_t)(n0x+row)*512 + ko); }
    __syncthreads();

    f32x4 gwh = {0.f,0.f,0.f,0.f};
    float hprev = 0.f;
    // ---- prologue: stage h0, xo-first XO(0), then gwh(0) ----
    {
      const u64_t* H8 = (const u64_t*)(hnewb + (size_t)b0*512);
      for (int i=tid; i<2048; i+=512){ int row=i>>7, k4=i&127;
        *(u64_t*)(As + row*520 + k4*4) = coh_ld64(H8 + row*128 + k4); }
      __syncthreads();
      if (tid < 256) hprev = bu2f(As[(tid>>4)*520 + jj*16 + (tid&15)]);
      if (jj>=24 && tid==0) coh_sti(flags + FLG(g*32+jj), 1);
      if (jj<24 && wave<2){
        f32x4 xo = {0.f,0.f,0.f,0.f};
        for (int kc=0;kc<512;kc+=32){
          FragU a,bx;
          a.u  = *(const ushort8*)(As + r*520 + kc + 8*q);
          bx.u = *(const ushort8*)(Wx + (wave*16 + r)*520 + kc + 8*q);
          xo = __builtin_amdgcn_mfma_f32_16x16x32_bf16(bx.b, a.b, xo, 0,0,0);
        }
        int col0 = n0x + wave*16 + 4*q;
        float vv[4];
        #pragma unroll
        for (int rr=0;rr<4;rr++) vv[rr] = xo[rr] + xbias[col0+rr];
        u64_t* dst = (u64_t*)(XO + (size_t)(b0 + r)*768 + col0);
        coh_st64(dst+0, ((const u64_t*)vv)[0]);
        coh_st64(dst+1, ((const u64_t*)vv)[1]);
      }
      __syncthreads();                               // drain XO stores
      if (jj<24 && tid==0) coh_sti(flags + FLG(g*32+jj), 1);
      if (wave < 4){
        for (int kc=0;kc<512;kc+=32){
          FragU a,bw;
          a.u  = *(const ushort8*)(As + r*520 + kc + 8*q);
          bw.u = *(const ushort8*)(Wh + (wave*16 + r)*520 + kc + 8*q);
          gwh = __builtin_amdgcn_mfma_f32_16x16x32_bf16(a.b, bw.b, gwh, 0,0,0);
        }
      }
    }

    for (int t=0;t<51;t++){
      float eih[4] = {0.f,0.f,0.f,0.f};
      if (wave < 4){
        #pragma unroll
        for (int rr=0;rr<4;rr++){
          int row = 4*q + rr;
          eih[rr] = bu2f(eihR[((size_t)(b0+row)*51 + t)*2048 + n0b + wave*16 + r]);
        }
      }
      // ---- C: wait xawe ----
      if (tid < 16) while (coh_ldi(flags + FLG(128 + b0 + tid)) < t+1) __builtin_amdgcn_s_sleep(1);
      __syncthreads();
      const u64_t* X8 = (const u64_t*)(xaweb + (size_t)b0*256);
      for (int i=tid; i<1024; i+=512){ int row=i>>6, k4=i&63;
        *(u64_t*)(As + row*264 + k4*4) = coh_ld64(X8 + row*64 + k4); }
      __syncthreads();
      if (wave < 4){
        f32x4 cc = {0.f,0.f,0.f,0.f};
        for (int kc=0;kc<256;kc+=32){
          FragU a,bw;
          a.u  = *(const ushort8*)(As + r*264 + kc + 8*q);
          bw.u = *(const ushort8*)(Wc + (wave*16 + r)*264 + kc + 8*q);
          cc = __builtin_amdgcn_mfma_f32_16x16x32_bf16(a.b, bw.b, cc, 0,0,0);
        }
        #pragma unroll
        for (int rr=0;rr<4;rr++)
          gl[(4*q+rr)*64 + wave*16 + r] = gwh[rr] + cc[rr] + eih[rr];
      }
      __syncthreads();
      if (tid < 256){
        int bl = tid>>4, dd = tid&15;
        int bb = b0 + bl, d = jj*16 + dd;
        float gi = gl[bl*64 + dd*4+0], gf = gl[bl*64 + dd*4+1];
        float gg = gl[bl*64 + dd*4+2], go = gl[bl*64 + dd*4+3];
        float cold = cbuf[(size_t)bb*512 + d];
        float cnew = sigm(gf)*cold + sigm(gi)*ftanh(gg);
        float hnew = sigm(go)*ftanh(cnew);
        bool upd = (t < declen[bb]);
        if (upd) cbuf[(size_t)bb*512 + d] = cnew;
        float hkeep = upd ? hnew : hprev;
        hprev = hkeep;
        hst[tid]  = f2bu(hkeep);
        hstA[tid] = f2bu(hnew);
      }
      __syncthreads();
      if (tid < 64){
        int bl2 = tid>>2, o = tid&3;
        coh_st64((u64_t*)(hnewb + (size_t)(b0+bl2)*512 + jj*16) + o,
                 *(const u64_t*)(hst + tid*4));
        coh_st64((u64_t*)(hallb + ((size_t)((b0+bl2)*51 + t))*512 + jj*16) + o,
                 *(const u64_t*)(hstA + tid*4));
      }
      __syncthreads();                               // drain h/hallb stores
      if (tid==0) coh_sti(flags + FLG(64 + g*32 + jj), t+1);
      if (t == 50) break;

      // ---- A-inline for t+1: stage h, publish-read-done / xo-first, then gwh ----
      if (tid < 32) while (coh_ldi(flags + FLG(64 + g*32 + tid)) < t+1) __builtin_amdgcn_s_sleep(1);
      __syncthreads();
      const u64_t* H8 = (const u64_t*)(hnewb + (size_t)b0*512);
      for (int i=tid; i<2048; i+=512){ int row=i>>7, k4=i&127;
        *(u64_t*)(As + row*520 + k4*4) = coh_ld64(H8 + row*128 + k4); }
      __syncthreads();
      if (jj>=24 && tid==0) coh_sti(flags + FLG(g*32+jj), t+2);
      if (jj<24 && wave<2){
        f32x4 xo = {0.f,0.f,0.f,0.f};
        for (int kc=0;kc<512;kc+=32){
          FragU a,bx;
          a.u  = *(const ushort8*)(As + r*520 + kc + 8*q);
          bx.u = *(const ushort8*)(Wx + (wave*16 + r)*520 + kc + 8*q);
          xo = __builtin_amdgcn_mfma_f32_16x16x32_bf16(bx.b, a.b, xo, 0,0,0);
        }
        int col0 = n0x + wave*16 + 4*q;
        float vv[4];
        #pragma unroll
        for (int rr=0;rr<4;rr++) vv[rr] = xo[rr] + xbias[col0+rr];
        u64_t* dst = (u64_t*)(XO + (size_t)(b0 + r)*768 + col0);
        coh_st64(dst+0, ((const u64_t*)vv)[0]);
        coh_st64(dst+1, ((const u64_t*)vv)[1]);
      }
      __syncthreads();                               // drain XO stores
      if (jj<24 && tid==0) coh_sti(flags + FLG(g*32+jj), t+2);
      gwh = (f32x4){0.f,0.f,0.f,0.f};
      if (wave < 4){
        for (int kc=0;kc<512;kc+=32){
          FragU a,bw;
          a.u  = *(const ushort8*)(As + r*520 + kc + 8*q);
          bw.u = *(const ushort8*)(Wh + (wave*16 + r)*520 + kc + 8*q);
          gwh = __builtin_amdgcn_mfma_f32_16x16x32_bf16(a.b, bw.b, gwh, 0,0,0);
        }
      }
    }
  } else {
    // ================= PRED: per-step logits tile, consumer-only =================
    int cs = blk - 96;
    int n0 = cs*128;
    ushort_t* As2 = (ushort_t*)pool;             // [32][520]
    ushort_t* Bs2 = (ushort_t*)(pool + 66560);   // [128][40]
    int til0 = wave*2, til1 = wave*2+1;
    int mt0 = til0>>3, nt0 = til0&7;
    int mt1 = til1>>3, nt1 = til1&7;

    // ---- prologue: convert own WfcT slice (Wfc fp32 [512][20000] -> bf16 [20000][512]) ----
    {
      ushort_t* cvt = (ushort_t*)pool;           // [128][520] = 133 KB
      int jc = tid & 127, kq = tid >> 7;
      int gcol = n0 + jc;
      if (gcol < 20000){
        for (int kk=0; kk<128; kk++){
          int k = kq*128 + kk;
          cvt[jc*520 + k] = f2bu(Wfc[(size_t)k*20000 + gcol]);   // coalesced fp32 read
        }
      }
      __syncthreads();
      for (int i=tid; i<128*64; i+=512){
        int row = i>>6, ko = (i&63)*8;
        if (n0+row < 20000)
          *(ushort8*)(WfcT + (size_t)(n0+row)*512 + ko) = *(const ushort8*)(cvt + row*520 + ko);
      }
      __syncthreads();
    }

    for (int t=0;t<51;t++){
      if (tid < 64) while (coh_ldi(flags + FLG(64 + tid)) < t+1) __builtin_amdgcn_s_sleep(4);
      __syncthreads();
      // stage A: 32 hallb rows for step t (coherent). 512 bf16 = 128 u64 per row.
      for (int i=tid; i<4096; i+=512){
        int row = i>>7, k4 = i&127;
        *(u64_t*)(As2 + row*520 + k4*4) =
          coh_ld64((const u64_t*)hallb + (size_t)(row*51 + t)*128 + k4);
      }
      __syncthreads();
      f32x4 acc0 = {0.f,0.f,0.f,0.f}, acc1 = {0.f,0.f,0.f,0.f};
      for (int kc=0; kc<512; kc+=32){
        {
          int row = tid>>2, ko = (tid&3)*8;
          ushort8 wv = {0,0,0,0,0,0,0,0};
          int gr = n0 + row;
          if (gr < 20000) wv = *(const ushort8*)(WfcT + (size_t)gr*512 + kc + ko);
          *(ushort8*)(Bs2 + row*40 + ko) = wv;
        }
        __syncthreads();
        FragU a0,b0f,a1,b1f;
        a0.u  = *(const ushort8*)(As2 + (mt0*16 + r)*520 + kc + 8*q);
        b0f.u = *(const ushort8*)(Bs2 + (nt0*16 + r)*40 + 8*q);
        acc0 = __builtin_amdgcn_mfma_f32_16x16x32_bf16(a0.b, b0f.b, acc0, 0,0,0);
        a1.u  = *(const ushort8*)(As2 + (mt1*16 + r)*520 + kc + 8*q);
        b1f.u = *(const ushort8*)(Bs2 + (nt1*16 + r)*40 + 8*q);
        acc1 = __builtin_amdgcn_mfma_f32_16x16x32_bf16(a1.b, b1f.b, acc1, 0,0,0);
        __syncthreads();
      }
      // epilogue: out_preds[(b*51+t)*20000 + col]
      {
        int colG = n0 + nt0*16 + r;
        if (colG < 20000){
          float bv = bfc[colG];
          #pragma unroll
          for (int rr=0;rr<4;rr++){
            int bidx = mt0*16 + 4*q + rr;
            float v = acc0[rr] + bv;
            if (t >= declen[bidx]) v = 0.f;
            out_preds[((size_t)(bidx*51 + t))*20000 + colG] = v;
          }
        }
      }
      {
        int colG = n0 + nt1*16 + r;
        if (colG < 20000){
          float bv = bfc[colG];
          #pragma unroll
          for (int rr=0;rr<4;rr++){
            int bidx = mt1*16 + 4*q + rr;
            float v = acc1[rr] + bv;
            if (t >= declen[bidx]) v = 0.f;
            out_preds[((size_t)(bidx*51 + t))*20000 + colG] = v;
          }
        }
      }
    }
  }
}

// -------------------------------------------------------------------------------------------
extern "C" void kernel_launch(void* const* d_in, const int* in_sizes, int n_in,
                              void* d_out, int out_size, void* d_ws, size_t ws_size,
                              hipStream_t stream)
{
  const float* enc   = (const float*)d_in[0];
  const int*   cap   = (const int*)d_in[1];
  const int*   lens  = (const int*)d_in[2];
  const float* Wenc  = (const float*)d_in[3];
  const float* benc  = (const float*)d_in[4];
  const float* Wdec  = (const float*)d_in[5];
  const float* bdec  = (const float*)d_in[6];
  const float* Wfull = (const float*)d_in[7];
  // d_in[8] = b_full_att: softmax-invariant, skipped
  const float* emb   = (const float*)d_in[9];
  const float* Wih   = (const float*)d_in[10];
  const float* bih   = (const float*)d_in[11];
  const float* Whh   = (const float*)d_in[12];
  const float* bhh   = (const float*)d_in[13];
  const float* Winh  = (const float*)d_in[14];
  const float* binh  = (const float*)d_in[15];
  const float* Winc  = (const float*)d_in[16];
  const float* binc  = (const float*)d_in[17];
  const float* Wfb   = (const float*)d_in[18];
  const float* bfb   = (const float*)d_in[19];
  const float* Wfc   = (const float*)d_in[20];
  const float* bfc   = (const float*)d_in[21];
  float* out = (float*)d_out;

  char* w = (char*)d_ws;
  size_t off = 0;
  auto alloc = [&](size_t bytes)->char*{ char* p = w + off; off += (bytes + 255) & ~(size_t)255; return p; };
  ushort_t* WfcT    = (ushort_t*)alloc(20000ull*512*2);  // [20000][512] (filled by PRED prologue)
  ushort_t* WHCp    = (ushort_t*)alloc(2048ull*768*2);   // rows r=d*4+g; k: [Whh^T | WihBot^T]
  ushort_t* WihTopTp= (ushort_t*)alloc(2048ull*512*2);   // rows r=d*4+g
  ushort_t* XWT768  = (ushort_t*)alloc(768ull*512*2);    // [Wdec^T ; Wfb^T]
  ushort_t* WencT   = (ushort_t*)alloc(512ull*256*2);
  ushort_t* encb    = (ushort_t*)alloc(32ull*196*256*2);
  ushort_t* erowsb  = (ushort_t*)alloc(1632ull*512*2);
  ushort_t* att1b   = (ushort_t*)alloc(6272ull*512*2);
  ushort_t* eihR    = (ushort_t*)alloc(1632ull*2048*2);  // cols r=d*4+g, incl. b_ih + b_hh
  ushort_t* hallb   = (ushort_t*)alloc(1632ull*512*2);
  ushort_t* hnewb   = (ushort_t*)alloc(32ull*512*2);
  ushort_t* xaweb   = (ushort_t*)alloc(32ull*256*2);
  float*    XO      = (float*)alloc(32ull*768*4);
  float*    cbuf    = (float*)alloc(32ull*512*4);
  float*    xbias   = (float*)alloc(768*4);
  float*    bihR    = (float*)alloc(2048*4);
  int*      declen  = (int*)alloc(32*4);
  int*      flags   = (int*)alloc(20480);                // 160 flags x 128B line

  float* out_preds = out;                        // 32*51*20000
  float* out_cap   = out + 32640000ull;          // 32*52
  float* out_dl    = out_cap + 1664;             // 32
  float* out_alph  = out_dl + 32;                // 32*51*196

  // ---- fused preamble (one launch): all cvts + misc + init + gather ----
  k_pre1<<<6312,256,0,stream>>>(Whh, Wih, Wdec, Wfb, Wenc, enc, cap, lens,
                                bdec, bfb, bih, bhh, Winh, binh, Winc, binc, emb,
                                WHCp, WihTopTp, XWT768, WencT, encb,
                                out_cap, out_dl, declen, xbias, bihR, flags,
                                hnewb, cbuf, erowsb);
  // att1b = encb @ WencT^T + benc  (6272 x 512, K=256) -> bf16
  k_gemm<<<dim3(4,49),256,0,stream>>>(encb, 256, WencT, 256, 6272, 512, 256,
                                      benc, nullptr, att1b, 512);
  // eihR = erowsb @ WihTopTp^T + (bih+bhh reordered)  (1632 x 2048(reord), K=512) -> bf16
  k_gemm<<<dim3(16,13),256,0,stream>>>(erowsb, 512, WihTopTp, 512, 1632, 2048, 512,
                                       bihR, nullptr, eihR, 2048);

  // ---- fused 51-step recurrence + in-kernel preds + in-kernel Wfc convert ----
  k_steps<<<253,512,0,stream>>>(XWT768, WHCp, xbias, att1b, Wfull, encb, eihR, declen,
                                hnewb, cbuf, XO, xaweb, hallb, out_alph,
                                Wfc, WfcT, bfc, out_preds, flags);
}